// Round 6
// baseline (1202.903 us; speedup 1.0000x reference)
//
#include <hip/hip_runtime.h>
#include <hip/hip_bf16.h>
#include <math.h>

// ---------------------------------------------------------------------------
// GAT (3-layer, DGL-style) on MI355X.
// CSR build + degree-sorted node schedule -> per layer:
//   gemm_ft: double-buffered K-tiled fp32 register GEMM, fused el/er.
//   gat_aggregate: single-pass exp-weighted aggregation, degree-sorted
//     scheduling, 2 nodes/wave (F=128) or 4 nodes/wave (F=64), 8-wide
//     batched gathers + index software-pipelining + masked tail.
// ---------------------------------------------------------------------------

#define WAVE 64
constexpr int KDIM = 128;

// ---------------- CSR build ----------------

__global__ __launch_bounds__(256) void count_deg(const int* __restrict__ dst,
                                                 int* __restrict__ cnt, int E) {
    int e = blockIdx.x * 256 + threadIdx.x;
    if (e < E) atomicAdd(&cnt[dst[e]], 1);
}

__global__ __launch_bounds__(256) void scan_block(const int* __restrict__ cnt,
                                                  int* __restrict__ rowptr,
                                                  int* __restrict__ bsum, int n) {
    __shared__ int sh[256];
    int i = blockIdx.x * 256 + threadIdx.x;
    int v = (i < n) ? cnt[i] : 0;
    sh[threadIdx.x] = v;
    __syncthreads();
    for (int off = 1; off < 256; off <<= 1) {
        int t = (threadIdx.x >= off) ? sh[threadIdx.x - off] : 0;
        __syncthreads();
        sh[threadIdx.x] += t;
        __syncthreads();
    }
    if (i < n) rowptr[i + 1] = sh[threadIdx.x];
    if (threadIdx.x == 255) bsum[blockIdx.x] = sh[255];
}

__global__ __launch_bounds__(512) void scan_partials(int* __restrict__ bsum, int nb) {
    __shared__ int sh[512];
    int tid = threadIdx.x;
    int v = (tid < nb) ? bsum[tid] : 0;
    sh[tid] = v;
    __syncthreads();
    for (int off = 1; off < 512; off <<= 1) {
        int t = (tid >= off) ? sh[tid - off] : 0;
        __syncthreads();
        sh[tid] += t;
        __syncthreads();
    }
    if (tid < nb) bsum[tid] = sh[tid] - v;  // exclusive
}

__global__ __launch_bounds__(256) void scan_add(int* __restrict__ rowptr,
                                                const int* __restrict__ bsum,
                                                const int* __restrict__ cnt,
                                                int* __restrict__ nxt, int n) {
    int i = blockIdx.x * 256 + threadIdx.x;
    if (i < n) {
        int r = rowptr[i + 1] + bsum[blockIdx.x];
        rowptr[i + 1] = r;
        nxt[i] = r - cnt[i];
        if (i == 0) rowptr[0] = 0;
    }
}

__global__ __launch_bounds__(256) void fill_csr(const int* __restrict__ src,
                                                const int* __restrict__ dst,
                                                int* __restrict__ nxt,
                                                int* __restrict__ colx, int E) {
    int e = blockIdx.x * 256 + threadIdx.x;
    if (e < E) {
        int d = dst[e];
        int pos = atomicAdd(&nxt[d], 1);
        colx[pos] = src[e];
    }
}

// ---------------- degree-sorted schedule (counting sort, descending) ------

__global__ __launch_bounds__(256) void deg_hist(const int* __restrict__ cnt,
                                                int* __restrict__ hist, int n) {
    int i = blockIdx.x * 256 + threadIdx.x;
    if (i < n) atomicAdd(&hist[min(cnt[i], 255)], 1);
}

__global__ __launch_bounds__(256) void bin_scan(const int* __restrict__ hist,
                                                int* __restrict__ binbase,
                                                int* __restrict__ bincur, int n) {
    __shared__ int sh[256];
    int t = threadIdx.x;
    int v = hist[t];
    sh[t] = v;
    __syncthreads();
    for (int off = 1; off < 256; off <<= 1) {
        int u = (t >= off) ? sh[t - off] : 0;
        __syncthreads();
        sh[t] += u;
        __syncthreads();
    }
    // descending bins: bin b starts at n - inclusive(b)
    binbase[t] = n - sh[t];
    bincur[t] = 0;
}

__global__ __launch_bounds__(256) void bin_scatter(const int* __restrict__ cnt,
                                                   const int* __restrict__ binbase,
                                                   int* __restrict__ bincur,
                                                   int* __restrict__ perm, int n) {
    int i = blockIdx.x * 256 + threadIdx.x;
    if (i < n) {
        int b = min(cnt[i], 255);
        int pos = binbase[b] + atomicAdd(&bincur[b], 1);
        perm[pos] = i;
    }
}

// ---------------- GEMM + attention logits (double-buffered) ----------------

template <int FOUT, int H>
__global__ __launch_bounds__(256) void gemm_ft(
    const float* __restrict__ hin, const float* __restrict__ W,
    const float* __restrict__ al, const float* __restrict__ ar,
    float* __restrict__ ft, float* __restrict__ el, float* __restrict__ er,
    int nnodes) {
    constexpr int BK = 32;
    constexpr int LDH = 132;                   // padded, mult of 4
    constexpr int TN = (FOUT == 128) ? 8 : 4;  // cols per thread
    constexpr int WCH = BK * FOUT / 1024;      // float4 staging iters: 4 or 2

    __shared__ float ht[2][BK * LDH];   // 2 x 16.9 KB
    __shared__ float Ws[2][BK * FOUT];  // 2 x 16 / 8 KB

    const int tid = threadIdx.x;
    const int nb = blockIdx.x * 128;
    const int tc = tid & 15, row = tid >> 4;
    const int nl = tid >> 3;       // 0..31
    const int kq = (tid & 7) * 4;  // 0,4,..,28

    float4 hreg[4];
    float4 wreg[WCH];

    auto load_chunk = [&](int k0) {
#pragma unroll
        for (int it = 0; it < 4; ++it) {
            int n = nb + nl + it * 32;
            hreg[it] = (n < nnodes)
                           ? *(const float4*)&hin[(size_t)n * KDIM + k0 + kq]
                           : make_float4(0.f, 0.f, 0.f, 0.f);
        }
        const float4* Wg = (const float4*)&W[(size_t)k0 * FOUT];
#pragma unroll
        for (int it = 0; it < WCH; ++it) wreg[it] = Wg[tid + it * 256];
    };
    auto store_chunk = [&](int b) {
#pragma unroll
        for (int it = 0; it < 4; ++it) {
            int nn = nl + it * 32;
            ht[b][(kq + 0) * LDH + nn] = hreg[it].x;
            ht[b][(kq + 1) * LDH + nn] = hreg[it].y;
            ht[b][(kq + 2) * LDH + nn] = hreg[it].z;
            ht[b][(kq + 3) * LDH + nn] = hreg[it].w;
        }
#pragma unroll
        for (int it = 0; it < WCH; ++it)
            ((float4*)Ws[b])[tid + it * 256] = wreg[it];
    };

    float acc[8][TN];
#pragma unroll
    for (int m = 0; m < 8; ++m)
#pragma unroll
        for (int j = 0; j < TN; ++j) acc[m][j] = 0.f;

    load_chunk(0);
    store_chunk(0);
    __syncthreads();

    for (int k0 = 0; k0 < KDIM / BK; ++k0) {
        const int cur = k0 & 1;
        if (k0 < KDIM / BK - 1) load_chunk((k0 + 1) * BK);

#pragma unroll 4
        for (int kk = 0; kk < BK; ++kk) {
            const float* hb = &ht[cur][kk * LDH];
            float4 h0 = *(const float4*)&hb[row * 4];
            float4 h1 = *(const float4*)&hb[64 + row * 4];
            float hv[8] = {h0.x, h0.y, h0.z, h0.w, h1.x, h1.y, h1.z, h1.w};
            const float* wb = &Ws[cur][kk * FOUT];
            float4 w0 = *(const float4*)&wb[tc * 4];
            float wv[TN];
            wv[0] = w0.x; wv[1] = w0.y; wv[2] = w0.z; wv[3] = w0.w;
            if constexpr (FOUT == 128) {
                float4 w1 = *(const float4*)&wb[64 + tc * 4];
                wv[4] = w1.x; wv[5] = w1.y; wv[6] = w1.z; wv[7] = w1.w;
            }
#pragma unroll
            for (int m = 0; m < 8; ++m)
#pragma unroll
                for (int j = 0; j < TN; ++j)
                    acc[m][j] = fmaf(hv[m], wv[j], acc[m][j]);
        }
        if (k0 < KDIM / BK - 1) store_chunk(cur ^ 1);
        __syncthreads();
    }

    float alv[TN], arv[TN];
#pragma unroll
    for (int j = 0; j < 4; ++j) {
        alv[j] = al[tc * 4 + j];
        arv[j] = ar[tc * 4 + j];
    }
    if constexpr (FOUT == 128) {
#pragma unroll
        for (int j = 0; j < 4; ++j) {
            alv[4 + j] = al[64 + tc * 4 + j];
            arv[4 + j] = ar[64 + tc * 4 + j];
        }
    }

#pragma unroll
    for (int m = 0; m < 8; ++m) {
        const int r = (m < 4) ? (row * 4 + m) : (64 + row * 4 + m - 4);
        const int n = nb + r;
        const bool valid = n < nnodes;

        float pl0 = 0.f, pr0 = 0.f, pl1 = 0.f, pr1 = 0.f;
#pragma unroll
        for (int j = 0; j < 4; ++j) {
            pl0 = fmaf(acc[m][j], alv[j], pl0);
            pr0 = fmaf(acc[m][j], arv[j], pr0);
        }
        if constexpr (FOUT == 128) {
#pragma unroll
            for (int j = 0; j < 4; ++j) {
                pl1 = fmaf(acc[m][4 + j], alv[4 + j], pl1);
                pr1 = fmaf(acc[m][4 + j], arv[4 + j], pr1);
            }
        }

        if constexpr (H == 4) {
#pragma unroll
            for (int msk = 1; msk < 8; msk <<= 1) {
                pl0 += __shfl_xor(pl0, msk);
                pr0 += __shfl_xor(pr0, msk);
                pl1 += __shfl_xor(pl1, msk);
                pr1 += __shfl_xor(pr1, msk);
            }
            if (valid && (tc == 0 || tc == 8)) {
                int hbase = (tc == 0) ? 0 : 1;
                el[(size_t)n * 4 + hbase] = pl0;
                er[(size_t)n * 4 + hbase] = pr0;
                el[(size_t)n * 4 + hbase + 2] = pl1;
                er[(size_t)n * 4 + hbase + 2] = pr1;
            }
        } else {
#pragma unroll
            for (int msk = 1; msk < 16; msk <<= 1) {
                pl0 += __shfl_xor(pl0, msk);
                pr0 += __shfl_xor(pr0, msk);
            }
            if (valid && tc == 0) {
                el[n] = pl0;
                er[n] = pr0;
            }
        }

        if (valid) {
            *(float4*)&ft[(size_t)n * FOUT + tc * 4] =
                make_float4(acc[m][0], acc[m][1], acc[m][2], acc[m][3]);
            if constexpr (FOUT == 128)
                *(float4*)&ft[(size_t)n * FOUT + 64 + tc * 4] =
                    make_float4(acc[m][4], acc[m][5], acc[m][6], acc[m][7]);
        }
    }
}

// ---------------- Edge-softmax aggregation ----------------
// Degree-sorted scheduling via perm. F=128: 2 nodes/wave (32 lanes each);
// F=64: 4 nodes/wave (16 lanes each). Each lane owns 4 cols (float4).
// Per iteration: 8 batched ft gathers, 8 el gathers, prefetch next 8
// indices, compute. Tail masked via idx=-1 -> p=0.

template <int F, int H, bool RELU>
__global__ __launch_bounds__(256) void gat_aggregate(
    const int* __restrict__ perm, const int* __restrict__ rowptr,
    const int* __restrict__ colx, const float* __restrict__ ft,
    const float* __restrict__ el, const float* __restrict__ er,
    const float* __restrict__ bias, float* __restrict__ out, int nnodes) {
    constexpr int UN = 8;
    constexpr int LPG = (F == 128) ? 32 : 16;  // lanes per node group
    constexpr int NPW = 64 / LPG;              // nodes per wave
    const int tid = threadIdx.x, wv = tid >> 6, lane = tid & 63;
    const int grp = lane / LPG, sub = lane % LPG;
    const int pos = blockIdx.x * (4 * NPW) + wv * NPW + grp;
    const int n = (pos < nnodes) ? perm[pos] : -1;
    const bool valid = n >= 0;
    const int nn = valid ? n : 0;

    const int start = rowptr[nn];
    const int end = valid ? rowptr[nn + 1] : start;
    const int deg = end - start;
    int md = deg;
    if constexpr (F == 64) md = max(md, __shfl_xor(md, 16));
    md = max(md, __shfl_xor(md, 32));
    const int nit = (md + UN - 1) / UN;

    const int head = (H == 4) ? (sub >> 3) : 0;
    const float er_s = (H == 4) ? er[(size_t)nn * 4 + head] : er[nn];

    float sA = 0.f, sB = 0.f;
    float aA[4], aB[4];
#pragma unroll
    for (int c = 0; c < 4; ++c) { aA[c] = 0.f; aB[c] = 0.f; }

    int idx[UN];
#pragma unroll
    for (int i = 0; i < UN; ++i) {
        int ee = start + i;
        idx[i] = (ee < end) ? colx[ee] : -1;
    }

    for (int it = 0; it < nit; ++it) {
        // 1) long-latency ft gathers first (8 independent, all in flight)
        float fx[UN][4];
#pragma unroll
        for (int i = 0; i < UN; ++i) {
            int sn = (idx[i] < 0) ? 0 : idx[i];
            float4 v = *(const float4*)&ft[(size_t)sn * F + sub * 4];
            fx[i][0] = v.x; fx[i][1] = v.y; fx[i][2] = v.z; fx[i][3] = v.w;
        }
        // 2) el gathers
        float xl[UN];
#pragma unroll
        for (int i = 0; i < UN; ++i) {
            int sn = (idx[i] < 0) ? 0 : idx[i];
            xl[i] = (H == 4) ? el[(size_t)sn * 4 + head] : el[sn];
        }
        // 3) software-pipeline: prefetch next batch of indices
        int nidx[UN];
        {
            int base2 = start + (it + 1) * UN;
#pragma unroll
            for (int i = 0; i < UN; ++i) {
                int ee = base2 + i;
                nidx[i] = (ee < end) ? colx[ee] : -1;
            }
        }
        // 4) compute
#pragma unroll
        for (int i = 0; i < UN; ++i) {
            float x = xl[i] + er_s;
            x = fmaxf(x, 0.2f * x);  // leaky_relu
            float p = __expf(x);
            p = (idx[i] >= 0) ? p : 0.f;
            if (i & 1) {
                sB += p;
#pragma unroll
                for (int c = 0; c < 4; ++c) aB[c] = fmaf(p, fx[i][c], aB[c]);
            } else {
                sA += p;
#pragma unroll
                for (int c = 0; c < 4; ++c) aA[c] = fmaf(p, fx[i][c], aA[c]);
            }
        }
#pragma unroll
        for (int i = 0; i < UN; ++i) idx[i] = nidx[i];
    }

    if (!valid) return;
    float s = sA + sB;
    float inv = 1.0f / s;  // deg >= 1 guaranteed
    float4 b4 = *(const float4*)&bias[sub * 4];
    float o[4] = {(aA[0] + aB[0]) * inv + b4.x, (aA[1] + aB[1]) * inv + b4.y,
                  (aA[2] + aB[2]) * inv + b4.z, (aA[3] + aB[3]) * inv + b4.w};
    if (RELU) {
#pragma unroll
        for (int c = 0; c < 4; ++c) o[c] = fmaxf(o[c], 0.f);
    }
    *(float4*)&out[(size_t)n * F + sub * 4] = make_float4(o[0], o[1], o[2], o[3]);
}

// ---------------- host launch ----------------

static inline size_t alignup(size_t x) { return (x + 255) & ~(size_t)255; }

extern "C" void kernel_launch(void* const* d_in, const int* in_sizes, int n_in,
                              void* d_out, int out_size, void* d_ws, size_t ws_size,
                              hipStream_t stream) {
    const float* features = (const float*)d_in[0];
    const int* src = (const int*)d_in[1];
    const int* dst = (const int*)d_in[2];
    const float* W0 = (const float*)d_in[3];
    const float* al0 = (const float*)d_in[4];
    const float* ar0 = (const float*)d_in[5];
    const float* b0 = (const float*)d_in[6];
    const float* W1 = (const float*)d_in[7];
    const float* al1 = (const float*)d_in[8];
    const float* ar1 = (const float*)d_in[9];
    const float* b1 = (const float*)d_in[10];
    const float* W2 = (const float*)d_in[11];
    const float* al2 = (const float*)d_in[12];
    const float* ar2 = (const float*)d_in[13];
    const float* b2 = (const float*)d_in[14];
    float* out = (float*)d_out;

    const int N = in_sizes[0] / 128;  // 100000
    const int E = in_sizes[1];        // 1600000

    char* w = (char*)d_ws;
    int* cnt = (int*)w;        w += alignup((size_t)N * 4);
    int* rowptr = (int*)w;     w += alignup((size_t)(N + 1) * 4);
    int* nxt = (int*)w;        w += alignup((size_t)N * 4);
    int* bsum = (int*)w;       w += alignup(512 * 4);
    int* colx = (int*)w;       w += alignup((size_t)E * 4);
    float* ft = (float*)w;     w += alignup((size_t)N * 128 * 4);
    float* hbuf = (float*)w;   w += alignup((size_t)N * 128 * 4);
    float* el = (float*)w;     w += alignup((size_t)N * 4 * 4);
    float* er = (float*)w;     w += alignup((size_t)N * 4 * 4);
    int* hist = (int*)w;       w += alignup(256 * 4);
    int* binbase = (int*)w;    w += alignup(256 * 4);
    int* bincur = (int*)w;     w += alignup(256 * 4);
    int* perm = (int*)w;       w += alignup((size_t)N * 4);

    const int nbE = (E + 255) / 256;
    const int nbN = (N + 255) / 256;

    // CSR build
    hipMemsetAsync(cnt, 0, (size_t)N * 4, stream);
    hipMemsetAsync(hist, 0, 256 * 4, stream);
    count_deg<<<nbE, 256, 0, stream>>>(dst, cnt, E);
    scan_block<<<nbN, 256, 0, stream>>>(cnt, rowptr, bsum, N);
    scan_partials<<<1, 512, 0, stream>>>(bsum, nbN);
    scan_add<<<nbN, 256, 0, stream>>>(rowptr, bsum, cnt, nxt, N);
    fill_csr<<<nbE, 256, 0, stream>>>(src, dst, nxt, colx, E);
    // degree-sorted schedule
    deg_hist<<<nbN, 256, 0, stream>>>(cnt, hist, N);
    bin_scan<<<1, 256, 0, stream>>>(hist, binbase, bincur, N);
    bin_scatter<<<nbN, 256, 0, stream>>>(cnt, binbase, bincur, perm, N);

    const int gGemm = (N + 127) / 128;
    const int gAgg8 = (N + 7) / 8;    // F=128: 2 nodes/wave, 4 waves
    const int gAgg16 = (N + 15) / 16; // F=64:  4 nodes/wave, 4 waves

    // Layer 0
    gemm_ft<128, 4><<<gGemm, 256, 0, stream>>>(features, W0, al0, ar0, ft, el, er, N);
    gat_aggregate<128, 4, true><<<gAgg8, 256, 0, stream>>>(perm, rowptr, colx, ft, el, er, b0, hbuf, N);

    // Layer 1
    gemm_ft<128, 4><<<gGemm, 256, 0, stream>>>(hbuf, W1, al1, ar1, ft, el, er, N);
    gat_aggregate<128, 4, true><<<gAgg8, 256, 0, stream>>>(perm, rowptr, colx, ft, el, er, b1, hbuf, N);

    // Layer 2
    gemm_ft<64, 1><<<gGemm, 256, 0, stream>>>(hbuf, W2, al2, ar2, ft, el, er, N);
    gat_aggregate<64, 1, false><<<gAgg16, 256, 0, stream>>>(perm, rowptr, colx, ft, el, er, b2, out, N);
}

// Round 7
// 685.377 us; speedup vs baseline: 1.7551x; 1.7551x over previous
//
#include <hip/hip_runtime.h>
#include <hip/hip_bf16.h>
#include <math.h>

// ---------------------------------------------------------------------------
// GAT (3-layer, DGL-style) on MI355X.
// CSR build + atomic-free degree-sorted node schedule -> per layer:
//   gemm_ft: double-buffered K-tiled fp32 register GEMM, fused el/er.
//   gat_aggregate: single-pass exp-weighted aggregation, degree-sorted
//     scheduling, 2 nodes/wave (F=128) or 4 nodes/wave (F=64), 8-wide
//     batched gathers + index software-pipelining + masked tail.
// ---------------------------------------------------------------------------

#define WAVE 64
constexpr int KDIM = 128;

// ---------------- CSR build ----------------

__global__ __launch_bounds__(256) void count_deg(const int* __restrict__ dst,
                                                 int* __restrict__ cnt, int E) {
    int e = blockIdx.x * 256 + threadIdx.x;
    if (e < E) atomicAdd(&cnt[dst[e]], 1);
}

__global__ __launch_bounds__(256) void scan_block(const int* __restrict__ cnt,
                                                  int* __restrict__ rowptr,
                                                  int* __restrict__ bsum, int n) {
    __shared__ int sh[256];
    int i = blockIdx.x * 256 + threadIdx.x;
    int v = (i < n) ? cnt[i] : 0;
    sh[threadIdx.x] = v;
    __syncthreads();
    for (int off = 1; off < 256; off <<= 1) {
        int t = (threadIdx.x >= off) ? sh[threadIdx.x - off] : 0;
        __syncthreads();
        sh[threadIdx.x] += t;
        __syncthreads();
    }
    if (i < n) rowptr[i + 1] = sh[threadIdx.x];
    if (threadIdx.x == 255) bsum[blockIdx.x] = sh[255];
}

__global__ __launch_bounds__(512) void scan_partials(int* __restrict__ bsum, int nb) {
    __shared__ int sh[512];
    int tid = threadIdx.x;
    int v = (tid < nb) ? bsum[tid] : 0;
    sh[tid] = v;
    __syncthreads();
    for (int off = 1; off < 512; off <<= 1) {
        int t = (tid >= off) ? sh[tid - off] : 0;
        __syncthreads();
        sh[tid] += t;
        __syncthreads();
    }
    if (tid < nb) bsum[tid] = sh[tid] - v;  // exclusive
}

__global__ __launch_bounds__(256) void scan_add(int* __restrict__ rowptr,
                                                const int* __restrict__ bsum,
                                                const int* __restrict__ cnt,
                                                int* __restrict__ nxt, int n) {
    int i = blockIdx.x * 256 + threadIdx.x;
    if (i < n) {
        int r = rowptr[i + 1] + bsum[blockIdx.x];
        rowptr[i + 1] = r;
        nxt[i] = r - cnt[i];
        if (i == 0) rowptr[0] = 0;
    }
}

__global__ __launch_bounds__(256) void fill_csr(const int* __restrict__ src,
                                                const int* __restrict__ dst,
                                                int* __restrict__ nxt,
                                                int* __restrict__ colx, int E) {
    int e = blockIdx.x * 256 + threadIdx.x;
    if (e < E) {
        int d = dst[e];
        int pos = atomicAdd(&nxt[d], 1);
        colx[pos] = src[e];
    }
}

// ------- degree-sorted schedule: atomic-free counting sort (descending) ----
// block_hist: per-block LDS histogram -> cmat[bin][blk]
// row_scan:   per-bin exclusive scan over blocks -> offsets + rowtot
// bin_base:   descending-bin exclusive scan of rowtot -> binbase
// bin_scatter2: per-block local ranks (LDS atomics) + direct scatter.

__global__ __launch_bounds__(256) void block_hist(const int* __restrict__ cnt,
                                                  int* __restrict__ cmat,
                                                  int n, int nb) {
    __shared__ int lh[256];
    const int t = threadIdx.x;
    lh[t] = 0;
    __syncthreads();
    int i = blockIdx.x * 256 + t;
    if (i < n) atomicAdd(&lh[min(cnt[i], 255)], 1);
    __syncthreads();
    cmat[t * nb + blockIdx.x] = lh[t];  // bin-major
}

__global__ __launch_bounds__(512) void row_scan(int* __restrict__ cmat,
                                                int* __restrict__ rowtot, int nb) {
    __shared__ int sh[512];
    const int b = blockIdx.x, t = threadIdx.x;
    int v = (t < nb) ? cmat[b * nb + t] : 0;
    sh[t] = v;
    __syncthreads();
    for (int off = 1; off < 512; off <<= 1) {
        int u = (t >= off) ? sh[t - off] : 0;
        __syncthreads();
        sh[t] += u;
        __syncthreads();
    }
    if (t < nb) cmat[b * nb + t] = sh[t] - v;  // exclusive within row
    if (t == 511) rowtot[b] = sh[511];
}

__global__ __launch_bounds__(256) void bin_base(const int* __restrict__ rowtot,
                                                int* __restrict__ binbase) {
    __shared__ int sh[256];
    const int t = threadIdx.x;
    int v = rowtot[255 - t];  // descending bin order
    sh[t] = v;
    __syncthreads();
    for (int off = 1; off < 256; off <<= 1) {
        int u = (t >= off) ? sh[t - off] : 0;
        __syncthreads();
        sh[t] += u;
        __syncthreads();
    }
    binbase[255 - t] = sh[t] - v;  // exclusive prefix (descending)
}

__global__ __launch_bounds__(256) void bin_scatter2(const int* __restrict__ cnt,
                                                    const int* __restrict__ cmat,
                                                    const int* __restrict__ binbase,
                                                    int* __restrict__ perm,
                                                    int n, int nb) {
    __shared__ int lh[256];
    const int t = threadIdx.x;
    lh[t] = 0;
    __syncthreads();
    int i = blockIdx.x * 256 + t;
    int b = 0, lr = 0;
    if (i < n) {
        b = min(cnt[i], 255);
        lr = atomicAdd(&lh[b], 1);  // LDS atomic: on-chip, cheap
    }
    __syncthreads();
    if (i < n) perm[binbase[b] + cmat[b * nb + blockIdx.x] + lr] = i;
}

// ---------------- GEMM + attention logits (double-buffered) ----------------

template <int FOUT, int H>
__global__ __launch_bounds__(256) void gemm_ft(
    const float* __restrict__ hin, const float* __restrict__ W,
    const float* __restrict__ al, const float* __restrict__ ar,
    float* __restrict__ ft, float* __restrict__ el, float* __restrict__ er,
    int nnodes) {
    constexpr int BK = 32;
    constexpr int LDH = 132;                   // padded, mult of 4
    constexpr int TN = (FOUT == 128) ? 8 : 4;  // cols per thread
    constexpr int WCH = BK * FOUT / 1024;      // float4 staging iters: 4 or 2

    __shared__ float ht[2][BK * LDH];   // 2 x 16.9 KB
    __shared__ float Ws[2][BK * FOUT];  // 2 x 16 / 8 KB

    const int tid = threadIdx.x;
    const int nb = blockIdx.x * 128;
    const int tc = tid & 15, row = tid >> 4;
    const int nl = tid >> 3;       // 0..31
    const int kq = (tid & 7) * 4;  // 0,4,..,28

    float4 hreg[4];
    float4 wreg[WCH];

    auto load_chunk = [&](int k0) {
#pragma unroll
        for (int it = 0; it < 4; ++it) {
            int n = nb + nl + it * 32;
            hreg[it] = (n < nnodes)
                           ? *(const float4*)&hin[(size_t)n * KDIM + k0 + kq]
                           : make_float4(0.f, 0.f, 0.f, 0.f);
        }
        const float4* Wg = (const float4*)&W[(size_t)k0 * FOUT];
#pragma unroll
        for (int it = 0; it < WCH; ++it) wreg[it] = Wg[tid + it * 256];
    };
    auto store_chunk = [&](int b) {
#pragma unroll
        for (int it = 0; it < 4; ++it) {
            int nn = nl + it * 32;
            ht[b][(kq + 0) * LDH + nn] = hreg[it].x;
            ht[b][(kq + 1) * LDH + nn] = hreg[it].y;
            ht[b][(kq + 2) * LDH + nn] = hreg[it].z;
            ht[b][(kq + 3) * LDH + nn] = hreg[it].w;
        }
#pragma unroll
        for (int it = 0; it < WCH; ++it)
            ((float4*)Ws[b])[tid + it * 256] = wreg[it];
    };

    float acc[8][TN];
#pragma unroll
    for (int m = 0; m < 8; ++m)
#pragma unroll
        for (int j = 0; j < TN; ++j) acc[m][j] = 0.f;

    load_chunk(0);
    store_chunk(0);
    __syncthreads();

    for (int k0 = 0; k0 < KDIM / BK; ++k0) {
        const int cur = k0 & 1;
        if (k0 < KDIM / BK - 1) load_chunk((k0 + 1) * BK);

#pragma unroll 4
        for (int kk = 0; kk < BK; ++kk) {
            const float* hb = &ht[cur][kk * LDH];
            float4 h0 = *(const float4*)&hb[row * 4];
            float4 h1 = *(const float4*)&hb[64 + row * 4];
            float hv[8] = {h0.x, h0.y, h0.z, h0.w, h1.x, h1.y, h1.z, h1.w};
            const float* wb = &Ws[cur][kk * FOUT];
            float4 w0 = *(const float4*)&wb[tc * 4];
            float wv[TN];
            wv[0] = w0.x; wv[1] = w0.y; wv[2] = w0.z; wv[3] = w0.w;
            if constexpr (FOUT == 128) {
                float4 w1 = *(const float4*)&wb[64 + tc * 4];
                wv[4] = w1.x; wv[5] = w1.y; wv[6] = w1.z; wv[7] = w1.w;
            }
#pragma unroll
            for (int m = 0; m < 8; ++m)
#pragma unroll
                for (int j = 0; j < TN; ++j)
                    acc[m][j] = fmaf(hv[m], wv[j], acc[m][j]);
        }
        if (k0 < KDIM / BK - 1) store_chunk(cur ^ 1);
        __syncthreads();
    }

    float alv[TN], arv[TN];
#pragma unroll
    for (int j = 0; j < 4; ++j) {
        alv[j] = al[tc * 4 + j];
        arv[j] = ar[tc * 4 + j];
    }
    if constexpr (FOUT == 128) {
#pragma unroll
        for (int j = 0; j < 4; ++j) {
            alv[4 + j] = al[64 + tc * 4 + j];
            arv[4 + j] = ar[64 + tc * 4 + j];
        }
    }

#pragma unroll
    for (int m = 0; m < 8; ++m) {
        const int r = (m < 4) ? (row * 4 + m) : (64 + row * 4 + m - 4);
        const int n = nb + r;
        const bool valid = n < nnodes;

        float pl0 = 0.f, pr0 = 0.f, pl1 = 0.f, pr1 = 0.f;
#pragma unroll
        for (int j = 0; j < 4; ++j) {
            pl0 = fmaf(acc[m][j], alv[j], pl0);
            pr0 = fmaf(acc[m][j], arv[j], pr0);
        }
        if constexpr (FOUT == 128) {
#pragma unroll
            for (int j = 0; j < 4; ++j) {
                pl1 = fmaf(acc[m][4 + j], alv[4 + j], pl1);
                pr1 = fmaf(acc[m][4 + j], arv[4 + j], pr1);
            }
        }

        if constexpr (H == 4) {
#pragma unroll
            for (int msk = 1; msk < 8; msk <<= 1) {
                pl0 += __shfl_xor(pl0, msk);
                pr0 += __shfl_xor(pr0, msk);
                pl1 += __shfl_xor(pl1, msk);
                pr1 += __shfl_xor(pr1, msk);
            }
            if (valid && (tc == 0 || tc == 8)) {
                int hbase = (tc == 0) ? 0 : 1;
                el[(size_t)n * 4 + hbase] = pl0;
                er[(size_t)n * 4 + hbase] = pr0;
                el[(size_t)n * 4 + hbase + 2] = pl1;
                er[(size_t)n * 4 + hbase + 2] = pr1;
            }
        } else {
#pragma unroll
            for (int msk = 1; msk < 16; msk <<= 1) {
                pl0 += __shfl_xor(pl0, msk);
                pr0 += __shfl_xor(pr0, msk);
            }
            if (valid && tc == 0) {
                el[n] = pl0;
                er[n] = pr0;
            }
        }

        if (valid) {
            *(float4*)&ft[(size_t)n * FOUT + tc * 4] =
                make_float4(acc[m][0], acc[m][1], acc[m][2], acc[m][3]);
            if constexpr (FOUT == 128)
                *(float4*)&ft[(size_t)n * FOUT + 64 + tc * 4] =
                    make_float4(acc[m][4], acc[m][5], acc[m][6], acc[m][7]);
        }
    }
}

// ---------------- Edge-softmax aggregation ----------------
// Degree-sorted scheduling via perm. F=128: 2 nodes/wave (32 lanes each);
// F=64: 4 nodes/wave (16 lanes each). Each lane owns 4 cols (float4).
// Per iteration: 8 batched ft gathers, 8 el gathers, prefetch next 8
// indices, compute. Tail masked via idx=-1 -> p=0.

template <int F, int H, bool RELU>
__global__ __launch_bounds__(256) void gat_aggregate(
    const int* __restrict__ perm, const int* __restrict__ rowptr,
    const int* __restrict__ colx, const float* __restrict__ ft,
    const float* __restrict__ el, const float* __restrict__ er,
    const float* __restrict__ bias, float* __restrict__ out, int nnodes) {
    constexpr int UN = 8;
    constexpr int LPG = (F == 128) ? 32 : 16;  // lanes per node group
    constexpr int NPW = 64 / LPG;              // nodes per wave
    const int tid = threadIdx.x, wv = tid >> 6, lane = tid & 63;
    const int grp = lane / LPG, sub = lane % LPG;
    const int pos = blockIdx.x * (4 * NPW) + wv * NPW + grp;
    const int n = (pos < nnodes) ? perm[pos] : -1;
    const bool valid = n >= 0;
    const int nn = valid ? n : 0;

    const int start = rowptr[nn];
    const int end = valid ? rowptr[nn + 1] : start;
    const int deg = end - start;
    int md = deg;
    if constexpr (F == 64) md = max(md, __shfl_xor(md, 16));
    md = max(md, __shfl_xor(md, 32));
    const int nit = (md + UN - 1) / UN;

    const int head = (H == 4) ? (sub >> 3) : 0;
    const float er_s = (H == 4) ? er[(size_t)nn * 4 + head] : er[nn];

    float sA = 0.f, sB = 0.f;
    float aA[4], aB[4];
#pragma unroll
    for (int c = 0; c < 4; ++c) { aA[c] = 0.f; aB[c] = 0.f; }

    int idx[UN];
#pragma unroll
    for (int i = 0; i < UN; ++i) {
        int ee = start + i;
        idx[i] = (ee < end) ? colx[ee] : -1;
    }

    for (int it = 0; it < nit; ++it) {
        // 1) long-latency ft gathers first (8 independent, all in flight)
        float fx[UN][4];
#pragma unroll
        for (int i = 0; i < UN; ++i) {
            int sn = (idx[i] < 0) ? 0 : idx[i];
            float4 v = *(const float4*)&ft[(size_t)sn * F + sub * 4];
            fx[i][0] = v.x; fx[i][1] = v.y; fx[i][2] = v.z; fx[i][3] = v.w;
        }
        // 2) el gathers
        float xl[UN];
#pragma unroll
        for (int i = 0; i < UN; ++i) {
            int sn = (idx[i] < 0) ? 0 : idx[i];
            xl[i] = (H == 4) ? el[(size_t)sn * 4 + head] : el[sn];
        }
        // 3) software-pipeline: prefetch next batch of indices
        int nidx[UN];
        {
            int base2 = start + (it + 1) * UN;
#pragma unroll
            for (int i = 0; i < UN; ++i) {
                int ee = base2 + i;
                nidx[i] = (ee < end) ? colx[ee] : -1;
            }
        }
        // 4) compute
#pragma unroll
        for (int i = 0; i < UN; ++i) {
            float x = xl[i] + er_s;
            x = fmaxf(x, 0.2f * x);  // leaky_relu
            float p = __expf(x);
            p = (idx[i] >= 0) ? p : 0.f;
            if (i & 1) {
                sB += p;
#pragma unroll
                for (int c = 0; c < 4; ++c) aB[c] = fmaf(p, fx[i][c], aB[c]);
            } else {
                sA += p;
#pragma unroll
                for (int c = 0; c < 4; ++c) aA[c] = fmaf(p, fx[i][c], aA[c]);
            }
        }
#pragma unroll
        for (int i = 0; i < UN; ++i) idx[i] = nidx[i];
    }

    if (!valid) return;
    float s = sA + sB;
    float inv = 1.0f / s;  // deg >= 1 guaranteed
    float4 b4 = *(const float4*)&bias[sub * 4];
    float o[4] = {(aA[0] + aB[0]) * inv + b4.x, (aA[1] + aB[1]) * inv + b4.y,
                  (aA[2] + aB[2]) * inv + b4.z, (aA[3] + aB[3]) * inv + b4.w};
    if (RELU) {
#pragma unroll
        for (int c = 0; c < 4; ++c) o[c] = fmaxf(o[c], 0.f);
    }
    *(float4*)&out[(size_t)n * F + sub * 4] = make_float4(o[0], o[1], o[2], o[3]);
}

// ---------------- host launch ----------------

static inline size_t alignup(size_t x) { return (x + 255) & ~(size_t)255; }

extern "C" void kernel_launch(void* const* d_in, const int* in_sizes, int n_in,
                              void* d_out, int out_size, void* d_ws, size_t ws_size,
                              hipStream_t stream) {
    const float* features = (const float*)d_in[0];
    const int* src = (const int*)d_in[1];
    const int* dst = (const int*)d_in[2];
    const float* W0 = (const float*)d_in[3];
    const float* al0 = (const float*)d_in[4];
    const float* ar0 = (const float*)d_in[5];
    const float* b0 = (const float*)d_in[6];
    const float* W1 = (const float*)d_in[7];
    const float* al1 = (const float*)d_in[8];
    const float* ar1 = (const float*)d_in[9];
    const float* b1 = (const float*)d_in[10];
    const float* W2 = (const float*)d_in[11];
    const float* al2 = (const float*)d_in[12];
    const float* ar2 = (const float*)d_in[13];
    const float* b2 = (const float*)d_in[14];
    float* out = (float*)d_out;

    const int N = in_sizes[0] / 128;  // 100000
    const int E = in_sizes[1];        // 1600000
    const int nbN = (N + 255) / 256;
    const int nbE = (E + 255) / 256;

    char* w = (char*)d_ws;
    int* cnt = (int*)w;        w += alignup((size_t)N * 4);
    int* rowptr = (int*)w;     w += alignup((size_t)(N + 1) * 4);
    int* nxt = (int*)w;        w += alignup((size_t)N * 4);
    int* bsum = (int*)w;       w += alignup(512 * 4);
    int* colx = (int*)w;       w += alignup((size_t)E * 4);
    float* ft = (float*)w;     w += alignup((size_t)N * 128 * 4);
    float* hbuf = (float*)w;   w += alignup((size_t)N * 128 * 4);
    float* el = (float*)w;     w += alignup((size_t)N * 4 * 4);
    float* er = (float*)w;     w += alignup((size_t)N * 4 * 4);
    int* cmat = (int*)w;       w += alignup((size_t)256 * nbN * 4);
    int* rowtot = (int*)w;     w += alignup(256 * 4);
    int* binbase = (int*)w;    w += alignup(256 * 4);
    int* perm = (int*)w;       w += alignup((size_t)N * 4);

    // CSR build
    hipMemsetAsync(cnt, 0, (size_t)N * 4, stream);
    count_deg<<<nbE, 256, 0, stream>>>(dst, cnt, E);
    scan_block<<<nbN, 256, 0, stream>>>(cnt, rowptr, bsum, N);
    scan_partials<<<1, 512, 0, stream>>>(bsum, nbN);
    scan_add<<<nbN, 256, 0, stream>>>(rowptr, bsum, cnt, nxt, N);
    fill_csr<<<nbE, 256, 0, stream>>>(src, dst, nxt, colx, E);

    // degree-sorted schedule (atomic-free counting sort, descending)
    block_hist<<<nbN, 256, 0, stream>>>(cnt, cmat, N, nbN);
    row_scan<<<256, 512, 0, stream>>>(cmat, rowtot, nbN);
    bin_base<<<1, 256, 0, stream>>>(rowtot, binbase);
    bin_scatter2<<<nbN, 256, 0, stream>>>(cnt, cmat, binbase, perm, N, nbN);

    const int gGemm = (N + 127) / 128;
    const int gAgg8 = (N + 7) / 8;    // F=128: 2 nodes/wave, 4 waves
    const int gAgg16 = (N + 15) / 16; // F=64:  4 nodes/wave, 4 waves

    // Layer 0
    gemm_ft<128, 4><<<gGemm, 256, 0, stream>>>(features, W0, al0, ar0, ft, el, er, N);
    gat_aggregate<128, 4, true><<<gAgg8, 256, 0, stream>>>(perm, rowptr, colx, ft, el, er, b0, hbuf, N);

    // Layer 1
    gemm_ft<128, 4><<<gGemm, 256, 0, stream>>>(hbuf, W1, al1, ar1, ft, el, er, N);
    gat_aggregate<128, 4, true><<<gAgg8, 256, 0, stream>>>(perm, rowptr, colx, ft, el, er, b1, hbuf, N);

    // Layer 2
    gemm_ft<64, 1><<<gGemm, 256, 0, stream>>>(hbuf, W2, al2, ar2, ft, el, er, N);
    gat_aggregate<64, 1, false><<<gAgg16, 256, 0, stream>>>(perm, rowptr, colx, ft, el, er, b2, out, N);
}

// Round 8
// 668.663 us; speedup vs baseline: 1.7990x; 1.0250x over previous
//
#include <hip/hip_runtime.h>
#include <hip/hip_bf16.h>
#include <math.h>

// ---------------------------------------------------------------------------
// GAT (3-layer, DGL-style) on MI355X.
// CSR build -> per layer:
//   gemm_ft: double-buffered K-tiled fp32 register GEMM, fused el/er.
//   edge_pe: edge-parallel pass computing pe[e] = exp(leaky(el[src]+er[dst]))
//            (massive TLP; removes attention math from the gather loop).
//   gat_aggregate: lean gather-accumulate, 2 nodes/wave (F=128) or 4
//            (F=64), depth-2 software-pipelined 4-edge batches (issue next
//            batch's gathers before computing current), masked tail.
// Normalization (1/sum pe) applied once at the end -> identical to softmax.
// ---------------------------------------------------------------------------

constexpr int KDIM = 128;

// ---------------- CSR build ----------------

__global__ __launch_bounds__(256) void count_deg(const int* __restrict__ dst,
                                                 int* __restrict__ cnt, int E) {
    int e = blockIdx.x * 256 + threadIdx.x;
    if (e < E) atomicAdd(&cnt[dst[e]], 1);
}

__global__ __launch_bounds__(256) void scan_block(const int* __restrict__ cnt,
                                                  int* __restrict__ rowptr,
                                                  int* __restrict__ bsum, int n) {
    __shared__ int sh[256];
    int i = blockIdx.x * 256 + threadIdx.x;
    int v = (i < n) ? cnt[i] : 0;
    sh[threadIdx.x] = v;
    __syncthreads();
    for (int off = 1; off < 256; off <<= 1) {
        int t = (threadIdx.x >= off) ? sh[threadIdx.x - off] : 0;
        __syncthreads();
        sh[threadIdx.x] += t;
        __syncthreads();
    }
    if (i < n) rowptr[i + 1] = sh[threadIdx.x];
    if (threadIdx.x == 255) bsum[blockIdx.x] = sh[255];
}

__global__ __launch_bounds__(512) void scan_partials(int* __restrict__ bsum, int nb) {
    __shared__ int sh[512];
    int tid = threadIdx.x;
    int v = (tid < nb) ? bsum[tid] : 0;
    sh[tid] = v;
    __syncthreads();
    for (int off = 1; off < 512; off <<= 1) {
        int t = (tid >= off) ? sh[tid - off] : 0;
        __syncthreads();
        sh[tid] += t;
        __syncthreads();
    }
    if (tid < nb) bsum[tid] = sh[tid] - v;  // exclusive
}

__global__ __launch_bounds__(256) void scan_add(int* __restrict__ rowptr,
                                                const int* __restrict__ bsum,
                                                const int* __restrict__ cnt,
                                                int* __restrict__ nxt, int n) {
    int i = blockIdx.x * 256 + threadIdx.x;
    if (i < n) {
        int r = rowptr[i + 1] + bsum[blockIdx.x];
        rowptr[i + 1] = r;
        nxt[i] = r - cnt[i];
        if (i == 0) rowptr[0] = 0;
    }
}

__global__ __launch_bounds__(256) void fill_csr(const int* __restrict__ src,
                                                const int* __restrict__ dst,
                                                int* __restrict__ nxt,
                                                int* __restrict__ colx,
                                                int* __restrict__ dste, int E) {
    int e = blockIdx.x * 256 + threadIdx.x;
    if (e < E) {
        int d = dst[e];
        int pos = atomicAdd(&nxt[d], 1);
        colx[pos] = src[e];
        dste[pos] = d;
    }
}

// ---------------- GEMM + attention logits (double-buffered) ----------------

template <int FOUT, int H>
__global__ __launch_bounds__(256) void gemm_ft(
    const float* __restrict__ hin, const float* __restrict__ W,
    const float* __restrict__ al, const float* __restrict__ ar,
    float* __restrict__ ft, float* __restrict__ el, float* __restrict__ er,
    int nnodes) {
    constexpr int BK = 32;
    constexpr int LDH = 132;                   // padded, mult of 4
    constexpr int TN = (FOUT == 128) ? 8 : 4;  // cols per thread
    constexpr int WCH = BK * FOUT / 1024;      // float4 staging iters: 4 or 2

    __shared__ float ht[2][BK * LDH];   // 2 x 16.9 KB
    __shared__ float Ws[2][BK * FOUT];  // 2 x 16 / 8 KB

    const int tid = threadIdx.x;
    const int nb = blockIdx.x * 128;
    const int tc = tid & 15, row = tid >> 4;
    const int nl = tid >> 3;       // 0..31
    const int kq = (tid & 7) * 4;  // 0,4,..,28

    float4 hreg[4];
    float4 wreg[WCH];

    auto load_chunk = [&](int k0) {
#pragma unroll
        for (int it = 0; it < 4; ++it) {
            int n = nb + nl + it * 32;
            hreg[it] = (n < nnodes)
                           ? *(const float4*)&hin[(size_t)n * KDIM + k0 + kq]
                           : make_float4(0.f, 0.f, 0.f, 0.f);
        }
        const float4* Wg = (const float4*)&W[(size_t)k0 * FOUT];
#pragma unroll
        for (int it = 0; it < WCH; ++it) wreg[it] = Wg[tid + it * 256];
    };
    auto store_chunk = [&](int b) {
#pragma unroll
        for (int it = 0; it < 4; ++it) {
            int nn = nl + it * 32;
            ht[b][(kq + 0) * LDH + nn] = hreg[it].x;
            ht[b][(kq + 1) * LDH + nn] = hreg[it].y;
            ht[b][(kq + 2) * LDH + nn] = hreg[it].z;
            ht[b][(kq + 3) * LDH + nn] = hreg[it].w;
        }
#pragma unroll
        for (int it = 0; it < WCH; ++it)
            ((float4*)Ws[b])[tid + it * 256] = wreg[it];
    };

    float acc[8][TN];
#pragma unroll
    for (int m = 0; m < 8; ++m)
#pragma unroll
        for (int j = 0; j < TN; ++j) acc[m][j] = 0.f;

    load_chunk(0);
    store_chunk(0);
    __syncthreads();

    for (int k0 = 0; k0 < KDIM / BK; ++k0) {
        const int cur = k0 & 1;
        if (k0 < KDIM / BK - 1) load_chunk((k0 + 1) * BK);

#pragma unroll 4
        for (int kk = 0; kk < BK; ++kk) {
            const float* hb = &ht[cur][kk * LDH];
            float4 h0 = *(const float4*)&hb[row * 4];
            float4 h1 = *(const float4*)&hb[64 + row * 4];
            float hv[8] = {h0.x, h0.y, h0.z, h0.w, h1.x, h1.y, h1.z, h1.w};
            const float* wb = &Ws[cur][kk * FOUT];
            float4 w0 = *(const float4*)&wb[tc * 4];
            float wv[TN];
            wv[0] = w0.x; wv[1] = w0.y; wv[2] = w0.z; wv[3] = w0.w;
            if constexpr (FOUT == 128) {
                float4 w1 = *(const float4*)&wb[64 + tc * 4];
                wv[4] = w1.x; wv[5] = w1.y; wv[6] = w1.z; wv[7] = w1.w;
            }
#pragma unroll
            for (int m = 0; m < 8; ++m)
#pragma unroll
                for (int j = 0; j < TN; ++j)
                    acc[m][j] = fmaf(hv[m], wv[j], acc[m][j]);
        }
        if (k0 < KDIM / BK - 1) store_chunk(cur ^ 1);
        __syncthreads();
    }

    float alv[TN], arv[TN];
#pragma unroll
    for (int j = 0; j < 4; ++j) {
        alv[j] = al[tc * 4 + j];
        arv[j] = ar[tc * 4 + j];
    }
    if constexpr (FOUT == 128) {
#pragma unroll
        for (int j = 0; j < 4; ++j) {
            alv[4 + j] = al[64 + tc * 4 + j];
            arv[4 + j] = ar[64 + tc * 4 + j];
        }
    }

#pragma unroll
    for (int m = 0; m < 8; ++m) {
        const int r = (m < 4) ? (row * 4 + m) : (64 + row * 4 + m - 4);
        const int n = nb + r;
        const bool valid = n < nnodes;

        float pl0 = 0.f, pr0 = 0.f, pl1 = 0.f, pr1 = 0.f;
#pragma unroll
        for (int j = 0; j < 4; ++j) {
            pl0 = fmaf(acc[m][j], alv[j], pl0);
            pr0 = fmaf(acc[m][j], arv[j], pr0);
        }
        if constexpr (FOUT == 128) {
#pragma unroll
            for (int j = 0; j < 4; ++j) {
                pl1 = fmaf(acc[m][4 + j], alv[4 + j], pl1);
                pr1 = fmaf(acc[m][4 + j], arv[4 + j], pr1);
            }
        }

        if constexpr (H == 4) {
#pragma unroll
            for (int msk = 1; msk < 8; msk <<= 1) {
                pl0 += __shfl_xor(pl0, msk);
                pr0 += __shfl_xor(pr0, msk);
                pl1 += __shfl_xor(pl1, msk);
                pr1 += __shfl_xor(pr1, msk);
            }
            if (valid && (tc == 0 || tc == 8)) {
                int hbase = (tc == 0) ? 0 : 1;
                el[(size_t)n * 4 + hbase] = pl0;
                er[(size_t)n * 4 + hbase] = pr0;
                el[(size_t)n * 4 + hbase + 2] = pl1;
                er[(size_t)n * 4 + hbase + 2] = pr1;
            }
        } else {
#pragma unroll
            for (int msk = 1; msk < 16; msk <<= 1) {
                pl0 += __shfl_xor(pl0, msk);
                pr0 += __shfl_xor(pr0, msk);
            }
            if (valid && tc == 0) {
                el[n] = pl0;
                er[n] = pr0;
            }
        }

        if (valid) {
            *(float4*)&ft[(size_t)n * FOUT + tc * 4] =
                make_float4(acc[m][0], acc[m][1], acc[m][2], acc[m][3]);
            if constexpr (FOUT == 128)
                *(float4*)&ft[(size_t)n * FOUT + 64 + tc * 4] =
                    make_float4(acc[m][4], acc[m][5], acc[m][6], acc[m][7]);
        }
    }
}

// ---------------- edge-parallel attention weights ----------------
// pe[e][h] = exp(leaky_relu(el[src_e][h] + er[dst_e][h])). One thread/edge.

template <int H>
__global__ __launch_bounds__(256) void edge_pe(
    const int* __restrict__ colx, const int* __restrict__ dste,
    const float* __restrict__ el, const float* __restrict__ er,
    float* __restrict__ pe, int E) {
    int e = blockIdx.x * 256 + threadIdx.x;
    if (e >= E) return;
    int sn = colx[e], d = dste[e];
    if constexpr (H == 4) {
        float4 l = *(const float4*)&el[(size_t)sn * 4];
        float4 r = *(const float4*)&er[(size_t)d * 4];
        float x0 = l.x + r.x, x1 = l.y + r.y, x2 = l.z + r.z, x3 = l.w + r.w;
        x0 = fmaxf(x0, 0.2f * x0);
        x1 = fmaxf(x1, 0.2f * x1);
        x2 = fmaxf(x2, 0.2f * x2);
        x3 = fmaxf(x3, 0.2f * x3);
        *(float4*)&pe[(size_t)e * 4] =
            make_float4(__expf(x0), __expf(x1), __expf(x2), __expf(x3));
    } else {
        float x = el[sn] + er[d];
        x = fmaxf(x, 0.2f * x);
        pe[e] = __expf(x);
    }
}

// ---------------- gather-accumulate aggregation ----------------
// F=128: 2 nodes/wave (32 lanes, 4 cols/lane). F=64: 4 nodes/wave (16 lanes).
// Depth-2 pipelined 4-edge batches: issue next batch's gathers before
// computing current batch. Masked tail (idx=-1 -> p=0, gather ft[0] row
// which stays L1-hot). out = (sum pe*ft)/(sum pe) + bias.

template <int F, int H, bool RELU>
__global__ __launch_bounds__(256) void gat_aggregate(
    const int* __restrict__ rowptr, const int* __restrict__ colx,
    const float* __restrict__ pe, const float* __restrict__ ft,
    const float* __restrict__ bias, float* __restrict__ out, int nnodes) {
    constexpr int LPG = (F == 128) ? 32 : 16;  // lanes per node group
    constexpr int NPW = 64 / LPG;              // nodes per wave
    const int tid = threadIdx.x, wv = tid >> 6, lane = tid & 63;
    const int grp = lane / LPG, sub = lane % LPG;
    const int n = blockIdx.x * (4 * NPW) + wv * NPW + grp;
    const bool valid = n < nnodes;
    const int nn = valid ? n : 0;

    const int start = rowptr[nn];
    const int end = valid ? rowptr[nn + 1] : start;
    int md = end - start;
    if constexpr (NPW == 4) md = max(md, __shfl_xor(md, 16));
    md = max(md, __shfl_xor(md, 32));
    const int nit = (md + 7) / 8;

    const int head = (H == 4) ? (sub >> 3) : 0;

    float s = 0.f;
    float acc[4] = {0.f, 0.f, 0.f, 0.f};

    int idxA[4], idxB[4];
    float pA[4], pB[4];
    float4 fA[4], fB[4];

    auto issue = [&](int (&idxX)[4], float (&pX)[4], float4 (&fX)[4], int e0) {
#pragma unroll
        for (int i = 0; i < 4; ++i) {
            int ee = e0 + i;
            idxX[i] = (ee < end) ? colx[ee] : -1;
        }
#pragma unroll
        for (int i = 0; i < 4; ++i) {
            int ee = e0 + i;
            int pee = (ee < end) ? ee : start;
            if constexpr (H == 4)
                pX[i] = pe[(size_t)pee * 4 + head];
            else
                pX[i] = pe[pee];
            int sn = (idxX[i] < 0) ? 0 : idxX[i];
            fX[i] = *(const float4*)&ft[(size_t)sn * F + sub * 4];
        }
    };
    auto compute = [&](int (&idxX)[4], float (&pX)[4], float4 (&fX)[4]) {
#pragma unroll
        for (int i = 0; i < 4; ++i) {
            float p = (idxX[i] >= 0) ? pX[i] : 0.f;
            s += p;
            acc[0] = fmaf(p, fX[i].x, acc[0]);
            acc[1] = fmaf(p, fX[i].y, acc[1]);
            acc[2] = fmaf(p, fX[i].z, acc[2]);
            acc[3] = fmaf(p, fX[i].w, acc[3]);
        }
    };

    int e0 = start;
    issue(idxA, pA, fA, e0);
    for (int it = 0; it < nit; ++it) {
        issue(idxB, pB, fB, e0 + 4);   // batch k+1 in flight
        compute(idxA, pA, fA);         // consume batch k
        issue(idxA, pA, fA, e0 + 8);   // batch k+2 in flight
        compute(idxB, pB, fB);         // consume batch k+1
        e0 += 8;
    }

    if (!valid) return;
    float inv = 1.0f / s;  // deg >= 1 guaranteed
    float4 b4 = *(const float4*)&bias[sub * 4];
    float o0 = acc[0] * inv + b4.x, o1 = acc[1] * inv + b4.y;
    float o2 = acc[2] * inv + b4.z, o3 = acc[3] * inv + b4.w;
    if (RELU) {
        o0 = fmaxf(o0, 0.f); o1 = fmaxf(o1, 0.f);
        o2 = fmaxf(o2, 0.f); o3 = fmaxf(o3, 0.f);
    }
    *(float4*)&out[(size_t)n * F + sub * 4] = make_float4(o0, o1, o2, o3);
}

// ---------------- host launch ----------------

static inline size_t alignup(size_t x) { return (x + 255) & ~(size_t)255; }

extern "C" void kernel_launch(void* const* d_in, const int* in_sizes, int n_in,
                              void* d_out, int out_size, void* d_ws, size_t ws_size,
                              hipStream_t stream) {
    const float* features = (const float*)d_in[0];
    const int* src = (const int*)d_in[1];
    const int* dst = (const int*)d_in[2];
    const float* W0 = (const float*)d_in[3];
    const float* al0 = (const float*)d_in[4];
    const float* ar0 = (const float*)d_in[5];
    const float* b0 = (const float*)d_in[6];
    const float* W1 = (const float*)d_in[7];
    const float* al1 = (const float*)d_in[8];
    const float* ar1 = (const float*)d_in[9];
    const float* b1 = (const float*)d_in[10];
    const float* W2 = (const float*)d_in[11];
    const float* al2 = (const float*)d_in[12];
    const float* ar2 = (const float*)d_in[13];
    const float* b2 = (const float*)d_in[14];
    float* out = (float*)d_out;

    const int N = in_sizes[0] / 128;  // 100000
    const int E = in_sizes[1];        // 1600000
    const int nbN = (N + 255) / 256;
    const int nbE = (E + 255) / 256;

    char* w = (char*)d_ws;
    int* cnt = (int*)w;        w += alignup((size_t)N * 4);
    int* rowptr = (int*)w;     w += alignup((size_t)(N + 1) * 4);
    int* nxt = (int*)w;        w += alignup((size_t)N * 4);
    int* bsum = (int*)w;       w += alignup(512 * 4);
    int* colx = (int*)w;       w += alignup((size_t)E * 4);
    int* dste = (int*)w;       w += alignup((size_t)E * 4);
    float* ft = (float*)w;     w += alignup((size_t)N * 128 * 4);
    float* hbuf = (float*)w;   w += alignup((size_t)N * 128 * 4);
    float* el = (float*)w;     w += alignup((size_t)N * 4 * 4);
    float* er = (float*)w;     w += alignup((size_t)N * 4 * 4);
    float* pe = (float*)w;     w += alignup((size_t)E * 4 * 4);

    // CSR build
    hipMemsetAsync(cnt, 0, (size_t)N * 4, stream);
    count_deg<<<nbE, 256, 0, stream>>>(dst, cnt, E);
    scan_block<<<nbN, 256, 0, stream>>>(cnt, rowptr, bsum, N);
    scan_partials<<<1, 512, 0, stream>>>(bsum, nbN);
    scan_add<<<nbN, 256, 0, stream>>>(rowptr, bsum, cnt, nxt, N);
    fill_csr<<<nbE, 256, 0, stream>>>(src, dst, nxt, colx, dste, E);

    const int gGemm = (N + 127) / 128;
    const int gAgg8 = (N + 7) / 8;    // F=128: 2 nodes/wave, 4 waves
    const int gAgg16 = (N + 15) / 16; // F=64:  4 nodes/wave, 4 waves

    // Layer 0
    gemm_ft<128, 4><<<gGemm, 256, 0, stream>>>(features, W0, al0, ar0, ft, el, er, N);
    edge_pe<4><<<nbE, 256, 0, stream>>>(colx, dste, el, er, pe, E);
    gat_aggregate<128, 4, true><<<gAgg8, 256, 0, stream>>>(rowptr, colx, pe, ft, b0, hbuf, N);

    // Layer 1
    gemm_ft<128, 4><<<gGemm, 256, 0, stream>>>(hbuf, W1, al1, ar1, ft, el, er, N);
    edge_pe<4><<<nbE, 256, 0, stream>>>(colx, dste, el, er, pe, E);
    gat_aggregate<128, 4, true><<<gAgg8, 256, 0, stream>>>(rowptr, colx, pe, ft, b1, hbuf, N);

    // Layer 2
    gemm_ft<64, 1><<<gGemm, 256, 0, stream>>>(hbuf, W2, al2, ar2, ft, el, er, N);
    edge_pe<1><<<nbE, 256, 0, stream>>>(colx, dste, el, er, pe, E);
    gat_aggregate<64, 1, false><<<gAgg16, 256, 0, stream>>>(rowptr, colx, pe, ft, b2, out, N);
}

// Round 9
// 630.222 us; speedup vs baseline: 1.9087x; 1.0610x over previous
//
#include <hip/hip_runtime.h>
#include <hip/hip_bf16.h>
#include <hip/hip_fp16.h>
#include <math.h>

// ---------------------------------------------------------------------------
// GAT (3-layer, DGL-style) on MI355X.
// CSR build (colx only; single scattered store per edge) -> per layer:
//   gemm_ft: double-buffered K-tiled fp32 register GEMM, fused el/er.
//            Layers 0/1 store ft as fp16 (halves aggregate gather traffic);
//            layer 2 stores fp32.
//   node_pe: node-parallel pe[e][h] = exp(leaky(el[src]+er[dst])) (dst
//            implicit from CSR range -> no dste array needed).
//   gat_aggregate: lean gather-accumulate, 2 nodes/wave (F=128) or 4
//            (F=64), depth-2 software-pipelined 4-edge batches, masked tail.
// Normalization (1/sum pe) applied once at the end -> identical to softmax.
// ---------------------------------------------------------------------------

constexpr int KDIM = 128;

// ---------------- CSR build ----------------

__global__ __launch_bounds__(256) void count_deg(const int* __restrict__ dst,
                                                 int* __restrict__ cnt, int E) {
    int e = blockIdx.x * 256 + threadIdx.x;
    if (e < E) atomicAdd(&cnt[dst[e]], 1);
}

__global__ __launch_bounds__(256) void scan_block(const int* __restrict__ cnt,
                                                  int* __restrict__ rowptr,
                                                  int* __restrict__ bsum, int n) {
    __shared__ int sh[256];
    int i = blockIdx.x * 256 + threadIdx.x;
    int v = (i < n) ? cnt[i] : 0;
    sh[threadIdx.x] = v;
    __syncthreads();
    for (int off = 1; off < 256; off <<= 1) {
        int t = (threadIdx.x >= off) ? sh[threadIdx.x - off] : 0;
        __syncthreads();
        sh[threadIdx.x] += t;
        __syncthreads();
    }
    if (i < n) rowptr[i + 1] = sh[threadIdx.x];
    if (threadIdx.x == 255) bsum[blockIdx.x] = sh[255];
}

__global__ __launch_bounds__(512) void scan_partials(int* __restrict__ bsum, int nb) {
    __shared__ int sh[512];
    int tid = threadIdx.x;
    int v = (tid < nb) ? bsum[tid] : 0;
    sh[tid] = v;
    __syncthreads();
    for (int off = 1; off < 512; off <<= 1) {
        int t = (tid >= off) ? sh[tid - off] : 0;
        __syncthreads();
        sh[tid] += t;
        __syncthreads();
    }
    if (tid < nb) bsum[tid] = sh[tid] - v;  // exclusive
}

__global__ __launch_bounds__(256) void scan_add(int* __restrict__ rowptr,
                                                const int* __restrict__ bsum,
                                                const int* __restrict__ cnt,
                                                int* __restrict__ nxt, int n) {
    int i = blockIdx.x * 256 + threadIdx.x;
    if (i < n) {
        int r = rowptr[i + 1] + bsum[blockIdx.x];
        rowptr[i + 1] = r;
        nxt[i] = r - cnt[i];
        if (i == 0) rowptr[0] = 0;
    }
}

__global__ __launch_bounds__(256) void fill_csr(const int* __restrict__ src,
                                                const int* __restrict__ dst,
                                                int* __restrict__ nxt,
                                                int* __restrict__ colx, int E) {
    int e = blockIdx.x * 256 + threadIdx.x;
    if (e < E) {
        int d = dst[e];
        int pos = atomicAdd(&nxt[d], 1);
        colx[pos] = src[e];
    }
}

// ---------------- GEMM + attention logits (double-buffered) ----------------

template <int FOUT, int H, bool HOUT>
__global__ __launch_bounds__(256) void gemm_ft(
    const float* __restrict__ hin, const float* __restrict__ W,
    const float* __restrict__ al, const float* __restrict__ ar,
    void* __restrict__ ftout, float* __restrict__ el, float* __restrict__ er,
    int nnodes) {
    constexpr int BK = 32;
    constexpr int LDH = 132;                   // padded, mult of 4
    constexpr int TN = (FOUT == 128) ? 8 : 4;  // cols per thread
    constexpr int WCH = BK * FOUT / 1024;      // float4 staging iters: 4 or 2

    __shared__ float ht[2][BK * LDH];   // 2 x 16.9 KB
    __shared__ float Ws[2][BK * FOUT];  // 2 x 16 / 8 KB

    const int tid = threadIdx.x;
    const int nb = blockIdx.x * 128;
    const int tc = tid & 15, row = tid >> 4;
    const int nl = tid >> 3;       // 0..31
    const int kq = (tid & 7) * 4;  // 0,4,..,28

    float4 hreg[4];
    float4 wreg[WCH];

    auto load_chunk = [&](int k0) {
#pragma unroll
        for (int it = 0; it < 4; ++it) {
            int n = nb + nl + it * 32;
            hreg[it] = (n < nnodes)
                           ? *(const float4*)&hin[(size_t)n * KDIM + k0 + kq]
                           : make_float4(0.f, 0.f, 0.f, 0.f);
        }
        const float4* Wg = (const float4*)&W[(size_t)k0 * FOUT];
#pragma unroll
        for (int it = 0; it < WCH; ++it) wreg[it] = Wg[tid + it * 256];
    };
    auto store_chunk = [&](int b) {
#pragma unroll
        for (int it = 0; it < 4; ++it) {
            int nn = nl + it * 32;
            ht[b][(kq + 0) * LDH + nn] = hreg[it].x;
            ht[b][(kq + 1) * LDH + nn] = hreg[it].y;
            ht[b][(kq + 2) * LDH + nn] = hreg[it].z;
            ht[b][(kq + 3) * LDH + nn] = hreg[it].w;
        }
#pragma unroll
        for (int it = 0; it < WCH; ++it)
            ((float4*)Ws[b])[tid + it * 256] = wreg[it];
    };

    float acc[8][TN];
#pragma unroll
    for (int m = 0; m < 8; ++m)
#pragma unroll
        for (int j = 0; j < TN; ++j) acc[m][j] = 0.f;

    load_chunk(0);
    store_chunk(0);
    __syncthreads();

    for (int k0 = 0; k0 < KDIM / BK; ++k0) {
        const int cur = k0 & 1;
        if (k0 < KDIM / BK - 1) load_chunk((k0 + 1) * BK);

#pragma unroll 4
        for (int kk = 0; kk < BK; ++kk) {
            const float* hb = &ht[cur][kk * LDH];
            float4 h0 = *(const float4*)&hb[row * 4];
            float4 h1 = *(const float4*)&hb[64 + row * 4];
            float hv[8] = {h0.x, h0.y, h0.z, h0.w, h1.x, h1.y, h1.z, h1.w};
            const float* wb = &Ws[cur][kk * FOUT];
            float4 w0 = *(const float4*)&wb[tc * 4];
            float wv[TN];
            wv[0] = w0.x; wv[1] = w0.y; wv[2] = w0.z; wv[3] = w0.w;
            if constexpr (FOUT == 128) {
                float4 w1 = *(const float4*)&wb[64 + tc * 4];
                wv[4] = w1.x; wv[5] = w1.y; wv[6] = w1.z; wv[7] = w1.w;
            }
#pragma unroll
            for (int m = 0; m < 8; ++m)
#pragma unroll
                for (int j = 0; j < TN; ++j)
                    acc[m][j] = fmaf(hv[m], wv[j], acc[m][j]);
        }
        if (k0 < KDIM / BK - 1) store_chunk(cur ^ 1);
        __syncthreads();
    }

    float alv[TN], arv[TN];
#pragma unroll
    for (int j = 0; j < 4; ++j) {
        alv[j] = al[tc * 4 + j];
        arv[j] = ar[tc * 4 + j];
    }
    if constexpr (FOUT == 128) {
#pragma unroll
        for (int j = 0; j < 4; ++j) {
            alv[4 + j] = al[64 + tc * 4 + j];
            arv[4 + j] = ar[64 + tc * 4 + j];
        }
    }

#pragma unroll
    for (int m = 0; m < 8; ++m) {
        const int r = (m < 4) ? (row * 4 + m) : (64 + row * 4 + m - 4);
        const int n = nb + r;
        const bool valid = n < nnodes;

        float pl0 = 0.f, pr0 = 0.f, pl1 = 0.f, pr1 = 0.f;
#pragma unroll
        for (int j = 0; j < 4; ++j) {
            pl0 = fmaf(acc[m][j], alv[j], pl0);
            pr0 = fmaf(acc[m][j], arv[j], pr0);
        }
        if constexpr (FOUT == 128) {
#pragma unroll
            for (int j = 0; j < 4; ++j) {
                pl1 = fmaf(acc[m][4 + j], alv[4 + j], pl1);
                pr1 = fmaf(acc[m][4 + j], arv[4 + j], pr1);
            }
        }

        if constexpr (H == 4) {
#pragma unroll
            for (int msk = 1; msk < 8; msk <<= 1) {
                pl0 += __shfl_xor(pl0, msk);
                pr0 += __shfl_xor(pr0, msk);
                pl1 += __shfl_xor(pl1, msk);
                pr1 += __shfl_xor(pr1, msk);
            }
            if (valid && (tc == 0 || tc == 8)) {
                int hbase = (tc == 0) ? 0 : 1;
                el[(size_t)n * 4 + hbase] = pl0;
                er[(size_t)n * 4 + hbase] = pr0;
                el[(size_t)n * 4 + hbase + 2] = pl1;
                er[(size_t)n * 4 + hbase + 2] = pr1;
            }
        } else {
#pragma unroll
            for (int msk = 1; msk < 16; msk <<= 1) {
                pl0 += __shfl_xor(pl0, msk);
                pr0 += __shfl_xor(pr0, msk);
            }
            if (valid && tc == 0) {
                el[n] = pl0;
                er[n] = pr0;
            }
        }

        if (valid) {
            if constexpr (HOUT) {
                __half* fth = (__half*)ftout;
                ushort4 u0;
                u0.x = __half_as_ushort(__float2half_rn(acc[m][0]));
                u0.y = __half_as_ushort(__float2half_rn(acc[m][1]));
                u0.z = __half_as_ushort(__float2half_rn(acc[m][2]));
                u0.w = __half_as_ushort(__float2half_rn(acc[m][3]));
                *(ushort4*)&fth[(size_t)n * FOUT + tc * 4] = u0;
                if constexpr (FOUT == 128) {
                    ushort4 u1;
                    u1.x = __half_as_ushort(__float2half_rn(acc[m][4]));
                    u1.y = __half_as_ushort(__float2half_rn(acc[m][5]));
                    u1.z = __half_as_ushort(__float2half_rn(acc[m][6]));
                    u1.w = __half_as_ushort(__float2half_rn(acc[m][7]));
                    *(ushort4*)&fth[(size_t)n * FOUT + 64 + tc * 4] = u1;
                }
            } else {
                float* ftf = (float*)ftout;
                *(float4*)&ftf[(size_t)n * FOUT + tc * 4] =
                    make_float4(acc[m][0], acc[m][1], acc[m][2], acc[m][3]);
                if constexpr (FOUT == 128)
                    *(float4*)&ftf[(size_t)n * FOUT + 64 + tc * 4] =
                        make_float4(acc[m][4], acc[m][5], acc[m][6], acc[m][7]);
            }
        }
    }
}

// ---------------- node-parallel attention weights ----------------
// One thread per dst node loops its CSR range; dst is implicit.
// pe[e][h] = exp(leaky_relu(el[src_e][h] + er[dst][h])).

template <int H>
__global__ __launch_bounds__(256) void node_pe(
    const int* __restrict__ rowptr, const int* __restrict__ colx,
    const float* __restrict__ el, const float* __restrict__ er,
    float* __restrict__ pe, int nnodes) {
    int n = blockIdx.x * 256 + threadIdx.x;
    if (n >= nnodes) return;
    const int s = rowptr[n], e = rowptr[n + 1];
    if constexpr (H == 4) {
        float4 r = *(const float4*)&er[(size_t)n * 4];
        for (int ee = s; ee < e; ++ee) {
            int sn = colx[ee];
            float4 l = *(const float4*)&el[(size_t)sn * 4];
            float x0 = l.x + r.x, x1 = l.y + r.y;
            float x2 = l.z + r.z, x3 = l.w + r.w;
            x0 = fmaxf(x0, 0.2f * x0);
            x1 = fmaxf(x1, 0.2f * x1);
            x2 = fmaxf(x2, 0.2f * x2);
            x3 = fmaxf(x3, 0.2f * x3);
            *(float4*)&pe[(size_t)ee * 4] =
                make_float4(__expf(x0), __expf(x1), __expf(x2), __expf(x3));
        }
    } else {
        float r = er[n];
        for (int ee = s; ee < e; ++ee) {
            float x = el[colx[ee]] + r;
            x = fmaxf(x, 0.2f * x);
            pe[ee] = __expf(x);
        }
    }
}

// ---------------- gather-accumulate aggregation ----------------
// F=128: 2 nodes/wave (32 lanes, 4 cols/lane). F=64: 4 nodes/wave (16 lanes).
// Depth-2 pipelined 4-edge batches. Masked tail (idx=-1 -> p=0).
// HIN: ft stored fp16 (8B/lane/edge). out = (sum pe*ft)/(sum pe) + bias.

template <int F, int H, bool RELU, bool HIN>
__global__ __launch_bounds__(256) void gat_aggregate(
    const int* __restrict__ rowptr, const int* __restrict__ colx,
    const float* __restrict__ pe, const void* __restrict__ ftv,
    const float* __restrict__ bias, float* __restrict__ out, int nnodes) {
    constexpr int LPG = (F == 128) ? 32 : 16;  // lanes per node group
    constexpr int NPW = 64 / LPG;              // nodes per wave
    const int tid = threadIdx.x, wv = tid >> 6, lane = tid & 63;
    const int grp = lane / LPG, sub = lane % LPG;
    const int n = blockIdx.x * (4 * NPW) + wv * NPW + grp;
    const bool valid = n < nnodes;
    const int nn = valid ? n : 0;

    const int start = rowptr[nn];
    const int end = valid ? rowptr[nn + 1] : start;
    int md = end - start;
    if constexpr (NPW == 4) md = max(md, __shfl_xor(md, 16));
    md = max(md, __shfl_xor(md, 32));
    const int nit = (md + 7) / 8;

    const int head = (H == 4) ? (sub >> 3) : 0;

    float s = 0.f;
    float acc[4] = {0.f, 0.f, 0.f, 0.f};

    int idxA[4], idxB[4];
    float pA[4], pB[4];
    float4 fA[4], fB[4];

    auto issue = [&](int (&idxX)[4], float (&pX)[4], float4 (&fX)[4], int e0) {
#pragma unroll
        for (int i = 0; i < 4; ++i) {
            int ee = e0 + i;
            idxX[i] = (ee < end) ? colx[ee] : -1;
        }
#pragma unroll
        for (int i = 0; i < 4; ++i) {
            int ee = e0 + i;
            int pee = (ee < end) ? ee : start;
            if constexpr (H == 4)
                pX[i] = pe[(size_t)pee * 4 + head];
            else
                pX[i] = pe[pee];
            int sn = (idxX[i] < 0) ? 0 : idxX[i];
            if constexpr (HIN) {
                const __half* fth = (const __half*)ftv;
                ushort4 u = *(const ushort4*)&fth[(size_t)sn * F + sub * 4];
                fX[i] = make_float4(__half2float(__ushort_as_half(u.x)),
                                    __half2float(__ushort_as_half(u.y)),
                                    __half2float(__ushort_as_half(u.z)),
                                    __half2float(__ushort_as_half(u.w)));
            } else {
                const float* ftf = (const float*)ftv;
                fX[i] = *(const float4*)&ftf[(size_t)sn * F + sub * 4];
            }
        }
    };
    auto compute = [&](int (&idxX)[4], float (&pX)[4], float4 (&fX)[4]) {
#pragma unroll
        for (int i = 0; i < 4; ++i) {
            float p = (idxX[i] >= 0) ? pX[i] : 0.f;
            s += p;
            acc[0] = fmaf(p, fX[i].x, acc[0]);
            acc[1] = fmaf(p, fX[i].y, acc[1]);
            acc[2] = fmaf(p, fX[i].z, acc[2]);
            acc[3] = fmaf(p, fX[i].w, acc[3]);
        }
    };

    int e0 = start;
    issue(idxA, pA, fA, e0);
    for (int it = 0; it < nit; ++it) {
        issue(idxB, pB, fB, e0 + 4);   // batch k+1 in flight
        compute(idxA, pA, fA);         // consume batch k
        issue(idxA, pA, fA, e0 + 8);   // batch k+2 in flight
        compute(idxB, pB, fB);         // consume batch k+1
        e0 += 8;
    }

    if (!valid) return;
    float inv = 1.0f / s;  // deg >= 1 guaranteed
    float4 b4 = *(const float4*)&bias[sub * 4];
    float o0 = acc[0] * inv + b4.x, o1 = acc[1] * inv + b4.y;
    float o2 = acc[2] * inv + b4.z, o3 = acc[3] * inv + b4.w;
    if (RELU) {
        o0 = fmaxf(o0, 0.f); o1 = fmaxf(o1, 0.f);
        o2 = fmaxf(o2, 0.f); o3 = fmaxf(o3, 0.f);
    }
    *(float4*)&out[(size_t)n * F + sub * 4] = make_float4(o0, o1, o2, o3);
}

// ---------------- host launch ----------------

static inline size_t alignup(size_t x) { return (x + 255) & ~(size_t)255; }

extern "C" void kernel_launch(void* const* d_in, const int* in_sizes, int n_in,
                              void* d_out, int out_size, void* d_ws, size_t ws_size,
                              hipStream_t stream) {
    const float* features = (const float*)d_in[0];
    const int* src = (const int*)d_in[1];
    const int* dst = (const int*)d_in[2];
    const float* W0 = (const float*)d_in[3];
    const float* al0 = (const float*)d_in[4];
    const float* ar0 = (const float*)d_in[5];
    const float* b0 = (const float*)d_in[6];
    const float* W1 = (const float*)d_in[7];
    const float* al1 = (const float*)d_in[8];
    const float* ar1 = (const float*)d_in[9];
    const float* b1 = (const float*)d_in[10];
    const float* W2 = (const float*)d_in[11];
    const float* al2 = (const float*)d_in[12];
    const float* ar2 = (const float*)d_in[13];
    const float* b2 = (const float*)d_in[14];
    float* out = (float*)d_out;

    const int N = in_sizes[0] / 128;  // 100000
    const int E = in_sizes[1];        // 1600000
    const int nbN = (N + 255) / 256;
    const int nbE = (E + 255) / 256;

    char* w = (char*)d_ws;
    int* cnt = (int*)w;        w += alignup((size_t)N * 4);
    int* rowptr = (int*)w;     w += alignup((size_t)(N + 1) * 4);
    int* nxt = (int*)w;        w += alignup((size_t)N * 4);
    int* bsum = (int*)w;       w += alignup(512 * 4);
    int* colx = (int*)w;       w += alignup((size_t)E * 4);
    float* ft32 = (float*)w;   w += alignup((size_t)N * 64 * 4);
    __half* ft16 = (__half*)w; w += alignup((size_t)N * 128 * 2);
    float* hbuf = (float*)w;   w += alignup((size_t)N * 128 * 4);
    float* el = (float*)w;     w += alignup((size_t)N * 4 * 4);
    float* er = (float*)w;     w += alignup((size_t)N * 4 * 4);
    float* pe = (float*)w;     w += alignup((size_t)E * 4 * 4);

    // CSR build
    hipMemsetAsync(cnt, 0, (size_t)N * 4, stream);
    count_deg<<<nbE, 256, 0, stream>>>(dst, cnt, E);
    scan_block<<<nbN, 256, 0, stream>>>(cnt, rowptr, bsum, N);
    scan_partials<<<1, 512, 0, stream>>>(bsum, nbN);
    scan_add<<<nbN, 256, 0, stream>>>(rowptr, bsum, cnt, nxt, N);
    fill_csr<<<nbE, 256, 0, stream>>>(src, dst, nxt, colx, E);

    const int gGemm = (N + 127) / 128;
    const int gAgg8 = (N + 7) / 8;    // F=128: 2 nodes/wave, 4 waves
    const int gAgg16 = (N + 15) / 16; // F=64:  4 nodes/wave, 4 waves

    // Layer 0
    gemm_ft<128, 4, true><<<gGemm, 256, 0, stream>>>(features, W0, al0, ar0, ft16, el, er, N);
    node_pe<4><<<nbN, 256, 0, stream>>>(rowptr, colx, el, er, pe, N);
    gat_aggregate<128, 4, true, true><<<gAgg8, 256, 0, stream>>>(rowptr, colx, pe, ft16, b0, hbuf, N);

    // Layer 1
    gemm_ft<128, 4, true><<<gGemm, 256, 0, stream>>>(hbuf, W1, al1, ar1, ft16, el, er, N);
    node_pe<4><<<nbN, 256, 0, stream>>>(rowptr, colx, el, er, pe, N);
    gat_aggregate<128, 4, true, true><<<gAgg8, 256, 0, stream>>>(rowptr, colx, pe, ft16, b1, hbuf, N);

    // Layer 2
    gemm_ft<64, 1, false><<<gGemm, 256, 0, stream>>>(hbuf, W2, al2, ar2, ft32, el, er, N);
    node_pe<1><<<nbN, 256, 0, stream>>>(rowptr, colx, el, er, pe, N);
    gat_aggregate<64, 1, false, false><<<gAgg16, 256, 0, stream>>>(rowptr, colx, pe, ft32, b2, out, N);
}

// Round 10
// 490.798 us; speedup vs baseline: 2.4509x; 1.2841x over previous
//
#include <hip/hip_runtime.h>
#include <hip/hip_bf16.h>
#include <hip/hip_fp16.h>
#include <math.h>

// ---------------------------------------------------------------------------
// GAT (3-layer, DGL-style) on MI355X.
// CSR build via bucketed counting sort (no global atomics, coalesced writes):
//   ehist -> bscan/bbase -> escatter (LDS local sort) -> bucket_fill
//   (rowptr + colx built per 512-node bucket inside a 32KB L2-merged window).
// Per layer:
//   gemm_ft: double-buffered K-tiled fp32 register GEMM, fused el/er.
//            Layers 0/1 store ft as fp16; layer 2 fp32.
//   node_pe: node-parallel pe[e][h] = exp(leaky(el[src]+er[dst])).
//   gat_aggregate: lean gather-accumulate, depth-2 pipelined 4-edge batches.
// Normalization (1/sum pe) applied once at the end -> identical to softmax.
// ---------------------------------------------------------------------------

constexpr int KDIM = 128;
constexpr int BSH = 9;            // bucket shift: 512 nodes per bucket
constexpr int EPB = 4096;         // edges per sort block

// ---------------- CSR build: bucketed counting sort ----------------

__global__ __launch_bounds__(256) void ehist(const int* __restrict__ dst,
                                             int* __restrict__ cmat,
                                             int E, int nebs) {
    __shared__ int lh[256];
    const int t = threadIdx.x;
    lh[t] = 0;
    __syncthreads();
    const int base = blockIdx.x * EPB;
    const int cntE = min(EPB, E - base);
    for (int i = t; i < cntE; i += 256) atomicAdd(&lh[dst[base + i] >> BSH], 1);
    __syncthreads();
    cmat[t * nebs + blockIdx.x] = lh[t];  // bucket-major
}

__global__ __launch_bounds__(512) void bscan(int* __restrict__ cmat,
                                             int* __restrict__ rowtot, int nebs) {
    __shared__ int sh[512];
    const int b = blockIdx.x, t = threadIdx.x;
    int v = (t < nebs) ? cmat[b * nebs + t] : 0;
    sh[t] = v;
    __syncthreads();
    for (int off = 1; off < 512; off <<= 1) {
        int u = (t >= off) ? sh[t - off] : 0;
        __syncthreads();
        sh[t] += u;
        __syncthreads();
    }
    if (t < nebs) cmat[b * nebs + t] = sh[t] - v;  // exclusive over blocks
    if (t == 511) rowtot[b] = sh[511];
}

__global__ __launch_bounds__(256) void bbase_scan(const int* __restrict__ rowtot,
                                                  int* __restrict__ bbase) {
    __shared__ int sh[256];
    const int t = threadIdx.x;
    int v = rowtot[t];
    sh[t] = v;
    __syncthreads();
    for (int off = 1; off < 256; off <<= 1) {
        int u = (t >= off) ? sh[t - off] : 0;
        __syncthreads();
        sh[t] += u;
        __syncthreads();
    }
    bbase[t] = sh[t] - v;  // exclusive (ascending buckets)
}

__global__ __launch_bounds__(256) void escatter(
    const int* __restrict__ src, const int* __restrict__ dst,
    const int* __restrict__ cmat, const int* __restrict__ bbase,
    unsigned long long* __restrict__ ebuf, int E, int nebs) {
    __shared__ unsigned long long sbuf[EPB];  // 32 KB
    __shared__ int lh[256], lstart[256], lcur[256];
    const int t = threadIdx.x;
    const int base = blockIdx.x * EPB;
    const int cntE = min(EPB, E - base);

    lh[t] = 0;
    __syncthreads();
    for (int i = t; i < cntE; i += 256) atomicAdd(&lh[dst[base + i] >> BSH], 1);
    __syncthreads();
    // exclusive scan of lh
    {
        __shared__ int sh[256];
        int v = lh[t];
        sh[t] = v;
        __syncthreads();
        for (int off = 1; off < 256; off <<= 1) {
            int u = (t >= off) ? sh[t - off] : 0;
            __syncthreads();
            sh[t] += u;
            __syncthreads();
        }
        lstart[t] = sh[t] - v;
        lcur[t] = sh[t] - v;
    }
    __syncthreads();
    // place into sbuf grouped by bucket
    for (int i = t; i < cntE; i += 256) {
        int d = dst[base + i], s = src[base + i];
        int r = atomicAdd(&lcur[d >> BSH], 1);
        sbuf[r] = ((unsigned long long)d << 32) | (unsigned int)s;
    }
    __syncthreads();
    // write runs out (coalesced within each bucket run)
    for (int j = t; j < cntE; j += 256) {
        unsigned long long v = sbuf[j];
        int bk = (int)(v >> 32) >> BSH;
        int gpos = bbase[bk] + cmat[bk * nebs + blockIdx.x] + (j - lstart[bk]);
        ebuf[gpos] = v;
    }
}

__global__ __launch_bounds__(512) void bucket_fill(
    const unsigned long long* __restrict__ ebuf, const int* __restrict__ bbase,
    int* __restrict__ rowptr, int* __restrict__ colx, int N, int E, int nbuck) {
    __shared__ int cnt[512], nxtl[512], sh[512];
    const int b = blockIdx.x, t = threadIdx.x;
    const int nodebase = b << BSH;
    const int nn = min(512, N - nodebase);
    const int estart = bbase[b];
    const int eend = (b + 1 < 256) ? bbase[b + 1] : E;

    cnt[t] = 0;
    __syncthreads();
    for (int i = estart + t; i < eend; i += 512)
        atomicAdd(&cnt[(int)(ebuf[i] >> 32) - nodebase], 1);
    __syncthreads();
    // inclusive scan over 512
    int v = cnt[t];
    sh[t] = v;
    __syncthreads();
    for (int off = 1; off < 512; off <<= 1) {
        int u = (t >= off) ? sh[t - off] : 0;
        __syncthreads();
        sh[t] += u;
        __syncthreads();
    }
    if (t < nn) rowptr[nodebase + t + 1] = estart + sh[t];
    if (b == 0 && t == 0) rowptr[0] = 0;
    nxtl[t] = estart + sh[t] - v;  // exclusive start cursor
    __syncthreads();
    for (int i = estart + t; i < eend; i += 512) {
        unsigned long long v2 = ebuf[i];
        int d = (int)(v2 >> 32) - nodebase;
        int pos = atomicAdd(&nxtl[d], 1);
        colx[pos] = (int)(unsigned int)v2;
    }
}

// ---------------- GEMM + attention logits (double-buffered) ----------------

template <int FOUT, int H, bool HOUT>
__global__ __launch_bounds__(256) void gemm_ft(
    const float* __restrict__ hin, const float* __restrict__ W,
    const float* __restrict__ al, const float* __restrict__ ar,
    void* __restrict__ ftout, float* __restrict__ el, float* __restrict__ er,
    int nnodes) {
    constexpr int BK = 32;
    constexpr int LDH = 132;                   // padded, mult of 4
    constexpr int TN = (FOUT == 128) ? 8 : 4;  // cols per thread
    constexpr int WCH = BK * FOUT / 1024;      // float4 staging iters: 4 or 2

    __shared__ float ht[2][BK * LDH];   // 2 x 16.9 KB
    __shared__ float Ws[2][BK * FOUT];  // 2 x 16 / 8 KB

    const int tid = threadIdx.x;
    const int nb = blockIdx.x * 128;
    const int tc = tid & 15, row = tid >> 4;
    const int nl = tid >> 3;       // 0..31
    const int kq = (tid & 7) * 4;  // 0,4,..,28

    float4 hreg[4];
    float4 wreg[WCH];

    auto load_chunk = [&](int k0) {
#pragma unroll
        for (int it = 0; it < 4; ++it) {
            int n = nb + nl + it * 32;
            hreg[it] = (n < nnodes)
                           ? *(const float4*)&hin[(size_t)n * KDIM + k0 + kq]
                           : make_float4(0.f, 0.f, 0.f, 0.f);
        }
        const float4* Wg = (const float4*)&W[(size_t)k0 * FOUT];
#pragma unroll
        for (int it = 0; it < WCH; ++it) wreg[it] = Wg[tid + it * 256];
    };
    auto store_chunk = [&](int b) {
#pragma unroll
        for (int it = 0; it < 4; ++it) {
            int nn = nl + it * 32;
            ht[b][(kq + 0) * LDH + nn] = hreg[it].x;
            ht[b][(kq + 1) * LDH + nn] = hreg[it].y;
            ht[b][(kq + 2) * LDH + nn] = hreg[it].z;
            ht[b][(kq + 3) * LDH + nn] = hreg[it].w;
        }
#pragma unroll
        for (int it = 0; it < WCH; ++it)
            ((float4*)Ws[b])[tid + it * 256] = wreg[it];
    };

    float acc[8][TN];
#pragma unroll
    for (int m = 0; m < 8; ++m)
#pragma unroll
        for (int j = 0; j < TN; ++j) acc[m][j] = 0.f;

    load_chunk(0);
    store_chunk(0);
    __syncthreads();

    for (int k0 = 0; k0 < KDIM / BK; ++k0) {
        const int cur = k0 & 1;
        if (k0 < KDIM / BK - 1) load_chunk((k0 + 1) * BK);

#pragma unroll 4
        for (int kk = 0; kk < BK; ++kk) {
            const float* hb = &ht[cur][kk * LDH];
            float4 h0 = *(const float4*)&hb[row * 4];
            float4 h1 = *(const float4*)&hb[64 + row * 4];
            float hv[8] = {h0.x, h0.y, h0.z, h0.w, h1.x, h1.y, h1.z, h1.w};
            const float* wb = &Ws[cur][kk * FOUT];
            float4 w0 = *(const float4*)&wb[tc * 4];
            float wv[TN];
            wv[0] = w0.x; wv[1] = w0.y; wv[2] = w0.z; wv[3] = w0.w;
            if constexpr (FOUT == 128) {
                float4 w1 = *(const float4*)&wb[64 + tc * 4];
                wv[4] = w1.x; wv[5] = w1.y; wv[6] = w1.z; wv[7] = w1.w;
            }
#pragma unroll
            for (int m = 0; m < 8; ++m)
#pragma unroll
                for (int j = 0; j < TN; ++j)
                    acc[m][j] = fmaf(hv[m], wv[j], acc[m][j]);
        }
        if (k0 < KDIM / BK - 1) store_chunk(cur ^ 1);
        __syncthreads();
    }

    float alv[TN], arv[TN];
#pragma unroll
    for (int j = 0; j < 4; ++j) {
        alv[j] = al[tc * 4 + j];
        arv[j] = ar[tc * 4 + j];
    }
    if constexpr (FOUT == 128) {
#pragma unroll
        for (int j = 0; j < 4; ++j) {
            alv[4 + j] = al[64 + tc * 4 + j];
            arv[4 + j] = ar[64 + tc * 4 + j];
        }
    }

#pragma unroll
    for (int m = 0; m < 8; ++m) {
        const int r = (m < 4) ? (row * 4 + m) : (64 + row * 4 + m - 4);
        const int n = nb + r;
        const bool valid = n < nnodes;

        float pl0 = 0.f, pr0 = 0.f, pl1 = 0.f, pr1 = 0.f;
#pragma unroll
        for (int j = 0; j < 4; ++j) {
            pl0 = fmaf(acc[m][j], alv[j], pl0);
            pr0 = fmaf(acc[m][j], arv[j], pr0);
        }
        if constexpr (FOUT == 128) {
#pragma unroll
            for (int j = 0; j < 4; ++j) {
                pl1 = fmaf(acc[m][4 + j], alv[4 + j], pl1);
                pr1 = fmaf(acc[m][4 + j], arv[4 + j], pr1);
            }
        }

        if constexpr (H == 4) {
#pragma unroll
            for (int msk = 1; msk < 8; msk <<= 1) {
                pl0 += __shfl_xor(pl0, msk);
                pr0 += __shfl_xor(pr0, msk);
                pl1 += __shfl_xor(pl1, msk);
                pr1 += __shfl_xor(pr1, msk);
            }
            if (valid && (tc == 0 || tc == 8)) {
                int hbase = (tc == 0) ? 0 : 1;
                el[(size_t)n * 4 + hbase] = pl0;
                er[(size_t)n * 4 + hbase] = pr0;
                el[(size_t)n * 4 + hbase + 2] = pl1;
                er[(size_t)n * 4 + hbase + 2] = pr1;
            }
        } else {
#pragma unroll
            for (int msk = 1; msk < 16; msk <<= 1) {
                pl0 += __shfl_xor(pl0, msk);
                pr0 += __shfl_xor(pr0, msk);
            }
            if (valid && tc == 0) {
                el[n] = pl0;
                er[n] = pr0;
            }
        }

        if (valid) {
            if constexpr (HOUT) {
                __half* fth = (__half*)ftout;
                ushort4 u0;
                u0.x = __half_as_ushort(__float2half_rn(acc[m][0]));
                u0.y = __half_as_ushort(__float2half_rn(acc[m][1]));
                u0.z = __half_as_ushort(__float2half_rn(acc[m][2]));
                u0.w = __half_as_ushort(__float2half_rn(acc[m][3]));
                *(ushort4*)&fth[(size_t)n * FOUT + tc * 4] = u0;
                if constexpr (FOUT == 128) {
                    ushort4 u1;
                    u1.x = __half_as_ushort(__float2half_rn(acc[m][4]));
                    u1.y = __half_as_ushort(__float2half_rn(acc[m][5]));
                    u1.z = __half_as_ushort(__float2half_rn(acc[m][6]));
                    u1.w = __half_as_ushort(__float2half_rn(acc[m][7]));
                    *(ushort4*)&fth[(size_t)n * FOUT + 64 + tc * 4] = u1;
                }
            } else {
                float* ftf = (float*)ftout;
                *(float4*)&ftf[(size_t)n * FOUT + tc * 4] =
                    make_float4(acc[m][0], acc[m][1], acc[m][2], acc[m][3]);
                if constexpr (FOUT == 128)
                    *(float4*)&ftf[(size_t)n * FOUT + 64 + tc * 4] =
                        make_float4(acc[m][4], acc[m][5], acc[m][6], acc[m][7]);
            }
        }
    }
}

// ---------------- node-parallel attention weights ----------------

template <int H>
__global__ __launch_bounds__(256) void node_pe(
    const int* __restrict__ rowptr, const int* __restrict__ colx,
    const float* __restrict__ el, const float* __restrict__ er,
    float* __restrict__ pe, int nnodes) {
    int n = blockIdx.x * 256 + threadIdx.x;
    if (n >= nnodes) return;
    const int s = rowptr[n], e = rowptr[n + 1];
    if constexpr (H == 4) {
        float4 r = *(const float4*)&er[(size_t)n * 4];
        for (int ee = s; ee < e; ++ee) {
            int sn = colx[ee];
            float4 l = *(const float4*)&el[(size_t)sn * 4];
            float x0 = l.x + r.x, x1 = l.y + r.y;
            float x2 = l.z + r.z, x3 = l.w + r.w;
            x0 = fmaxf(x0, 0.2f * x0);
            x1 = fmaxf(x1, 0.2f * x1);
            x2 = fmaxf(x2, 0.2f * x2);
            x3 = fmaxf(x3, 0.2f * x3);
            *(float4*)&pe[(size_t)ee * 4] =
                make_float4(__expf(x0), __expf(x1), __expf(x2), __expf(x3));
        }
    } else {
        float r = er[n];
        for (int ee = s; ee < e; ++ee) {
            float x = el[colx[ee]] + r;
            x = fmaxf(x, 0.2f * x);
            pe[ee] = __expf(x);
        }
    }
}

// ---------------- gather-accumulate aggregation ----------------

template <int F, int H, bool RELU, bool HIN>
__global__ __launch_bounds__(256) void gat_aggregate(
    const int* __restrict__ rowptr, const int* __restrict__ colx,
    const float* __restrict__ pe, const void* __restrict__ ftv,
    const float* __restrict__ bias, float* __restrict__ out, int nnodes) {
    constexpr int LPG = (F == 128) ? 32 : 16;  // lanes per node group
    constexpr int NPW = 64 / LPG;              // nodes per wave
    const int tid = threadIdx.x, wv = tid >> 6, lane = tid & 63;
    const int grp = lane / LPG, sub = lane % LPG;
    const int n = blockIdx.x * (4 * NPW) + wv * NPW + grp;
    const bool valid = n < nnodes;
    const int nn = valid ? n : 0;

    const int start = rowptr[nn];
    const int end = valid ? rowptr[nn + 1] : start;
    int md = end - start;
    if constexpr (NPW == 4) md = max(md, __shfl_xor(md, 16));
    md = max(md, __shfl_xor(md, 32));
    const int nit = (md + 7) / 8;

    const int head = (H == 4) ? (sub >> 3) : 0;

    float s = 0.f;
    float acc[4] = {0.f, 0.f, 0.f, 0.f};

    int idxA[4], idxB[4];
    float pA[4], pB[4];
    float4 fA[4], fB[4];

    auto issue = [&](int (&idxX)[4], float (&pX)[4], float4 (&fX)[4], int e0) {
#pragma unroll
        for (int i = 0; i < 4; ++i) {
            int ee = e0 + i;
            idxX[i] = (ee < end) ? colx[ee] : -1;
        }
#pragma unroll
        for (int i = 0; i < 4; ++i) {
            int ee = e0 + i;
            int pee = (ee < end) ? ee : start;
            if constexpr (H == 4)
                pX[i] = pe[(size_t)pee * 4 + head];
            else
                pX[i] = pe[pee];
            int sn = (idxX[i] < 0) ? 0 : idxX[i];
            if constexpr (HIN) {
                const __half* fth = (const __half*)ftv;
                ushort4 u = *(const ushort4*)&fth[(size_t)sn * F + sub * 4];
                fX[i] = make_float4(__half2float(__ushort_as_half(u.x)),
                                    __half2float(__ushort_as_half(u.y)),
                                    __half2float(__ushort_as_half(u.z)),
                                    __half2float(__ushort_as_half(u.w)));
            } else {
                const float* ftf = (const float*)ftv;
                fX[i] = *(const float4*)&ftf[(size_t)sn * F + sub * 4];
            }
        }
    };
    auto compute = [&](int (&idxX)[4], float (&pX)[4], float4 (&fX)[4]) {
#pragma unroll
        for (int i = 0; i < 4; ++i) {
            float p = (idxX[i] >= 0) ? pX[i] : 0.f;
            s += p;
            acc[0] = fmaf(p, fX[i].x, acc[0]);
            acc[1] = fmaf(p, fX[i].y, acc[1]);
            acc[2] = fmaf(p, fX[i].z, acc[2]);
            acc[3] = fmaf(p, fX[i].w, acc[3]);
        }
    };

    int e0 = start;
    issue(idxA, pA, fA, e0);
    for (int it = 0; it < nit; ++it) {
        issue(idxB, pB, fB, e0 + 4);   // batch k+1 in flight
        compute(idxA, pA, fA);         // consume batch k
        issue(idxA, pA, fA, e0 + 8);   // batch k+2 in flight
        compute(idxB, pB, fB);         // consume batch k+1
        e0 += 8;
    }

    if (!valid) return;
    float inv = 1.0f / s;  // deg >= 1 guaranteed
    float4 b4 = *(const float4*)&bias[sub * 4];
    float o0 = acc[0] * inv + b4.x, o1 = acc[1] * inv + b4.y;
    float o2 = acc[2] * inv + b4.z, o3 = acc[3] * inv + b4.w;
    if (RELU) {
        o0 = fmaxf(o0, 0.f); o1 = fmaxf(o1, 0.f);
        o2 = fmaxf(o2, 0.f); o3 = fmaxf(o3, 0.f);
    }
    *(float4*)&out[(size_t)n * F + sub * 4] = make_float4(o0, o1, o2, o3);
}

// ---------------- host launch ----------------

static inline size_t alignup(size_t x) { return (x + 255) & ~(size_t)255; }

extern "C" void kernel_launch(void* const* d_in, const int* in_sizes, int n_in,
                              void* d_out, int out_size, void* d_ws, size_t ws_size,
                              hipStream_t stream) {
    const float* features = (const float*)d_in[0];
    const int* src = (const int*)d_in[1];
    const int* dst = (const int*)d_in[2];
    const float* W0 = (const float*)d_in[3];
    const float* al0 = (const float*)d_in[4];
    const float* ar0 = (const float*)d_in[5];
    const float* b0 = (const float*)d_in[6];
    const float* W1 = (const float*)d_in[7];
    const float* al1 = (const float*)d_in[8];
    const float* ar1 = (const float*)d_in[9];
    const float* b1 = (const float*)d_in[10];
    const float* W2 = (const float*)d_in[11];
    const float* al2 = (const float*)d_in[12];
    const float* ar2 = (const float*)d_in[13];
    const float* b2 = (const float*)d_in[14];
    float* out = (float*)d_out;

    const int N = in_sizes[0] / 128;  // 100000
    const int E = in_sizes[1];        // 1600000
    const int nbN = (N + 255) / 256;
    const int nebs = (E + EPB - 1) / EPB;   // sort blocks (391)
    const int nbuck = (N + 511) >> BSH;     // 196 buckets

    char* w = (char*)d_ws;
    int* rowptr = (int*)w;     w += alignup((size_t)(N + 1) * 4);
    int* colx = (int*)w;       w += alignup((size_t)E * 4);
    float* ft32 = (float*)w;   w += alignup((size_t)N * 64 * 4);
    __half* ft16 = (__half*)w; w += alignup((size_t)N * 128 * 2);
    float* hbuf = (float*)w;   w += alignup((size_t)N * 128 * 4);
    float* el = (float*)w;     w += alignup((size_t)N * 4 * 4);
    float* er = (float*)w;     w += alignup((size_t)N * 4 * 4);
    float* pe = (float*)w;     w += alignup((size_t)E * 4 * 4);
    // ebuf aliases pe (disjoint lifetimes: CSR build finishes before pe use)
    unsigned long long* ebuf = (unsigned long long*)pe;
    int* cmat = (int*)w;       w += alignup((size_t)256 * nebs * 4);
    int* rowtot = (int*)w;     w += alignup(256 * 4);
    int* bbase = (int*)w;      w += alignup(256 * 4);

    // CSR build (atomic-free bucketed counting sort)
    hipMemsetAsync(rowtot, 0, 256 * 4, stream);
    ehist<<<nebs, 256, 0, stream>>>(dst, cmat, E, nebs);
    bscan<<<nbuck, 512, 0, stream>>>(cmat, rowtot, nebs);
    bbase_scan<<<1, 256, 0, stream>>>(rowtot, bbase);
    escatter<<<nebs, 256, 0, stream>>>(src, dst, cmat, bbase, ebuf, E, nebs);
    bucket_fill<<<nbuck, 512, 0, stream>>>(ebuf, bbase, rowptr, colx, N, E, nbuck);

    const int gGemm = (N + 127) / 128;
    const int gAgg8 = (N + 7) / 8;    // F=128: 2 nodes/wave, 4 waves
    const int gAgg16 = (N + 15) / 16; // F=64:  4 nodes/wave, 4 waves

    // Layer 0
    gemm_ft<128, 4, true><<<gGemm, 256, 0, stream>>>(features, W0, al0, ar0, ft16, el, er, N);
    node_pe<4><<<nbN, 256, 0, stream>>>(rowptr, colx, el, er, pe, N);
    gat_aggregate<128, 4, true, true><<<gAgg8, 256, 0, stream>>>(rowptr, colx, pe, ft16, b0, hbuf, N);

    // Layer 1
    gemm_ft<128, 4, true><<<gGemm, 256, 0, stream>>>(hbuf, W1, al1, ar1, ft16, el, er, N);
    node_pe<4><<<nbN, 256, 0, stream>>>(rowptr, colx, el, er, pe, N);
    gat_aggregate<128, 4, true, true><<<gAgg8, 256, 0, stream>>>(rowptr, colx, pe, ft16, b1, hbuf, N);

    // Layer 2
    gemm_ft<64, 1, false><<<gGemm, 256, 0, stream>>>(hbuf, W2, al2, ar2, ft32, el, er, N);
    node_pe<1><<<nbN, 256, 0, stream>>>(rowptr, colx, el, er, pe, N);
    gat_aggregate<64, 1, false, false><<<gAgg16, 256, 0, stream>>>(rowptr, colx, pe, ft32, b2, out, N);
}

// Round 11
// 474.427 us; speedup vs baseline: 2.5355x; 1.0345x over previous
//
#include <hip/hip_runtime.h>
#include <hip/hip_bf16.h>
#include <hip/hip_fp16.h>
#include <math.h>

// ---------------------------------------------------------------------------
// GAT (3-layer, DGL-style) on MI355X.
// CSR build via bucketed counting sort (no global atomics, coalesced writes).
// Per layer:
//   gemm_ft: double-buffered K-tiled (BK=16, 33KB LDS -> 4 blocks/CU) fp32
//            register GEMM, fused el/er. Layers 0/1 store ft fp16; layer 2 fp32.
//   node_pe: node-parallel pe[e][h] = exp(leaky(el[src]+er[dst])).
//   gat_aggregate: lean gather-accumulate, depth-2 pipelined 4-edge batches.
// Normalization (1/sum pe) applied once at the end -> identical to softmax.
// ---------------------------------------------------------------------------

constexpr int KDIM = 128;
constexpr int BSH = 9;            // bucket shift: 512 nodes per bucket
constexpr int EPB = 4096;         // edges per sort block

// ---------------- CSR build: bucketed counting sort ----------------

__global__ __launch_bounds__(256) void ehist(const int* __restrict__ dst,
                                             int* __restrict__ cmat,
                                             int E, int nebs) {
    __shared__ int lh[256];
    const int t = threadIdx.x;
    lh[t] = 0;
    __syncthreads();
    const int base = blockIdx.x * EPB;
    const int cntE = min(EPB, E - base);
    for (int i = t; i < cntE; i += 256) atomicAdd(&lh[dst[base + i] >> BSH], 1);
    __syncthreads();
    cmat[t * nebs + blockIdx.x] = lh[t];  // bucket-major
}

__global__ __launch_bounds__(512) void bscan(int* __restrict__ cmat,
                                             int* __restrict__ rowtot, int nebs) {
    __shared__ int sh[512];
    const int b = blockIdx.x, t = threadIdx.x;
    int v = (t < nebs) ? cmat[b * nebs + t] : 0;
    sh[t] = v;
    __syncthreads();
    for (int off = 1; off < 512; off <<= 1) {
        int u = (t >= off) ? sh[t - off] : 0;
        __syncthreads();
        sh[t] += u;
        __syncthreads();
    }
    if (t < nebs) cmat[b * nebs + t] = sh[t] - v;  // exclusive over blocks
    if (t == 511) rowtot[b] = sh[511];
}

__global__ __launch_bounds__(256) void bbase_scan(const int* __restrict__ rowtot,
                                                  int* __restrict__ bbase) {
    __shared__ int sh[256];
    const int t = threadIdx.x;
    int v = rowtot[t];
    sh[t] = v;
    __syncthreads();
    for (int off = 1; off < 256; off <<= 1) {
        int u = (t >= off) ? sh[t - off] : 0;
        __syncthreads();
        sh[t] += u;
        __syncthreads();
    }
    bbase[t] = sh[t] - v;  // exclusive (ascending buckets)
}

__global__ __launch_bounds__(256) void escatter(
    const int* __restrict__ src, const int* __restrict__ dst,
    const int* __restrict__ cmat, const int* __restrict__ bbase,
    unsigned long long* __restrict__ ebuf, int E, int nebs) {
    __shared__ unsigned long long sbuf[EPB];  // 32 KB
    __shared__ int lh[256], lstart[256], lcur[256];
    const int t = threadIdx.x;
    const int base = blockIdx.x * EPB;
    const int cntE = min(EPB, E - base);

    lh[t] = 0;
    __syncthreads();
    for (int i = t; i < cntE; i += 256) atomicAdd(&lh[dst[base + i] >> BSH], 1);
    __syncthreads();
    {
        __shared__ int sh[256];
        int v = lh[t];
        sh[t] = v;
        __syncthreads();
        for (int off = 1; off < 256; off <<= 1) {
            int u = (t >= off) ? sh[t - off] : 0;
            __syncthreads();
            sh[t] += u;
            __syncthreads();
        }
        lstart[t] = sh[t] - v;
        lcur[t] = sh[t] - v;
    }
    __syncthreads();
    for (int i = t; i < cntE; i += 256) {
        int d = dst[base + i], s = src[base + i];
        int r = atomicAdd(&lcur[d >> BSH], 1);
        sbuf[r] = ((unsigned long long)d << 32) | (unsigned int)s;
    }
    __syncthreads();
    for (int j = t; j < cntE; j += 256) {
        unsigned long long v = sbuf[j];
        int bk = (int)(v >> 32) >> BSH;
        int gpos = bbase[bk] + cmat[bk * nebs + blockIdx.x] + (j - lstart[bk]);
        ebuf[gpos] = v;
    }
}

__global__ __launch_bounds__(512) void bucket_fill(
    const unsigned long long* __restrict__ ebuf, const int* __restrict__ bbase,
    int* __restrict__ rowptr, int* __restrict__ colx, int N, int E, int nbuck) {
    __shared__ int cnt[512], nxtl[512], sh[512];
    const int b = blockIdx.x, t = threadIdx.x;
    const int nodebase = b << BSH;
    const int nn = min(512, N - nodebase);
    const int estart = bbase[b];
    const int eend = (b + 1 < 256) ? bbase[b + 1] : E;

    cnt[t] = 0;
    __syncthreads();
    for (int i = estart + t; i < eend; i += 512)
        atomicAdd(&cnt[(int)(ebuf[i] >> 32) - nodebase], 1);
    __syncthreads();
    int v = cnt[t];
    sh[t] = v;
    __syncthreads();
    for (int off = 1; off < 512; off <<= 1) {
        int u = (t >= off) ? sh[t - off] : 0;
        __syncthreads();
        sh[t] += u;
        __syncthreads();
    }
    if (t < nn) rowptr[nodebase + t + 1] = estart + sh[t];
    if (b == 0 && t == 0) rowptr[0] = 0;
    nxtl[t] = estart + sh[t] - v;  // exclusive start cursor
    __syncthreads();
    for (int i = estart + t; i < eend; i += 512) {
        unsigned long long v2 = ebuf[i];
        int d = (int)(v2 >> 32) - nodebase;
        int pos = atomicAdd(&nxtl[d], 1);
        colx[pos] = (int)(unsigned int)v2;
    }
}

// ---------------- GEMM + attention logits (double-buffered, BK=16) ---------

template <int FOUT, int H, bool HOUT>
__global__ __launch_bounds__(256, 4) void gemm_ft(
    const float* __restrict__ hin, const float* __restrict__ W,
    const float* __restrict__ al, const float* __restrict__ ar,
    void* __restrict__ ftout, float* __restrict__ el, float* __restrict__ er,
    int nnodes) {
    constexpr int BK = 16;
    constexpr int LDH = 132;                   // padded, mult of 4
    constexpr int TN = (FOUT == 128) ? 8 : 4;  // cols per thread
    constexpr int WCH = BK * FOUT / 1024;      // float4 staging iters: 2 or 1

    __shared__ float ht[2][BK * LDH];   // 2 x 8.45 KB
    __shared__ float Ws[2][BK * FOUT];  // 2 x 8 / 4 KB

    const int tid = threadIdx.x;
    const int nb = blockIdx.x * 128;
    const int tc = tid & 15, row = tid >> 4;
    const int nl = tid >> 2;       // 0..63
    const int kq = (tid & 3) * 4;  // 0,4,8,12

    float4 hreg[2];
    float4 wreg[WCH];

    auto load_chunk = [&](int k0) {
#pragma unroll
        for (int it = 0; it < 2; ++it) {
            int n = nb + nl + it * 64;
            hreg[it] = (n < nnodes)
                           ? *(const float4*)&hin[(size_t)n * KDIM + k0 + kq]
                           : make_float4(0.f, 0.f, 0.f, 0.f);
        }
        const float4* Wg = (const float4*)&W[(size_t)k0 * FOUT];
#pragma unroll
        for (int it = 0; it < WCH; ++it) wreg[it] = Wg[tid + it * 256];
    };
    auto store_chunk = [&](int b) {
#pragma unroll
        for (int it = 0; it < 2; ++it) {
            int nn = nl + it * 64;
            ht[b][(kq + 0) * LDH + nn] = hreg[it].x;
            ht[b][(kq + 1) * LDH + nn] = hreg[it].y;
            ht[b][(kq + 2) * LDH + nn] = hreg[it].z;
            ht[b][(kq + 3) * LDH + nn] = hreg[it].w;
        }
#pragma unroll
        for (int it = 0; it < WCH; ++it)
            ((float4*)Ws[b])[tid + it * 256] = wreg[it];
    };

    float acc[8][TN];
#pragma unroll
    for (int m = 0; m < 8; ++m)
#pragma unroll
        for (int j = 0; j < TN; ++j) acc[m][j] = 0.f;

    load_chunk(0);
    store_chunk(0);
    __syncthreads();

    for (int k0 = 0; k0 < KDIM / BK; ++k0) {
        const int cur = k0 & 1;
        if (k0 < KDIM / BK - 1) load_chunk((k0 + 1) * BK);

#pragma unroll 4
        for (int kk = 0; kk < BK; ++kk) {
            const float* hb = &ht[cur][kk * LDH];
            float4 h0 = *(const float4*)&hb[row * 4];
            float4 h1 = *(const float4*)&hb[64 + row * 4];
            float hv[8] = {h0.x, h0.y, h0.z, h0.w, h1.x, h1.y, h1.z, h1.w};
            const float* wb = &Ws[cur][kk * FOUT];
            float4 w0 = *(const float4*)&wb[tc * 4];
            float wv[TN];
            wv[0] = w0.x; wv[1] = w0.y; wv[2] = w0.z; wv[3] = w0.w;
            if constexpr (FOUT == 128) {
                float4 w1 = *(const float4*)&wb[64 + tc * 4];
                wv[4] = w1.x; wv[5] = w1.y; wv[6] = w1.z; wv[7] = w1.w;
            }
#pragma unroll
            for (int m = 0; m < 8; ++m)
#pragma unroll
                for (int j = 0; j < TN; ++j)
                    acc[m][j] = fmaf(hv[m], wv[j], acc[m][j]);
        }
        if (k0 < KDIM / BK - 1) store_chunk(cur ^ 1);
        __syncthreads();
    }

    float alv[TN], arv[TN];
#pragma unroll
    for (int j = 0; j < 4; ++j) {
        alv[j] = al[tc * 4 + j];
        arv[j] = ar[tc * 4 + j];
    }
    if constexpr (FOUT == 128) {
#pragma unroll
        for (int j = 0; j < 4; ++j) {
            alv[4 + j] = al[64 + tc * 4 + j];
            arv[4 + j] = ar[64 + tc * 4 + j];
        }
    }

#pragma unroll
    for (int m = 0; m < 8; ++m) {
        const int r = (m < 4) ? (row * 4 + m) : (64 + row * 4 + m - 4);
        const int n = nb + r;
        const bool valid = n < nnodes;

        float pl0 = 0.f, pr0 = 0.f, pl1 = 0.f, pr1 = 0.f;
#pragma unroll
        for (int j = 0; j < 4; ++j) {
            pl0 = fmaf(acc[m][j], alv[j], pl0);
            pr0 = fmaf(acc[m][j], arv[j], pr0);
        }
        if constexpr (FOUT == 128) {
#pragma unroll
            for (int j = 0; j < 4; ++j) {
                pl1 = fmaf(acc[m][4 + j], alv[4 + j], pl1);
                pr1 = fmaf(acc[m][4 + j], arv[4 + j], pr1);
            }
        }

        if constexpr (H == 4) {
#pragma unroll
            for (int msk = 1; msk < 8; msk <<= 1) {
                pl0 += __shfl_xor(pl0, msk);
                pr0 += __shfl_xor(pr0, msk);
                pl1 += __shfl_xor(pl1, msk);
                pr1 += __shfl_xor(pr1, msk);
            }
            if (valid && (tc == 0 || tc == 8)) {
                int hbase = (tc == 0) ? 0 : 1;
                el[(size_t)n * 4 + hbase] = pl0;
                er[(size_t)n * 4 + hbase] = pr0;
                el[(size_t)n * 4 + hbase + 2] = pl1;
                er[(size_t)n * 4 + hbase + 2] = pr1;
            }
        } else {
#pragma unroll
            for (int msk = 1; msk < 16; msk <<= 1) {
                pl0 += __shfl_xor(pl0, msk);
                pr0 += __shfl_xor(pr0, msk);
            }
            if (valid && tc == 0) {
                el[n] = pl0;
                er[n] = pr0;
            }
        }

        if (valid) {
            if constexpr (HOUT) {
                __half* fth = (__half*)ftout;
                ushort4 u0;
                u0.x = __half_as_ushort(__float2half_rn(acc[m][0]));
                u0.y = __half_as_ushort(__float2half_rn(acc[m][1]));
                u0.z = __half_as_ushort(__float2half_rn(acc[m][2]));
                u0.w = __half_as_ushort(__float2half_rn(acc[m][3]));
                *(ushort4*)&fth[(size_t)n * FOUT + tc * 4] = u0;
                if constexpr (FOUT == 128) {
                    ushort4 u1;
                    u1.x = __half_as_ushort(__float2half_rn(acc[m][4]));
                    u1.y = __half_as_ushort(__float2half_rn(acc[m][5]));
                    u1.z = __half_as_ushort(__float2half_rn(acc[m][6]));
                    u1.w = __half_as_ushort(__float2half_rn(acc[m][7]));
                    *(ushort4*)&fth[(size_t)n * FOUT + 64 + tc * 4] = u1;
                }
            } else {
                float* ftf = (float*)ftout;
                *(float4*)&ftf[(size_t)n * FOUT + tc * 4] =
                    make_float4(acc[m][0], acc[m][1], acc[m][2], acc[m][3]);
                if constexpr (FOUT == 128)
                    *(float4*)&ftf[(size_t)n * FOUT + 64 + tc * 4] =
                        make_float4(acc[m][4], acc[m][5], acc[m][6], acc[m][7]);
            }
        }
    }
}

// ---------------- node-parallel attention weights ----------------

template <int H>
__global__ __launch_bounds__(256) void node_pe(
    const int* __restrict__ rowptr, const int* __restrict__ colx,
    const float* __restrict__ el, const float* __restrict__ er,
    float* __restrict__ pe, int nnodes) {
    int n = blockIdx.x * 256 + threadIdx.x;
    if (n >= nnodes) return;
    const int s = rowptr[n], e = rowptr[n + 1];
    if constexpr (H == 4) {
        float4 r = *(const float4*)&er[(size_t)n * 4];
        for (int ee = s; ee < e; ++ee) {
            int sn = colx[ee];
            float4 l = *(const float4*)&el[(size_t)sn * 4];
            float x0 = l.x + r.x, x1 = l.y + r.y;
            float x2 = l.z + r.z, x3 = l.w + r.w;
            x0 = fmaxf(x0, 0.2f * x0);
            x1 = fmaxf(x1, 0.2f * x1);
            x2 = fmaxf(x2, 0.2f * x2);
            x3 = fmaxf(x3, 0.2f * x3);
            *(float4*)&pe[(size_t)ee * 4] =
                make_float4(__expf(x0), __expf(x1), __expf(x2), __expf(x3));
        }
    } else {
        float r = er[n];
        for (int ee = s; ee < e; ++ee) {
            float x = el[colx[ee]] + r;
            x = fmaxf(x, 0.2f * x);
            pe[ee] = __expf(x);
        }
    }
}

// ---------------- gather-accumulate aggregation ----------------

template <int F, int H, bool RELU, bool HIN>
__global__ __launch_bounds__(256) void gat_aggregate(
    const int* __restrict__ rowptr, const int* __restrict__ colx,
    const float* __restrict__ pe, const void* __restrict__ ftv,
    const float* __restrict__ bias, float* __restrict__ out, int nnodes) {
    constexpr int LPG = (F == 128) ? 32 : 16;  // lanes per node group
    constexpr int NPW = 64 / LPG;              // nodes per wave
    const int tid = threadIdx.x, wv = tid >> 6, lane = tid & 63;
    const int grp = lane / LPG, sub = lane % LPG;
    const int n = blockIdx.x * (4 * NPW) + wv * NPW + grp;
    const bool valid = n < nnodes;
    const int nn = valid ? n : 0;

    const int start = rowptr[nn];
    const int end = valid ? rowptr[nn + 1] : start;
    int md = end - start;
    if constexpr (NPW == 4) md = max(md, __shfl_xor(md, 16));
    md = max(md, __shfl_xor(md, 32));
    const int nit = (md + 7) / 8;

    const int head = (H == 4) ? (sub >> 3) : 0;

    float s = 0.f;
    float acc[4] = {0.f, 0.f, 0.f, 0.f};

    int idxA[4], idxB[4];
    float pA[4], pB[4];
    float4 fA[4], fB[4];

    auto issue = [&](int (&idxX)[4], float (&pX)[4], float4 (&fX)[4], int e0) {
#pragma unroll
        for (int i = 0; i < 4; ++i) {
            int ee = e0 + i;
            idxX[i] = (ee < end) ? colx[ee] : -1;
        }
#pragma unroll
        for (int i = 0; i < 4; ++i) {
            int ee = e0 + i;
            int pee = (ee < end) ? ee : start;
            if constexpr (H == 4)
                pX[i] = pe[(size_t)pee * 4 + head];
            else
                pX[i] = pe[pee];
            int sn = (idxX[i] < 0) ? 0 : idxX[i];
            if constexpr (HIN) {
                const __half* fth = (const __half*)ftv;
                ushort4 u = *(const ushort4*)&fth[(size_t)sn * F + sub * 4];
                fX[i] = make_float4(__half2float(__ushort_as_half(u.x)),
                                    __half2float(__ushort_as_half(u.y)),
                                    __half2float(__ushort_as_half(u.z)),
                                    __half2float(__ushort_as_half(u.w)));
            } else {
                const float* ftf = (const float*)ftv;
                fX[i] = *(const float4*)&ftf[(size_t)sn * F + sub * 4];
            }
        }
    };
    auto compute = [&](int (&idxX)[4], float (&pX)[4], float4 (&fX)[4]) {
#pragma unroll
        for (int i = 0; i < 4; ++i) {
            float p = (idxX[i] >= 0) ? pX[i] : 0.f;
            s += p;
            acc[0] = fmaf(p, fX[i].x, acc[0]);
            acc[1] = fmaf(p, fX[i].y, acc[1]);
            acc[2] = fmaf(p, fX[i].z, acc[2]);
            acc[3] = fmaf(p, fX[i].w, acc[3]);
        }
    };

    int e0 = start;
    issue(idxA, pA, fA, e0);
    for (int it = 0; it < nit; ++it) {
        issue(idxB, pB, fB, e0 + 4);   // batch k+1 in flight
        compute(idxA, pA, fA);         // consume batch k
        issue(idxA, pA, fA, e0 + 8);   // batch k+2 in flight
        compute(idxB, pB, fB);         // consume batch k+1
        e0 += 8;
    }

    if (!valid) return;
    float inv = 1.0f / s;  // deg >= 1 guaranteed
    float4 b4 = *(const float4*)&bias[sub * 4];
    float o0 = acc[0] * inv + b4.x, o1 = acc[1] * inv + b4.y;
    float o2 = acc[2] * inv + b4.z, o3 = acc[3] * inv + b4.w;
    if (RELU) {
        o0 = fmaxf(o0, 0.f); o1 = fmaxf(o1, 0.f);
        o2 = fmaxf(o2, 0.f); o3 = fmaxf(o3, 0.f);
    }
    *(float4*)&out[(size_t)n * F + sub * 4] = make_float4(o0, o1, o2, o3);
}

// ---------------- host launch ----------------

static inline size_t alignup(size_t x) { return (x + 255) & ~(size_t)255; }

extern "C" void kernel_launch(void* const* d_in, const int* in_sizes, int n_in,
                              void* d_out, int out_size, void* d_ws, size_t ws_size,
                              hipStream_t stream) {
    const float* features = (const float*)d_in[0];
    const int* src = (const int*)d_in[1];
    const int* dst = (const int*)d_in[2];
    const float* W0 = (const float*)d_in[3];
    const float* al0 = (const float*)d_in[4];
    const float* ar0 = (const float*)d_in[5];
    const float* b0 = (const float*)d_in[6];
    const float* W1 = (const float*)d_in[7];
    const float* al1 = (const float*)d_in[8];
    const float* ar1 = (const float*)d_in[9];
    const float* b1 = (const float*)d_in[10];
    const float* W2 = (const float*)d_in[11];
    const float* al2 = (const float*)d_in[12];
    const float* ar2 = (const float*)d_in[13];
    const float* b2 = (const float*)d_in[14];
    float* out = (float*)d_out;

    const int N = in_sizes[0] / 128;  // 100000
    const int E = in_sizes[1];        // 1600000
    const int nbN = (N + 255) / 256;
    const int nebs = (E + EPB - 1) / EPB;   // sort blocks (391)
    const int nbuck = (N + 511) >> BSH;     // 196 buckets

    char* w = (char*)d_ws;
    int* rowptr = (int*)w;     w += alignup((size_t)(N + 1) * 4);
    int* colx = (int*)w;       w += alignup((size_t)E * 4);
    float* ft32 = (float*)w;   w += alignup((size_t)N * 64 * 4);
    __half* ft16 = (__half*)w; w += alignup((size_t)N * 128 * 2);
    float* hbuf = (float*)w;   w += alignup((size_t)N * 128 * 4);
    float* el = (float*)w;     w += alignup((size_t)N * 4 * 4);
    float* er = (float*)w;     w += alignup((size_t)N * 4 * 4);
    float* pe = (float*)w;     w += alignup((size_t)E * 4 * 4);
    // ebuf aliases pe (disjoint lifetimes: CSR build finishes before pe use)
    unsigned long long* ebuf = (unsigned long long*)pe;
    int* cmat = (int*)w;       w += alignup((size_t)256 * nebs * 4);
    int* rowtot = (int*)w;     w += alignup(256 * 4);
    int* bbase = (int*)w;      w += alignup(256 * 4);

    // CSR build (atomic-free bucketed counting sort)
    hipMemsetAsync(rowtot, 0, 256 * 4, stream);
    ehist<<<nebs, 256, 0, stream>>>(dst, cmat, E, nebs);
    bscan<<<nbuck, 512, 0, stream>>>(cmat, rowtot, nebs);
    bbase_scan<<<1, 256, 0, stream>>>(rowtot, bbase);
    escatter<<<nebs, 256, 0, stream>>>(src, dst, cmat, bbase, ebuf, E, nebs);
    bucket_fill<<<nbuck, 512, 0, stream>>>(ebuf, bbase, rowptr, colx, N, E, nbuck);

    const int gGemm = (N + 127) / 128;
    const int gAgg8 = (N + 7) / 8;    // F=128: 2 nodes/wave, 4 waves
    const int gAgg16 = (N + 15) / 16; // F=64:  4 nodes/wave, 4 waves

    // Layer 0
    gemm_ft<128, 4, true><<<gGemm, 256, 0, stream>>>(features, W0, al0, ar0, ft16, el, er, N);
    node_pe<4><<<nbN, 256, 0, stream>>>(rowptr, colx, el, er, pe, N);
    gat_aggregate<128, 4, true, true><<<gAgg8, 256, 0, stream>>>(rowptr, colx, pe, ft16, b0, hbuf, N);

    // Layer 1
    gemm_ft<128, 4, true><<<gGemm, 256, 0, stream>>>(hbuf, W1, al1, ar1, ft16, el, er, N);
    node_pe<4><<<nbN, 256, 0, stream>>>(rowptr, colx, el, er, pe, N);
    gat_aggregate<128, 4, true, true><<<gAgg8, 256, 0, stream>>>(rowptr, colx, pe, ft16, b1, hbuf, N);

    // Layer 2
    gemm_ft<64, 1, false><<<gGemm, 256, 0, stream>>>(hbuf, W2, al2, ar2, ft32, el, er, N);
    node_pe<1><<<nbN, 256, 0, stream>>>(rowptr, colx, el, er, pe, N);
    gat_aggregate<64, 1, false, false><<<gAgg16, 256, 0, stream>>>(rowptr, colx, pe, ft32, b2, out, N);
}

// Round 12
// 395.085 us; speedup vs baseline: 3.0447x; 1.2008x over previous
//
#include <hip/hip_runtime.h>
#include <hip/hip_bf16.h>
#include <hip/hip_fp16.h>
#include <math.h>

// ---------------------------------------------------------------------------
// GAT (3-layer, DGL-style) on MI355X.
// CSR build via bucketed counting sort (no global atomics, coalesced writes).
// Per layer:
//   gemm_ft: double-buffered K-tiled (BK=16, 33KB LDS -> 4 blocks/CU) fp32
//            register GEMM, fused el/er. Layers 0/1 store ft fp16; layer 2 fp32.
//   gat_aggregate: FUSED attention-weight + gather-accumulate. 4 nodes/wave
//            (16 lanes/node), p = exp(leaky(el[src]+er[dst])) computed inline,
//            depth-2 pipelined 4-edge batches, masked tail.
// Normalization (1/sum p) applied once at the end -> identical to softmax.
// ---------------------------------------------------------------------------

constexpr int KDIM = 128;
constexpr int BSH = 9;            // bucket shift: 512 nodes per bucket
constexpr int EPB = 4096;         // edges per sort block

// ---------------- CSR build: bucketed counting sort ----------------

__global__ __launch_bounds__(256) void ehist(const int* __restrict__ dst,
                                             int* __restrict__ cmat,
                                             int E, int nebs) {
    __shared__ int lh[256];
    const int t = threadIdx.x;
    lh[t] = 0;
    __syncthreads();
    const int base = blockIdx.x * EPB;
    const int cntE = min(EPB, E - base);
    for (int i = t; i < cntE; i += 256) atomicAdd(&lh[dst[base + i] >> BSH], 1);
    __syncthreads();
    cmat[t * nebs + blockIdx.x] = lh[t];  // bucket-major
}

__global__ __launch_bounds__(512) void bscan(int* __restrict__ cmat,
                                             int* __restrict__ rowtot, int nebs) {
    __shared__ int sh[512];
    const int b = blockIdx.x, t = threadIdx.x;
    int v = (t < nebs) ? cmat[b * nebs + t] : 0;
    sh[t] = v;
    __syncthreads();
    for (int off = 1; off < 512; off <<= 1) {
        int u = (t >= off) ? sh[t - off] : 0;
        __syncthreads();
        sh[t] += u;
        __syncthreads();
    }
    if (t < nebs) cmat[b * nebs + t] = sh[t] - v;  // exclusive over blocks
    if (t == 511) rowtot[b] = sh[511];
}

__global__ __launch_bounds__(256) void bbase_scan(const int* __restrict__ rowtot,
                                                  int* __restrict__ bbase) {
    __shared__ int sh[256];
    const int t = threadIdx.x;
    int v = rowtot[t];
    sh[t] = v;
    __syncthreads();
    for (int off = 1; off < 256; off <<= 1) {
        int u = (t >= off) ? sh[t - off] : 0;
        __syncthreads();
        sh[t] += u;
        __syncthreads();
    }
    bbase[t] = sh[t] - v;  // exclusive (ascending buckets)
}

__global__ __launch_bounds__(256) void escatter(
    const int* __restrict__ src, const int* __restrict__ dst,
    const int* __restrict__ cmat, const int* __restrict__ bbase,
    unsigned long long* __restrict__ ebuf, int E, int nebs) {
    __shared__ unsigned long long sbuf[EPB];  // 32 KB
    __shared__ int lh[256], lstart[256], lcur[256];
    const int t = threadIdx.x;
    const int base = blockIdx.x * EPB;
    const int cntE = min(EPB, E - base);

    lh[t] = 0;
    __syncthreads();
    for (int i = t; i < cntE; i += 256) atomicAdd(&lh[dst[base + i] >> BSH], 1);
    __syncthreads();
    {
        __shared__ int sh[256];
        int v = lh[t];
        sh[t] = v;
        __syncthreads();
        for (int off = 1; off < 256; off <<= 1) {
            int u = (t >= off) ? sh[t - off] : 0;
            __syncthreads();
            sh[t] += u;
            __syncthreads();
        }
        lstart[t] = sh[t] - v;
        lcur[t] = sh[t] - v;
    }
    __syncthreads();
    for (int i = t; i < cntE; i += 256) {
        int d = dst[base + i], s = src[base + i];
        int r = atomicAdd(&lcur[d >> BSH], 1);
        sbuf[r] = ((unsigned long long)d << 32) | (unsigned int)s;
    }
    __syncthreads();
    for (int j = t; j < cntE; j += 256) {
        unsigned long long v = sbuf[j];
        int bk = (int)(v >> 32) >> BSH;
        int gpos = bbase[bk] + cmat[bk * nebs + blockIdx.x] + (j - lstart[bk]);
        ebuf[gpos] = v;
    }
}

__global__ __launch_bounds__(512) void bucket_fill(
    const unsigned long long* __restrict__ ebuf, const int* __restrict__ bbase,
    int* __restrict__ rowptr, int* __restrict__ colx, int N, int E, int nbuck) {
    __shared__ int cnt[512], nxtl[512], sh[512];
    const int b = blockIdx.x, t = threadIdx.x;
    const int nodebase = b << BSH;
    const int nn = min(512, N - nodebase);
    const int estart = bbase[b];
    const int eend = (b + 1 < 256) ? bbase[b + 1] : E;

    cnt[t] = 0;
    __syncthreads();
    for (int i = estart + t; i < eend; i += 512)
        atomicAdd(&cnt[(int)(ebuf[i] >> 32) - nodebase], 1);
    __syncthreads();
    int v = cnt[t];
    sh[t] = v;
    __syncthreads();
    for (int off = 1; off < 512; off <<= 1) {
        int u = (t >= off) ? sh[t - off] : 0;
        __syncthreads();
        sh[t] += u;
        __syncthreads();
    }
    if (t < nn) rowptr[nodebase + t + 1] = estart + sh[t];
    if (b == 0 && t == 0) rowptr[0] = 0;
    nxtl[t] = estart + sh[t] - v;  // exclusive start cursor
    __syncthreads();
    for (int i = estart + t; i < eend; i += 512) {
        unsigned long long v2 = ebuf[i];
        int d = (int)(v2 >> 32) - nodebase;
        int pos = atomicAdd(&nxtl[d], 1);
        colx[pos] = (int)(unsigned int)v2;
    }
}

// ---------------- GEMM + attention logits (double-buffered, BK=16) ---------

template <int FOUT, int H, bool HOUT>
__global__ __launch_bounds__(256, 4) void gemm_ft(
    const float* __restrict__ hin, const float* __restrict__ W,
    const float* __restrict__ al, const float* __restrict__ ar,
    void* __restrict__ ftout, float* __restrict__ el, float* __restrict__ er,
    int nnodes) {
    constexpr int BK = 16;
    constexpr int LDH = 132;                   // padded, mult of 4
    constexpr int TN = (FOUT == 128) ? 8 : 4;  // cols per thread
    constexpr int WCH = BK * FOUT / 1024;      // float4 staging iters: 2 or 1

    __shared__ float ht[2][BK * LDH];   // 2 x 8.45 KB
    __shared__ float Ws[2][BK * FOUT];  // 2 x 8 / 4 KB

    const int tid = threadIdx.x;
    const int nb = blockIdx.x * 128;
    const int tc = tid & 15, row = tid >> 4;
    const int nl = tid >> 2;       // 0..63
    const int kq = (tid & 3) * 4;  // 0,4,8,12

    float4 hreg[2];
    float4 wreg[WCH];

    auto load_chunk = [&](int k0) {
#pragma unroll
        for (int it = 0; it < 2; ++it) {
            int n = nb + nl + it * 64;
            hreg[it] = (n < nnodes)
                           ? *(const float4*)&hin[(size_t)n * KDIM + k0 + kq]
                           : make_float4(0.f, 0.f, 0.f, 0.f);
        }
        const float4* Wg = (const float4*)&W[(size_t)k0 * FOUT];
#pragma unroll
        for (int it = 0; it < WCH; ++it) wreg[it] = Wg[tid + it * 256];
    };
    auto store_chunk = [&](int b) {
#pragma unroll
        for (int it = 0; it < 2; ++it) {
            int nn = nl + it * 64;
            ht[b][(kq + 0) * LDH + nn] = hreg[it].x;
            ht[b][(kq + 1) * LDH + nn] = hreg[it].y;
            ht[b][(kq + 2) * LDH + nn] = hreg[it].z;
            ht[b][(kq + 3) * LDH + nn] = hreg[it].w;
        }
#pragma unroll
        for (int it = 0; it < WCH; ++it)
            ((float4*)Ws[b])[tid + it * 256] = wreg[it];
    };

    float acc[8][TN];
#pragma unroll
    for (int m = 0; m < 8; ++m)
#pragma unroll
        for (int j = 0; j < TN; ++j) acc[m][j] = 0.f;

    load_chunk(0);
    store_chunk(0);
    __syncthreads();

    for (int k0 = 0; k0 < KDIM / BK; ++k0) {
        const int cur = k0 & 1;
        if (k0 < KDIM / BK - 1) load_chunk((k0 + 1) * BK);

#pragma unroll 4
        for (int kk = 0; kk < BK; ++kk) {
            const float* hb = &ht[cur][kk * LDH];
            float4 h0 = *(const float4*)&hb[row * 4];
            float4 h1 = *(const float4*)&hb[64 + row * 4];
            float hv[8] = {h0.x, h0.y, h0.z, h0.w, h1.x, h1.y, h1.z, h1.w};
            const float* wb = &Ws[cur][kk * FOUT];
            float4 w0 = *(const float4*)&wb[tc * 4];
            float wv[TN];
            wv[0] = w0.x; wv[1] = w0.y; wv[2] = w0.z; wv[3] = w0.w;
            if constexpr (FOUT == 128) {
                float4 w1 = *(const float4*)&wb[64 + tc * 4];
                wv[4] = w1.x; wv[5] = w1.y; wv[6] = w1.z; wv[7] = w1.w;
            }
#pragma unroll
            for (int m = 0; m < 8; ++m)
#pragma unroll
                for (int j = 0; j < TN; ++j)
                    acc[m][j] = fmaf(hv[m], wv[j], acc[m][j]);
        }
        if (k0 < KDIM / BK - 1) store_chunk(cur ^ 1);
        __syncthreads();
    }

    float alv[TN], arv[TN];
#pragma unroll
    for (int j = 0; j < 4; ++j) {
        alv[j] = al[tc * 4 + j];
        arv[j] = ar[tc * 4 + j];
    }
    if constexpr (FOUT == 128) {
#pragma unroll
        for (int j = 0; j < 4; ++j) {
            alv[4 + j] = al[64 + tc * 4 + j];
            arv[4 + j] = ar[64 + tc * 4 + j];
        }
    }

#pragma unroll
    for (int m = 0; m < 8; ++m) {
        const int r = (m < 4) ? (row * 4 + m) : (64 + row * 4 + m - 4);
        const int n = nb + r;
        const bool valid = n < nnodes;

        float pl0 = 0.f, pr0 = 0.f, pl1 = 0.f, pr1 = 0.f;
#pragma unroll
        for (int j = 0; j < 4; ++j) {
            pl0 = fmaf(acc[m][j], alv[j], pl0);
            pr0 = fmaf(acc[m][j], arv[j], pr0);
        }
        if constexpr (FOUT == 128) {
#pragma unroll
            for (int j = 0; j < 4; ++j) {
                pl1 = fmaf(acc[m][4 + j], alv[4 + j], pl1);
                pr1 = fmaf(acc[m][4 + j], arv[4 + j], pr1);
            }
        }

        if constexpr (H == 4) {
#pragma unroll
            for (int msk = 1; msk < 8; msk <<= 1) {
                pl0 += __shfl_xor(pl0, msk);
                pr0 += __shfl_xor(pr0, msk);
                pl1 += __shfl_xor(pl1, msk);
                pr1 += __shfl_xor(pr1, msk);
            }
            if (valid && (tc == 0 || tc == 8)) {
                int hbase = (tc == 0) ? 0 : 1;
                el[(size_t)n * 4 + hbase] = pl0;
                er[(size_t)n * 4 + hbase] = pr0;
                el[(size_t)n * 4 + hbase + 2] = pl1;
                er[(size_t)n * 4 + hbase + 2] = pr1;
            }
        } else {
#pragma unroll
            for (int msk = 1; msk < 16; msk <<= 1) {
                pl0 += __shfl_xor(pl0, msk);
                pr0 += __shfl_xor(pr0, msk);
            }
            if (valid && tc == 0) {
                el[n] = pl0;
                er[n] = pr0;
            }
        }

        if (valid) {
            if constexpr (HOUT) {
                __half* fth = (__half*)ftout;
                ushort4 u0;
                u0.x = __half_as_ushort(__float2half_rn(acc[m][0]));
                u0.y = __half_as_ushort(__float2half_rn(acc[m][1]));
                u0.z = __half_as_ushort(__float2half_rn(acc[m][2]));
                u0.w = __half_as_ushort(__float2half_rn(acc[m][3]));
                *(ushort4*)&fth[(size_t)n * FOUT + tc * 4] = u0;
                if constexpr (FOUT == 128) {
                    ushort4 u1;
                    u1.x = __half_as_ushort(__float2half_rn(acc[m][4]));
                    u1.y = __half_as_ushort(__float2half_rn(acc[m][5]));
                    u1.z = __half_as_ushort(__float2half_rn(acc[m][6]));
                    u1.w = __half_as_ushort(__float2half_rn(acc[m][7]));
                    *(ushort4*)&fth[(size_t)n * FOUT + 64 + tc * 4] = u1;
                }
            } else {
                float* ftf = (float*)ftout;
                *(float4*)&ftf[(size_t)n * FOUT + tc * 4] =
                    make_float4(acc[m][0], acc[m][1], acc[m][2], acc[m][3]);
                if constexpr (FOUT == 128)
                    *(float4*)&ftf[(size_t)n * FOUT + 64 + tc * 4] =
                        make_float4(acc[m][4], acc[m][5], acc[m][6], acc[m][7]);
            }
        }
    }
}

// ---------------- FUSED attention-weight + gather-accumulate ---------------
// 4 nodes/wave (16 lanes each). CPL = F/16 cols per lane.
// p = exp(leaky(el[src]+er[dst])) computed inline (identical fp32 math to
// the old node_pe pass -> bit-identical output, no pe buffer).
// Depth-2 pipelined 4-edge batches; masked tail (idx=-1 -> p=0).

template <int F, int H, bool RELU, bool HIN>
__global__ __launch_bounds__(256) void gat_aggregate(
    const int* __restrict__ rowptr, const int* __restrict__ colx,
    const float* __restrict__ el, const float* __restrict__ er,
    const void* __restrict__ ftv, const float* __restrict__ bias,
    float* __restrict__ out, int nnodes) {
    constexpr int CPL = F / 16;  // 8 (F=128, fp16) or 4 (F=64, fp32)
    const int tid = threadIdx.x, wv = tid >> 6, lane = tid & 63;
    const int grp = lane >> 4, sub = lane & 15;
    const int n = blockIdx.x * 16 + wv * 4 + grp;
    const bool valid = n < nnodes;
    const int nn = valid ? n : 0;

    const int start = rowptr[nn];
    const int end = valid ? rowptr[nn + 1] : start;
    int md = end - start;
    md = max(md, __shfl_xor(md, 16));
    md = max(md, __shfl_xor(md, 32));
    const int nit = (md + 7) / 8;

    // F=128: lane sub covers cols [sub*8, sub*8+8) -> head = sub>>2
    const int head = (H == 4) ? (sub >> 2) : 0;
    const float er_s = (H == 4) ? er[(size_t)nn * 4 + head] : er[nn];

    float sA = 0.f, sB = 0.f;
    float acc[CPL];
#pragma unroll
    for (int c = 0; c < CPL; ++c) acc[c] = 0.f;

    int idxA[4], idxB[4];
    float xA[4], xB[4];
    uint4 hA[4], hB[4];   // fp16 path: 8 halves
    float4 fA[4], fB[4];  // fp32 path

    auto issue = [&](int (&idxX)[4], float (&xX)[4], uint4 (&hX)[4],
                     float4 (&fX)[4], int e0) {
#pragma unroll
        for (int i = 0; i < 4; ++i) {
            int ee = e0 + i;
            idxX[i] = (ee < end) ? colx[ee] : -1;
        }
#pragma unroll
        for (int i = 0; i < 4; ++i) {
            int sn = (idxX[i] < 0) ? 0 : idxX[i];
            if constexpr (HIN) {
                const __half* fth = (const __half*)ftv;
                hX[i] = *(const uint4*)&fth[(size_t)sn * F + sub * 8];
            } else {
                const float* ftf = (const float*)ftv;
                fX[i] = *(const float4*)&ftf[(size_t)sn * F + sub * 4];
            }
            xX[i] = (H == 4) ? el[(size_t)sn * 4 + head] : el[sn];
        }
    };
    auto compute = [&](int (&idxX)[4], float (&xX)[4], uint4 (&hX)[4],
                       float4 (&fX)[4], float& sX) {
#pragma unroll
        for (int i = 0; i < 4; ++i) {
            float x = xX[i] + er_s;
            x = fmaxf(x, 0.2f * x);  // leaky_relu
            float p = __expf(x);
            p = (idxX[i] >= 0) ? p : 0.f;
            sX += p;
            if constexpr (HIN) {
                const __half* hv = (const __half*)&hX[i];
#pragma unroll
                for (int c = 0; c < CPL; ++c)
                    acc[c] = fmaf(p, __half2float(hv[c]), acc[c]);
            } else {
                acc[0] = fmaf(p, fX[i].x, acc[0]);
                acc[1] = fmaf(p, fX[i].y, acc[1]);
                acc[2] = fmaf(p, fX[i].z, acc[2]);
                acc[3] = fmaf(p, fX[i].w, acc[3]);
            }
        }
    };

    int e0 = start;
    issue(idxA, xA, hA, fA, e0);
    for (int it = 0; it < nit; ++it) {
        issue(idxB, xB, hB, fB, e0 + 4);       // batch k+1 in flight
        compute(idxA, xA, hA, fA, sA);         // consume batch k
        issue(idxA, xA, hA, fA, e0 + 8);       // batch k+2 in flight
        compute(idxB, xB, hB, fB, sB);         // consume batch k+1
        e0 += 8;
    }

    if (!valid) return;
    float s = sA + sB;
    float inv = 1.0f / s;  // deg >= 1 guaranteed
    float o[CPL];
#pragma unroll
    for (int c = 0; c < CPL; ++c) {
        o[c] = acc[c] * inv + bias[sub * CPL + c];
        if (RELU) o[c] = fmaxf(o[c], 0.f);
    }
    if constexpr (CPL == 8) {
        *(float4*)&out[(size_t)n * F + sub * 8] =
            make_float4(o[0], o[1], o[2], o[3]);
        *(float4*)&out[(size_t)n * F + sub * 8 + 4] =
            make_float4(o[4], o[5], o[6], o[7]);
    } else {
        *(float4*)&out[(size_t)n * F + sub * 4] =
            make_float4(o[0], o[1], o[2], o[3]);
    }
}

// ---------------- host launch ----------------

static inline size_t alignup(size_t x) { return (x + 255) & ~(size_t)255; }

extern "C" void kernel_launch(void* const* d_in, const int* in_sizes, int n_in,
                              void* d_out, int out_size, void* d_ws, size_t ws_size,
                              hipStream_t stream) {
    const float* features = (const float*)d_in[0];
    const int* src = (const int*)d_in[1];
    const int* dst = (const int*)d_in[2];
    const float* W0 = (const float*)d_in[3];
    const float* al0 = (const float*)d_in[4];
    const float* ar0 = (const float*)d_in[5];
    const float* b0 = (const float*)d_in[6];
    const float* W1 = (const float*)d_in[7];
    const float* al1 = (const float*)d_in[8];
    const float* ar1 = (const float*)d_in[9];
    const float* b1 = (const float*)d_in[10];
    const float* W2 = (const float*)d_in[11];
    const float* al2 = (const float*)d_in[12];
    const float* ar2 = (const float*)d_in[13];
    const float* b2 = (const float*)d_in[14];
    float* out = (float*)d_out;

    const int N = in_sizes[0] / 128;  // 100000
    const int E = in_sizes[1];        // 1600000
    const int nebs = (E + EPB - 1) / EPB;   // sort blocks (391)
    const int nbuck = (N + 511) >> BSH;     // 196 buckets

    char* w = (char*)d_ws;
    int* rowptr = (int*)w;     w += alignup((size_t)(N + 1) * 4);
    int* colx = (int*)w;       w += alignup((size_t)E * 4);
    float* ft32 = (float*)w;   w += alignup((size_t)N * 64 * 4);
    __half* ft16 = (__half*)w; w += alignup((size_t)N * 128 * 2);
    float* hbuf = (float*)w;   w += alignup((size_t)N * 128 * 4);
    float* el = (float*)w;     w += alignup((size_t)N * 4 * 4);
    float* er = (float*)w;     w += alignup((size_t)N * 4 * 4);
    unsigned long long* ebuf = (unsigned long long*)w;
    w += alignup((size_t)E * 8);
    int* cmat = (int*)w;       w += alignup((size_t)256 * nebs * 4);
    int* rowtot = (int*)w;     w += alignup(256 * 4);
    int* bbase = (int*)w;      w += alignup(256 * 4);

    // CSR build (atomic-free bucketed counting sort)
    hipMemsetAsync(rowtot, 0, 256 * 4, stream);
    ehist<<<nebs, 256, 0, stream>>>(dst, cmat, E, nebs);
    bscan<<<nbuck, 512, 0, stream>>>(cmat, rowtot, nebs);
    bbase_scan<<<1, 256, 0, stream>>>(rowtot, bbase);
    escatter<<<nebs, 256, 0, stream>>>(src, dst, cmat, bbase, ebuf, E, nebs);
    bucket_fill<<<nbuck, 512, 0, stream>>>(ebuf, bbase, rowptr, colx, N, E, nbuck);

    const int gGemm = (N + 127) / 128;
    const int gAgg = (N + 15) / 16;  // 4 nodes/wave, 4 waves/block

    // Layer 0
    gemm_ft<128, 4, true><<<gGemm, 256, 0, stream>>>(features, W0, al0, ar0, ft16, el, er, N);
    gat_aggregate<128, 4, true, true><<<gAgg, 256, 0, stream>>>(rowptr, colx, el, er, ft16, b0, hbuf, N);

    // Layer 1
    gemm_ft<128, 4, true><<<gGemm, 256, 0, stream>>>(hbuf, W1, al1, ar1, ft16, el, er, N);
    gat_aggregate<128, 4, true, true><<<gAgg, 256, 0, stream>>>(rowptr, colx, el, er, ft16, b1, hbuf, N);

    // Layer 2
    gemm_ft<64, 1, false><<<gGemm, 256, 0, stream>>>(hbuf, W2, al2, ar2, ft32, el, er, N);
    gat_aggregate<64, 1, false, false><<<gAgg, 256, 0, stream>>>(rowptr, colx, el, er, ft32, b2, out, N);
}

// Round 13
// 363.559 us; speedup vs baseline: 3.3087x; 1.0867x over previous
//
#include <hip/hip_runtime.h>
#include <hip/hip_bf16.h>
#include <hip/hip_fp16.h>
#include <math.h>

// ---------------------------------------------------------------------------
// GAT (3-layer, DGL-style) on MI355X.
// CSR build via bucketed counting sort (no global atomics, coalesced writes).
// Per layer:
//   gemm_mfma: bf16 split (hi+lo) MFMA GEMM -> fp32 accuracy at matrix-core
//              rate. C = Ahi*Bhi + Ahi*Blo + Alo*Bhi. W pre-swizzled once by
//              wprep. Fused el/er epilogue; ft stored fp16 (L0/L1) / fp32 (L2).
//   gat_aggregate: FUSED attention-weight + gather-accumulate (4 nodes/wave,
//              depth-2 pipelined 4-edge batches, masked tail).
// Normalization (1/sum p) applied once at the end -> identical to softmax.
// ---------------------------------------------------------------------------

constexpr int BSH = 9;            // bucket shift: 512 nodes per bucket
constexpr int EPB = 4096;         // edges per sort block

typedef __attribute__((ext_vector_type(8))) short bf16x8;
typedef __attribute__((ext_vector_type(4))) float f32x4;

__device__ __forceinline__ ushort bf16_rne(float f) {
    unsigned u = __float_as_uint(f);
    u += 0x7FFF + ((u >> 16) & 1);
    return (ushort)(u >> 16);
}
__device__ __forceinline__ float bf16_tof(ushort h) {
    return __uint_as_float(((unsigned)h) << 16);
}

// ---------------- CSR build: bucketed counting sort ----------------

__global__ __launch_bounds__(256) void ehist(const int* __restrict__ dst,
                                             int* __restrict__ cmat,
                                             int E, int nebs) {
    __shared__ int lh[256];
    const int t = threadIdx.x;
    lh[t] = 0;
    __syncthreads();
    const int base = blockIdx.x * EPB;
    const int cntE = min(EPB, E - base);
    for (int i = t; i < cntE; i += 256) atomicAdd(&lh[dst[base + i] >> BSH], 1);
    __syncthreads();
    cmat[t * nebs + blockIdx.x] = lh[t];  // bucket-major
}

__global__ __launch_bounds__(512) void bscan(int* __restrict__ cmat,
                                             int* __restrict__ rowtot, int nebs) {
    __shared__ int sh[512];
    const int b = blockIdx.x, t = threadIdx.x;
    int v = (t < nebs) ? cmat[b * nebs + t] : 0;
    sh[t] = v;
    __syncthreads();
    for (int off = 1; off < 512; off <<= 1) {
        int u = (t >= off) ? sh[t - off] : 0;
        __syncthreads();
        sh[t] += u;
        __syncthreads();
    }
    if (t < nebs) cmat[b * nebs + t] = sh[t] - v;  // exclusive over blocks
    if (t == 511) rowtot[b] = sh[511];
}

__global__ __launch_bounds__(256) void bbase_scan(const int* __restrict__ rowtot,
                                                  int* __restrict__ bbase) {
    __shared__ int sh[256];
    const int t = threadIdx.x;
    int v = rowtot[t];
    sh[t] = v;
    __syncthreads();
    for (int off = 1; off < 256; off <<= 1) {
        int u = (t >= off) ? sh[t - off] : 0;
        __syncthreads();
        sh[t] += u;
        __syncthreads();
    }
    bbase[t] = sh[t] - v;  // exclusive (ascending buckets)
}

__global__ __launch_bounds__(256) void escatter(
    const int* __restrict__ src, const int* __restrict__ dst,
    const int* __restrict__ cmat, const int* __restrict__ bbase,
    unsigned long long* __restrict__ ebuf, int E, int nebs) {
    __shared__ unsigned long long sbuf[EPB];  // 32 KB
    __shared__ int lh[256], lstart[256], lcur[256];
    const int t = threadIdx.x;
    const int base = blockIdx.x * EPB;
    const int cntE = min(EPB, E - base);

    lh[t] = 0;
    __syncthreads();
    for (int i = t; i < cntE; i += 256) atomicAdd(&lh[dst[base + i] >> BSH], 1);
    __syncthreads();
    {
        __shared__ int sh[256];
        int v = lh[t];
        sh[t] = v;
        __syncthreads();
        for (int off = 1; off < 256; off <<= 1) {
            int u = (t >= off) ? sh[t - off] : 0;
            __syncthreads();
            sh[t] += u;
            __syncthreads();
        }
        lstart[t] = sh[t] - v;
        lcur[t] = sh[t] - v;
    }
    __syncthreads();
    for (int i = t; i < cntE; i += 256) {
        int d = dst[base + i], s = src[base + i];
        int r = atomicAdd(&lcur[d >> BSH], 1);
        sbuf[r] = ((unsigned long long)d << 32) | (unsigned int)s;
    }
    __syncthreads();
    for (int j = t; j < cntE; j += 256) {
        unsigned long long v = sbuf[j];
        int bk = (int)(v >> 32) >> BSH;
        int gpos = bbase[bk] + cmat[bk * nebs + blockIdx.x] + (j - lstart[bk]);
        ebuf[gpos] = v;
    }
}

__global__ __launch_bounds__(512) void bucket_fill(
    const unsigned long long* __restrict__ ebuf, const int* __restrict__ bbase,
    int* __restrict__ rowptr, int* __restrict__ colx, int N, int E, int nbuck) {
    __shared__ int cnt[512], nxtl[512], sh[512];
    const int b = blockIdx.x, t = threadIdx.x;
    const int nodebase = b << BSH;
    const int nn = min(512, N - nodebase);
    const int estart = bbase[b];
    const int eend = (b + 1 < 256) ? bbase[b + 1] : E;

    cnt[t] = 0;
    __syncthreads();
    for (int i = estart + t; i < eend; i += 512)
        atomicAdd(&cnt[(int)(ebuf[i] >> 32) - nodebase], 1);
    __syncthreads();
    int v = cnt[t];
    sh[t] = v;
    __syncthreads();
    for (int off = 1; off < 512; off <<= 1) {
        int u = (t >= off) ? sh[t - off] : 0;
        __syncthreads();
        sh[t] += u;
        __syncthreads();
    }
    if (t < nn) rowptr[nodebase + t + 1] = estart + sh[t];
    if (b == 0 && t == 0) rowptr[0] = 0;
    nxtl[t] = estart + sh[t] - v;  // exclusive start cursor
    __syncthreads();
    for (int i = estart + t; i < eend; i += 512) {
        unsigned long long v2 = ebuf[i];
        int d = (int)(v2 >> 32) - nodebase;
        int pos = atomicAdd(&nxtl[d], 1);
        colx[pos] = (int)(unsigned int)v2;
    }
}

// ---------------- W prep: fp32 -> swizzled bf16 hi/lo fragments ------------
// Layout: [kstep:K/32][tile:FOUT/16][half:2][lane:64][i:8] ushort.
// B-frag convention: lane&15 = col, lane>>4 = k-group, i = k in group.

template <int FOUT>
__global__ __launch_bounds__(256) void wprep(const float* __restrict__ W,
                                             ushort* __restrict__ wsw) {
    constexpr int NT = FOUT / 16;
    int idx = blockIdx.x * 256 + threadIdx.x;
    if (idx >= 128 * FOUT / 4) return;
    float4 v = ((const float4*)W)[idx];
    int e0 = idx * 4;
    int k = e0 / FOUT, c0 = e0 - k * FOUT;
    int kstep = k >> 5, g = (k >> 3) & 3, i = k & 7;
    float vv[4] = {v.x, v.y, v.z, v.w};
#pragma unroll
    for (int d = 0; d < 4; ++d) {
        int c = c0 + d;
        int tile = c >> 4, l16 = c & 15;
        int lane = g * 16 + l16;
        ushort hi = bf16_rne(vv[d]);
        ushort lo = bf16_rne(vv[d] - bf16_tof(hi));
        size_t base = ((((size_t)kstep * NT + tile) * 2 + 0) * 64 + lane) * 8 + i;
        wsw[base] = hi;
        wsw[base + 512] = lo;  // half stride = 64*8
    }
}

// ---------------- split-bf16 MFMA GEMM + fused el/er -----------------------
// Block: 256 thr = 4 waves; 64 nodes x FOUT. Wave: 16 nodes x FOUT (NT acc
// tiles). K=128 as 4 ksteps of 32; W staged from wsw in 2 K-halves.
// C/D layout (HW-verified): col = lane&15, row = (lane>>4)*4 + j.

template <int FOUT, int H, bool HOUT>
__global__ __launch_bounds__(256) void gemm_mfma(
    const float* __restrict__ hin, const ushort* __restrict__ wsw,
    const float* __restrict__ al, const float* __restrict__ ar,
    void* __restrict__ ftout, float* __restrict__ el, float* __restrict__ er,
    int nnodes) {
    constexpr int NT = FOUT / 16;
    constexpr int WHALF = 2 * NT * 2 * 64 * 8;      // ushorts per K-half
    __shared__ ushort Asw[4 * 4 * 2 * 64 * 8];      // 32 KB
    __shared__ ushort Wsw[WHALF];                   // 32 / 16 KB

    const int tid = threadIdx.x;
    const int wv = tid >> 6, lane = tid & 63;
    const int nb = blockIdx.x * 64;

    // ---- stage A: fp32 -> bf16 hi/lo, frag-swizzled ----
    {
        const int nloc = tid >> 2;       // 0..63
        const int qb = tid & 3;
        const int gw = nloc >> 4, m = nloc & 15;
        const int n = nb + nloc;
        const bool v = n < nnodes;
        const float4* hrow = (const float4*)&hin[(size_t)(v ? n : 0) * 128];
#pragma unroll
        for (int it = 0; it < 8; ++it) {
            int q = qb + it * 4;         // float4 index in row, 0..31
            int k0 = q * 4;
            float4 x = v ? hrow[q] : make_float4(0.f, 0.f, 0.f, 0.f);
            int kstep = k0 >> 5, g = (k0 >> 3) & 3, i0 = k0 & 7;
            int laneA = g * 16 + m;
            size_t base =
                ((((size_t)gw * 4 + kstep) * 2 + 0) * 64 + laneA) * 8 + i0;
            float xs[4] = {x.x, x.y, x.z, x.w};
            ushort4 uh, ul;
            ushort h;
            h = bf16_rne(xs[0]); uh.x = h; ul.x = bf16_rne(xs[0] - bf16_tof(h));
            h = bf16_rne(xs[1]); uh.y = h; ul.y = bf16_rne(xs[1] - bf16_tof(h));
            h = bf16_rne(xs[2]); uh.z = h; ul.z = bf16_rne(xs[2] - bf16_tof(h));
            h = bf16_rne(xs[3]); uh.w = h; ul.w = bf16_rne(xs[3] - bf16_tof(h));
            *(ushort4*)&Asw[base] = uh;
            *(ushort4*)&Asw[base + 512] = ul;  // half stride = 64*8
        }
    }

    f32x4 acc[NT];
#pragma unroll
    for (int t = 0; t < NT; ++t) acc[t] = (f32x4){0.f, 0.f, 0.f, 0.f};

#pragma unroll
    for (int kh = 0; kh < 2; ++kh) {
        __syncthreads();  // A ready (kh=0) / W reads done (kh=1)
        {
            const uint4* srcp = (const uint4*)(wsw + (size_t)kh * WHALF);
            uint4* dstp = (uint4*)Wsw;
            constexpr int CNT = WHALF / 8;
#pragma unroll
            for (int ii = 0; ii < CNT / 256; ++ii)
                dstp[tid + ii * 256] = srcp[tid + ii * 256];
        }
        __syncthreads();

#pragma unroll
        for (int ks2 = 0; ks2 < 2; ++ks2) {
            const int kstep = kh * 2 + ks2;
            bf16x8 ahi = *(const bf16x8*)
                &Asw[(((wv * 4 + kstep) * 2 + 0) * 64 + lane) * 8];
            bf16x8 alo = *(const bf16x8*)
                &Asw[(((wv * 4 + kstep) * 2 + 1) * 64 + lane) * 8];
#pragma unroll
            for (int t = 0; t < NT; ++t) {
                bf16x8 bhi = *(const bf16x8*)
                    &Wsw[(((ks2 * NT + t) * 2 + 0) * 64 + lane) * 8];
                bf16x8 blo = *(const bf16x8*)
                    &Wsw[(((ks2 * NT + t) * 2 + 1) * 64 + lane) * 8];
                acc[t] = __builtin_amdgcn_mfma_f32_16x16x32_bf16(ahi, bhi, acc[t], 0, 0, 0);
                acc[t] = __builtin_amdgcn_mfma_f32_16x16x32_bf16(ahi, blo, acc[t], 0, 0, 0);
                acc[t] = __builtin_amdgcn_mfma_f32_16x16x32_bf16(alo, bhi, acc[t], 0, 0, 0);
            }
        }
    }

    // ---- epilogue: el/er (16-lane reductions) + ft store ----
    const int g = lane >> 4, l16 = lane & 15;
    const int nrow0 = nb + wv * 16 + g * 4;

    if constexpr (H == 4) {
#pragma unroll
        for (int h = 0; h < 4; ++h) {
            float a0 = al[h * 32 + l16], a1 = al[h * 32 + 16 + l16];
            float r0 = ar[h * 32 + l16], r1 = ar[h * 32 + 16 + l16];
#pragma unroll
            for (int j = 0; j < 4; ++j) {
                float pl = acc[2 * h][j] * a0 + acc[2 * h + 1][j] * a1;
                float pr = acc[2 * h][j] * r0 + acc[2 * h + 1][j] * r1;
#pragma unroll
                for (int msk = 1; msk < 16; msk <<= 1) {
                    pl += __shfl_xor(pl, msk);
                    pr += __shfl_xor(pr, msk);
                }
                int n = nrow0 + j;
                if (l16 == 0 && n < nnodes) {
                    el[(size_t)n * 4 + h] = pl;
                    er[(size_t)n * 4 + h] = pr;
                }
            }
        }
    } else {
#pragma unroll
        for (int j = 0; j < 4; ++j) {
            float pl = 0.f, pr = 0.f;
#pragma unroll
            for (int t = 0; t < NT; ++t) {
                pl = fmaf(acc[t][j], al[t * 16 + l16], pl);
                pr = fmaf(acc[t][j], ar[t * 16 + l16], pr);
            }
#pragma unroll
            for (int msk = 1; msk < 16; msk <<= 1) {
                pl += __shfl_xor(pl, msk);
                pr += __shfl_xor(pr, msk);
            }
            int n = nrow0 + j;
            if (l16 == 0 && n < nnodes) {
                el[n] = pl;
                er[n] = pr;
            }
        }
    }

#pragma unroll
    for (int j = 0; j < 4; ++j) {
        int n = nrow0 + j;
        if (n < nnodes) {
            if constexpr (HOUT) {
                __half* fth = (__half*)ftout;
#pragma unroll
                for (int t = 0; t < NT; ++t)
                    fth[(size_t)n * FOUT + t * 16 + l16] =
                        __float2half_rn(acc[t][j]);
            } else {
                float* ftf = (float*)ftout;
#pragma unroll
                for (int t = 0; t < NT; ++t)
                    ftf[(size_t)n * FOUT + t * 16 + l16] = acc[t][j];
            }
        }
    }
}

// ---------------- FUSED attention-weight + gather-accumulate ---------------

template <int F, int H, bool RELU, bool HIN>
__global__ __launch_bounds__(256) void gat_aggregate(
    const int* __restrict__ rowptr, const int* __restrict__ colx,
    const float* __restrict__ el, const float* __restrict__ er,
    const void* __restrict__ ftv, const float* __restrict__ bias,
    float* __restrict__ out, int nnodes) {
    constexpr int CPL = F / 16;  // 8 (F=128, fp16) or 4 (F=64, fp32)
    const int tid = threadIdx.x, wv = tid >> 6, lane = tid & 63;
    const int grp = lane >> 4, sub = lane & 15;
    const int n = blockIdx.x * 16 + wv * 4 + grp;
    const bool valid = n < nnodes;
    const int nn = valid ? n : 0;

    const int start = rowptr[nn];
    const int end = valid ? rowptr[nn + 1] : start;
    int md = end - start;
    md = max(md, __shfl_xor(md, 16));
    md = max(md, __shfl_xor(md, 32));
    const int nit = (md + 7) / 8;

    const int head = (H == 4) ? (sub >> 2) : 0;
    const float er_s = (H == 4) ? er[(size_t)nn * 4 + head] : er[nn];

    float sA = 0.f, sB = 0.f;
    float acc[CPL];
#pragma unroll
    for (int c = 0; c < CPL; ++c) acc[c] = 0.f;

    int idxA[4], idxB[4];
    float xA[4], xB[4];
    uint4 hA[4], hB[4];
    float4 fA[4], fB[4];

    auto issue = [&](int (&idxX)[4], float (&xX)[4], uint4 (&hX)[4],
                     float4 (&fX)[4], int e0) {
#pragma unroll
        for (int i = 0; i < 4; ++i) {
            int ee = e0 + i;
            idxX[i] = (ee < end) ? colx[ee] : -1;
        }
#pragma unroll
        for (int i = 0; i < 4; ++i) {
            int sn = (idxX[i] < 0) ? 0 : idxX[i];
            if constexpr (HIN) {
                const __half* fth = (const __half*)ftv;
                hX[i] = *(const uint4*)&fth[(size_t)sn * F + sub * 8];
            } else {
                const float* ftf = (const float*)ftv;
                fX[i] = *(const float4*)&ftf[(size_t)sn * F + sub * 4];
            }
            xX[i] = (H == 4) ? el[(size_t)sn * 4 + head] : el[sn];
        }
    };
    auto compute = [&](int (&idxX)[4], float (&xX)[4], uint4 (&hX)[4],
                       float4 (&fX)[4], float& sX) {
#pragma unroll
        for (int i = 0; i < 4; ++i) {
            float x = xX[i] + er_s;
            x = fmaxf(x, 0.2f * x);  // leaky_relu
            float p = __expf(x);
            p = (idxX[i] >= 0) ? p : 0.f;
            sX += p;
            if constexpr (HIN) {
                const __half* hv = (const __half*)&hX[i];
#pragma unroll
                for (int c = 0; c < CPL; ++c)
                    acc[c] = fmaf(p, __half2float(hv[c]), acc[c]);
            } else {
                acc[0] = fmaf(p, fX[i].x, acc[0]);
                acc[1] = fmaf(p, fX[i].y, acc[1]);
                acc[2] = fmaf(p, fX[i].z, acc[2]);
                acc[3] = fmaf(p, fX[i].w, acc[3]);
            }
        }
    };

    int e0 = start;
    issue(idxA, xA, hA, fA, e0);
    for (int it = 0; it < nit; ++it) {
        issue(idxB, xB, hB, fB, e0 + 4);
        compute(idxA, xA, hA, fA, sA);
        issue(idxA, xA, hA, fA, e0 + 8);
        compute(idxB, xB, hB, fB, sB);
        e0 += 8;
    }

    if (!valid) return;
    float s = sA + sB;
    float inv = 1.0f / s;  // deg >= 1 guaranteed
    float o[CPL];
#pragma unroll
    for (int c = 0; c < CPL; ++c) {
        o[c] = acc[c] * inv + bias[sub * CPL + c];
        if (RELU) o[c] = fmaxf(o[c], 0.f);
    }
    if constexpr (CPL == 8) {
        *(float4*)&out[(size_t)n * F + sub * 8] =
            make_float4(o[0], o[1], o[2], o[3]);
        *(float4*)&out[(size_t)n * F + sub * 8 + 4] =
            make_float4(o[4], o[5], o[6], o[7]);
    } else {
        *(float4*)&out[(size_t)n * F + sub * 4] =
            make_float4(o[0], o[1], o[2], o[3]);
    }
}

// ---------------- host launch ----------------

static inline size_t alignup(size_t x) { return (x + 255) & ~(size_t)255; }

extern "C" void kernel_launch(void* const* d_in, const int* in_sizes, int n_in,
                              void* d_out, int out_size, void* d_ws, size_t ws_size,
                              hipStream_t stream) {
    const float* features = (const float*)d_in[0];
    const int* src = (const int*)d_in[1];
    const int* dst = (const int*)d_in[2];
    const float* W0 = (const float*)d_in[3];
    const float* al0 = (const float*)d_in[4];
    const float* ar0 = (const float*)d_in[5];
    const float* b0 = (const float*)d_in[6];
    const float* W1 = (const float*)d_in[7];
    const float* al1 = (const float*)d_in[8];
    const float* ar1 = (const float*)d_in[9];
    const float* b1 = (const float*)d_in[10];
    const float* W2 = (const float*)d_in[11];
    const float* al2 = (const float*)d_in[12];
    const float* ar2 = (const float*)d_in[13];
    const float* b2 = (const float*)d_in[14];
    float* out = (float*)d_out;

    const int N = in_sizes[0] / 128;  // 100000
    const int E = in_sizes[1];        // 1600000
    const int nebs = (E + EPB - 1) / EPB;   // sort blocks (391)
    const int nbuck = (N + 511) >> BSH;     // 196 buckets

    char* w = (char*)d_ws;
    int* rowptr = (int*)w;     w += alignup((size_t)(N + 1) * 4);
    int* colx = (int*)w;       w += alignup((size_t)E * 4);
    float* ft32 = (float*)w;   w += alignup((size_t)N * 64 * 4);
    __half* ft16 = (__half*)w; w += alignup((size_t)N * 128 * 2);
    float* hbuf = (float*)w;   w += alignup((size_t)N * 128 * 4);
    float* el = (float*)w;     w += alignup((size_t)N * 4 * 4);
    float* er = (float*)w;     w += alignup((size_t)N * 4 * 4);
    unsigned long long* ebuf = (unsigned long long*)w;
    w += alignup((size_t)E * 8);
    int* cmat = (int*)w;       w += alignup((size_t)256 * nebs * 4);
    int* rowtot = (int*)w;     w += alignup(256 * 4);
    int* bbase = (int*)w;      w += alignup(256 * 4);
    ushort* wsw0 = (ushort*)w; w += alignup(128 * 128 * 2 * 2);
    ushort* wsw1 = (ushort*)w; w += alignup(128 * 128 * 2 * 2);
    ushort* wsw2 = (ushort*)w; w += alignup(128 * 64 * 2 * 2);

    // CSR build (atomic-free bucketed counting sort)
    hipMemsetAsync(rowtot, 0, 256 * 4, stream);
    ehist<<<nebs, 256, 0, stream>>>(dst, cmat, E, nebs);
    bscan<<<nbuck, 512, 0, stream>>>(cmat, rowtot, nebs);
    bbase_scan<<<1, 256, 0, stream>>>(rowtot, bbase);
    escatter<<<nebs, 256, 0, stream>>>(src, dst, cmat, bbase, ebuf, E, nebs);
    bucket_fill<<<nbuck, 512, 0, stream>>>(ebuf, bbase, rowptr, colx, N, E, nbuck);

    // W pre-swizzle (once per weight)
    wprep<128><<<16, 256, 0, stream>>>(W0, wsw0);
    wprep<128><<<16, 256, 0, stream>>>(W1, wsw1);
    wprep<64><<<8, 256, 0, stream>>>(W2, wsw2);

    const int gG = (N + 63) / 64;
    const int gAgg = (N + 15) / 16;  // 4 nodes/wave, 4 waves/block

    // Layer 0
    gemm_mfma<128, 4, true><<<gG, 256, 0, stream>>>(features, wsw0, al0, ar0, ft16, el, er, N);
    gat_aggregate<128, 4, true, true><<<gAgg, 256, 0, stream>>>(rowptr, colx, el, er, ft16, b0, hbuf, N);

    // Layer 1
    gemm_mfma<128, 4, true><<<gG, 256, 0, stream>>>(hbuf, wsw1, al1, ar1, ft16, el, er, N);
    gat_aggregate<128, 4, true, true><<<gAgg, 256, 0, stream>>>(rowptr, colx, el, er, ft16, b1, hbuf, N);

    // Layer 2
    gemm_mfma<64, 1, false><<<gG, 256, 0, stream>>>(hbuf, wsw2, al2, ar2, ft32, el, er, N);
    gat_aggregate<64, 1, false, false><<<gAgg, 256, 0, stream>>>(rowptr, colx, el, er, ft32, b2, out, N);
}

// Round 14
// 340.627 us; speedup vs baseline: 3.5314x; 1.0673x over previous
//
#include <hip/hip_runtime.h>
#include <hip/hip_bf16.h>
#include <hip/hip_fp16.h>
#include <math.h>

// ---------------------------------------------------------------------------
// GAT (3-layer, DGL-style) on MI355X.
// CSR build via bucketed counting sort (u32-packed, no global atomics).
// Per layer:
//   gemm_mfma: bf16 split (hi+lo) MFMA GEMM (fp32 accuracy at matrix rate).
//   gat_aggregate: fused attention-weight + gather-accumulate, 4 nodes/wave,
//                  depth-2 pipelined 4-edge batches.
// ft16/hbuf16 fp16 intermediates (L0/L1); layer-2 ft and final out fp32.
// ---------------------------------------------------------------------------

constexpr int BSH = 9;            // 512 nodes per bucket
constexpr int EPB = 4096;         // edges per sort block

typedef __attribute__((ext_vector_type(8))) short bf16x8;
typedef __attribute__((ext_vector_type(4))) float f32x4;

__device__ __forceinline__ ushort bf16_rne(float f) {
    unsigned u = __float_as_uint(f);
    u += 0x7FFF + ((u >> 16) & 1);
    return (ushort)(u >> 16);
}
__device__ __forceinline__ float bf16_tof(ushort h) {
    return __uint_as_float(((unsigned)h) << 16);
}

// ---------------- CSR build ----------------

__global__ __launch_bounds__(256) void ehist(const int* __restrict__ dst,
                                             int* __restrict__ cmat,
                                             int E, int nebs) {
    __shared__ int lh[256];
    const int t = threadIdx.x;
    lh[t] = 0;
    __syncthreads();
    const int base = blockIdx.x * EPB;
    const int cntE = min(EPB, E - base);
    for (int i = t; i < cntE; i += 256) atomicAdd(&lh[dst[base + i] >> BSH], 1);
    __syncthreads();
    cmat[t * nebs + blockIdx.x] = lh[t];  // bucket-major
}

__global__ __launch_bounds__(512) void bscan(int* __restrict__ cmat,
                                             int* __restrict__ rowtot, int nebs) {
    __shared__ int sh[512];
    const int b = blockIdx.x, t = threadIdx.x;
    int v = (t < nebs) ? cmat[b * nebs + t] : 0;
    sh[t] = v;
    __syncthreads();
    for (int off = 1; off < 512; off <<= 1) {
        int u = (t >= off) ? sh[t - off] : 0;
        __syncthreads();
        sh[t] += u;
        __syncthreads();
    }
    if (t < nebs) cmat[b * nebs + t] = sh[t] - v;
    if (t == 511) rowtot[b] = sh[511];
}

__global__ __launch_bounds__(256) void bbase_scan(const int* __restrict__ rowtot,
                                                  int* __restrict__ bbase, int nbuck) {
    __shared__ int sh[256];
    const int t = threadIdx.x;
    int v = (t < nbuck) ? rowtot[t] : 0;
    sh[t] = v;
    __syncthreads();
    for (int off = 1; off < 256; off <<= 1) {
        int u = (t >= off) ? sh[t - off] : 0;
        __syncthreads();
        sh[t] += u;
        __syncthreads();
    }
    bbase[t] = sh[t] - v;  // exclusive
}

__global__ __launch_bounds__(256) void escatter(
    const int* __restrict__ src, const int* __restrict__ dst,
    const int* __restrict__ cmat, const int* __restrict__ bbase,
    unsigned* __restrict__ ebuf, int E, int nebs) {
    __shared__ unsigned sbuf[EPB];        // 16 KB
    __shared__ unsigned char sbk[EPB];    // 4 KB
    __shared__ int lh[256], lstart[256], lcur[256], sh[256];
    const int t = threadIdx.x;
    const int base = blockIdx.x * EPB;
    const int cntE = min(EPB, E - base);

    lh[t] = 0;
    __syncthreads();
    for (int i = t; i < cntE; i += 256) atomicAdd(&lh[dst[base + i] >> BSH], 1);
    __syncthreads();
    {
        int v = lh[t];
        sh[t] = v;
        __syncthreads();
        for (int off = 1; off < 256; off <<= 1) {
            int u = (t >= off) ? sh[t - off] : 0;
            __syncthreads();
            sh[t] += u;
            __syncthreads();
        }
        lstart[t] = sh[t] - v;
        lcur[t] = sh[t] - v;
    }
    __syncthreads();
    for (int i = t; i < cntE; i += 256) {
        int d = dst[base + i], s = src[base + i];
        int bk = d >> BSH;
        int r = atomicAdd(&lcur[bk], 1);
        sbuf[r] = ((unsigned)(d & 511) << 17) | (unsigned)s;
        sbk[r] = (unsigned char)bk;
    }
    __syncthreads();
    for (int j = t; j < cntE; j += 256) {
        int bk = sbk[j];
        int gpos = bbase[bk] + cmat[bk * nebs + blockIdx.x] + (j - lstart[bk]);
        ebuf[gpos] = sbuf[j];
    }
}

__global__ __launch_bounds__(512) void bucket_fill(
    const unsigned* __restrict__ ebuf, const int* __restrict__ bbase,
    int* __restrict__ rowptr, int* __restrict__ colx, int N, int E, int nbuck) {
    __shared__ int cnt[512], nxtl[512], sh[512];
    const int b = blockIdx.x, t = threadIdx.x;
    const int nodebase = b << BSH;
    const int nn = min(512, N - nodebase);
    const int estart = bbase[b];
    const int eend = (b + 1 < 256) ? bbase[b + 1] : E;

    cnt[t] = 0;
    __syncthreads();
    for (int i = estart + t; i < eend; i += 512)
        atomicAdd(&cnt[ebuf[i] >> 17], 1);
    __syncthreads();
    int v = cnt[t];
    sh[t] = v;
    __syncthreads();
    for (int off = 1; off < 512; off <<= 1) {
        int u = (t >= off) ? sh[t - off] : 0;
        __syncthreads();
        sh[t] += u;
        __syncthreads();
    }
    if (t < nn) rowptr[nodebase + t + 1] = estart + sh[t];
    if (b == 0 && t == 0) rowptr[0] = 0;
    nxtl[t] = estart + sh[t] - v;
    __syncthreads();
    for (int i = estart + t; i < eend; i += 512) {
        unsigned v2 = ebuf[i];
        int dl = v2 >> 17;
        int pos = atomicAdd(&nxtl[dl], 1);
        colx[pos] = (int)(v2 & 0x1FFFFu);
    }
}

// ---------------- W prep (all 3 weights, one launch) ----------------
// Layout: [kstep:K/32][tile:FOUT/16][half:2][lane:64][i:8] ushort.

__global__ __launch_bounds__(256) void wprep_all(
    const float* __restrict__ W0, const float* __restrict__ W1,
    const float* __restrict__ W2, ushort* __restrict__ o0,
    ushort* __restrict__ o1, ushort* __restrict__ o2) {
    int b = blockIdx.x;
    const float* W;
    ushort* o;
    int FOUT, bb;
    if (b < 16) { W = W0; o = o0; FOUT = 128; bb = b; }
    else if (b < 32) { W = W1; o = o1; FOUT = 128; bb = b - 16; }
    else { W = W2; o = o2; FOUT = 64; bb = b - 32; }
    const int NT = FOUT / 16;
    int idx = bb * 256 + threadIdx.x;
    if (idx >= 128 * FOUT / 4) return;
    float4 v = ((const float4*)W)[idx];
    int e0 = idx * 4;
    int k = e0 / FOUT, c0 = e0 - k * FOUT;
    int kstep = k >> 5, g = (k >> 3) & 3, i = k & 7;
    float vv[4] = {v.x, v.y, v.z, v.w};
#pragma unroll
    for (int d = 0; d < 4; ++d) {
        int c = c0 + d;
        int tile = c >> 4, l16 = c & 15;
        int lane = g * 16 + l16;
        ushort hi = bf16_rne(vv[d]);
        ushort lo = bf16_rne(vv[d] - bf16_tof(hi));
        size_t base = ((((size_t)kstep * NT + tile) * 2 + 0) * 64 + lane) * 8 + i;
        o[base] = hi;
        o[base + 512] = lo;
    }
}

// ---------------- split-bf16 MFMA GEMM + fused el/er -----------------------
// Block: 4 waves; 64 nodes x FOUT. C/D: col = lane&15, row = (lane>>4)*4+j.

template <int FOUT, int H, bool HOUT, bool HIN16>
__global__ __launch_bounds__(256) void gemm_mfma(
    const void* __restrict__ hinv, const ushort* __restrict__ wsw,
    const float* __restrict__ al, const float* __restrict__ ar,
    void* __restrict__ ftout, float* __restrict__ el, float* __restrict__ er,
    int nnodes) {
    constexpr int NT = FOUT / 16;
    constexpr int WHALF = 2 * NT * 2 * 64 * 8;
    __shared__ ushort Asw[4 * 4 * 2 * 64 * 8];  // 32 KB
    __shared__ ushort Wsw[WHALF];

    const int tid = threadIdx.x;
    const int wv = tid >> 6, lane = tid & 63;
    const int nb = blockIdx.x * 64;

    // ---- stage A ----
    {
        const int nloc = tid >> 2;  // 0..63
        const int qb = tid & 3;
        const int gw = nloc >> 4, m = nloc & 15;
        const int n = nb + nloc;
        const bool v = n < nnodes;
        if constexpr (HIN16) {
            const __half* hrow = (const __half*)hinv + (size_t)(v ? n : 0) * 128;
#pragma unroll
            for (int it = 0; it < 4; ++it) {
                int k0 = (qb + it * 4) * 8;
                uint4 x = v ? *(const uint4*)&hrow[k0]
                            : make_uint4(0, 0, 0, 0);
                const __half* hp = (const __half*)&x;
                int kstep = k0 >> 5, g = (k0 >> 3) & 3;
                int laneA = g * 16 + m;
                size_t base =
                    ((((size_t)gw * 4 + kstep) * 2 + 0) * 64 + laneA) * 8;
                ushort4 uh0, uh1, ul0, ul1;
                float f;
                ushort h;
                f = __half2float(hp[0]); h = bf16_rne(f); uh0.x = h; ul0.x = bf16_rne(f - bf16_tof(h));
                f = __half2float(hp[1]); h = bf16_rne(f); uh0.y = h; ul0.y = bf16_rne(f - bf16_tof(h));
                f = __half2float(hp[2]); h = bf16_rne(f); uh0.z = h; ul0.z = bf16_rne(f - bf16_tof(h));
                f = __half2float(hp[3]); h = bf16_rne(f); uh0.w = h; ul0.w = bf16_rne(f - bf16_tof(h));
                f = __half2float(hp[4]); h = bf16_rne(f); uh1.x = h; ul1.x = bf16_rne(f - bf16_tof(h));
                f = __half2float(hp[5]); h = bf16_rne(f); uh1.y = h; ul1.y = bf16_rne(f - bf16_tof(h));
                f = __half2float(hp[6]); h = bf16_rne(f); uh1.z = h; ul1.z = bf16_rne(f - bf16_tof(h));
                f = __half2float(hp[7]); h = bf16_rne(f); uh1.w = h; ul1.w = bf16_rne(f - bf16_tof(h));
                *(ushort4*)&Asw[base] = uh0;
                *(ushort4*)&Asw[base + 4] = uh1;
                *(ushort4*)&Asw[base + 512] = ul0;
                *(ushort4*)&Asw[base + 516] = ul1;
            }
        } else {
            const float4* hrow =
                (const float4*)((const float*)hinv + (size_t)(v ? n : 0) * 128);
#pragma unroll
            for (int it = 0; it < 8; ++it) {
                int q = qb + it * 4;
                int k0 = q * 4;
                float4 x = v ? hrow[q] : make_float4(0.f, 0.f, 0.f, 0.f);
                int kstep = k0 >> 5, g = (k0 >> 3) & 3, i0 = k0 & 7;
                int laneA = g * 16 + m;
                size_t base =
                    ((((size_t)gw * 4 + kstep) * 2 + 0) * 64 + laneA) * 8 + i0;
                float xs[4] = {x.x, x.y, x.z, x.w};
                ushort4 uh, ul;
                ushort h;
                h = bf16_rne(xs[0]); uh.x = h; ul.x = bf16_rne(xs[0] - bf16_tof(h));
                h = bf16_rne(xs[1]); uh.y = h; ul.y = bf16_rne(xs[1] - bf16_tof(h));
                h = bf16_rne(xs[2]); uh.z = h; ul.z = bf16_rne(xs[2] - bf16_tof(h));
                h = bf16_rne(xs[3]); uh.w = h; ul.w = bf16_rne(xs[3] - bf16_tof(h));
                *(ushort4*)&Asw[base] = uh;
                *(ushort4*)&Asw[base + 512] = ul;
            }
        }
    }

    f32x4 acc[NT];
#pragma unroll
    for (int t = 0; t < NT; ++t) acc[t] = (f32x4){0.f, 0.f, 0.f, 0.f};

#pragma unroll
    for (int kh = 0; kh < 2; ++kh) {
        __syncthreads();
        {
            const uint4* srcp = (const uint4*)(wsw + (size_t)kh * WHALF);
            uint4* dstp = (uint4*)Wsw;
            constexpr int CNT = WHALF / 8;
#pragma unroll
            for (int ii = 0; ii < CNT / 256; ++ii)
                dstp[tid + ii * 256] = srcp[tid + ii * 256];
        }
        __syncthreads();

#pragma unroll
        for (int ks2 = 0; ks2 < 2; ++ks2) {
            const int kstep = kh * 2 + ks2;
            bf16x8 ahi = *(const bf16x8*)
                &Asw[(((wv * 4 + kstep) * 2 + 0) * 64 + lane) * 8];
            bf16x8 alo = *(const bf16x8*)
                &Asw[(((wv * 4 + kstep) * 2 + 1) * 64 + lane) * 8];
#pragma unroll
            for (int t = 0; t < NT; ++t) {
                bf16x8 bhi = *(const bf16x8*)
                    &Wsw[(((ks2 * NT + t) * 2 + 0) * 64 + lane) * 8];
                bf16x8 blo = *(const bf16x8*)
                    &Wsw[(((ks2 * NT + t) * 2 + 1) * 64 + lane) * 8];
                acc[t] = __builtin_amdgcn_mfma_f32_16x16x32_bf16(ahi, bhi, acc[t], 0, 0, 0);
                acc[t] = __builtin_amdgcn_mfma_f32_16x16x32_bf16(ahi, blo, acc[t], 0, 0, 0);
                acc[t] = __builtin_amdgcn_mfma_f32_16x16x32_bf16(alo, bhi, acc[t], 0, 0, 0);
            }
        }
    }

    // ---- epilogue ----
    const int g = lane >> 4, l16 = lane & 15;
    const int nrow0 = nb + wv * 16 + g * 4;

    if constexpr (H == 4) {
#pragma unroll
        for (int h = 0; h < 4; ++h) {
            float a0 = al[h * 32 + l16], a1 = al[h * 32 + 16 + l16];
            float r0 = ar[h * 32 + l16], r1 = ar[h * 32 + 16 + l16];
#pragma unroll
            for (int j = 0; j < 4; ++j) {
                float pl = acc[2 * h][j] * a0 + acc[2 * h + 1][j] * a1;
                float pr = acc[2 * h][j] * r0 + acc[2 * h + 1][j] * r1;
#pragma unroll
                for (int msk = 1; msk < 16; msk <<= 1) {
                    pl += __shfl_xor(pl, msk);
                    pr += __shfl_xor(pr, msk);
                }
                int n = nrow0 + j;
                if (l16 == 0 && n < nnodes) {
                    el[(size_t)n * 4 + h] = pl;
                    er[(size_t)n * 4 + h] = pr;
                }
            }
        }
    } else {
#pragma unroll
        for (int j = 0; j < 4; ++j) {
            float pl = 0.f, pr = 0.f;
#pragma unroll
            for (int t = 0; t < NT; ++t) {
                pl = fmaf(acc[t][j], al[t * 16 + l16], pl);
                pr = fmaf(acc[t][j], ar[t * 16 + l16], pr);
            }
#pragma unroll
            for (int msk = 1; msk < 16; msk <<= 1) {
                pl += __shfl_xor(pl, msk);
                pr += __shfl_xor(pr, msk);
            }
            int n = nrow0 + j;
            if (l16 == 0 && n < nnodes) {
                el[n] = pl;
                er[n] = pr;
            }
        }
    }

#pragma unroll
    for (int j = 0; j < 4; ++j) {
        int n = nrow0 + j;
        if (n < nnodes) {
            if constexpr (HOUT) {
                __half* fth = (__half*)ftout;
#pragma unroll
                for (int t = 0; t < NT; ++t)
                    fth[(size_t)n * FOUT + t * 16 + l16] =
                        __float2half_rn(acc[t][j]);
            } else {
                float* ftf = (float*)ftout;
#pragma unroll
                for (int t = 0; t < NT; ++t)
                    ftf[(size_t)n * FOUT + t * 16 + l16] = acc[t][j];
            }
        }
    }
}

// ---------------- FUSED attention-weight + gather-accumulate ---------------
// 4 nodes/wave (16 lanes each). CPL = F/16. Depth-2 pipelined 4-edge batches.
// Tail masked via (e0+i<end); gather addr clamped in-bounds.

template <int F, int H, bool RELU, bool HIN, bool HOUT16>
__global__ __launch_bounds__(256) void gat_aggregate(
    const int* __restrict__ rowptr, const int* __restrict__ colx,
    const float* __restrict__ el, const float* __restrict__ er,
    const void* __restrict__ ftv, const float* __restrict__ bias,
    void* __restrict__ outv, int nnodes) {
    constexpr int CPL = F / 16;  // 8 (F=128) or 4 (F=64)
    const int tid = threadIdx.x, wv = tid >> 6, lane = tid & 63;
    const int grp = lane >> 4, sub = lane & 15;
    const int n = blockIdx.x * 16 + wv * 4 + grp;
    const bool valid = n < nnodes;
    const int nn = valid ? n : 0;

    const int start = rowptr[nn];
    const int end = valid ? rowptr[nn + 1] : start;
    int md = end - start;
    md = max(md, __shfl_xor(md, 16));
    md = max(md, __shfl_xor(md, 32));
    const int nit = (md + 7) / 8;

    const int head = (H == 4) ? (sub >> 2) : 0;
    const float er_s = (H == 4) ? er[(size_t)nn * 4 + head] : er[nn];

    float sA = 0.f, sB = 0.f;
    float acc[CPL];
#pragma unroll
    for (int c = 0; c < CPL; ++c) acc[c] = 0.f;

    float xA[4], xB[4];
    uint4 hA[4], hB[4];

    auto issue = [&](float (&xX)[4], uint4 (&hX)[4], int e0) {
#pragma unroll
        for (int i = 0; i < 4; ++i) {
            int ee = e0 + i;
            int eec = max(min(ee, end - 1), 0);
            int sn = colx[eec];
            if constexpr (HIN) {
                const __half* fth = (const __half*)ftv;
                if constexpr (CPL == 8) {
                    hX[i] = *(const uint4*)&fth[(size_t)sn * F + sub * 8];
                } else {
                    uint2 t2 = *(const uint2*)&fth[(size_t)sn * F + sub * 4];
                    hX[i].x = t2.x;
                    hX[i].y = t2.y;
                }
            } else {
                const float* ftf = (const float*)ftv;
                float4 f = *(const float4*)&ftf[(size_t)sn * F + sub * 4];
                hX[i].x = __float_as_uint(f.x);
                hX[i].y = __float_as_uint(f.y);
                hX[i].z = __float_as_uint(f.z);
                hX[i].w = __float_as_uint(f.w);
            }
            xX[i] = (H == 4) ? el[(size_t)sn * 4 + head] : el[sn];
        }
    };
    auto compute = [&](float (&xX)[4], uint4 (&hX)[4], int e0, float& sX) {
#pragma unroll
        for (int i = 0; i < 4; ++i) {
            float x = xX[i] + er_s;
            x = fmaxf(x, 0.2f * x);  // leaky_relu
            float p = __expf(x);
            p = (e0 + i < end) ? p : 0.f;
            sX += p;
            if constexpr (HIN) {
                const __half* hv = (const __half*)&hX[i];
#pragma unroll
                for (int c = 0; c < CPL; ++c)
                    acc[c] = fmaf(p, __half2float(hv[c]), acc[c]);
            } else {
                const float* fv = (const float*)&hX[i];
#pragma unroll
                for (int c = 0; c < CPL; ++c)
                    acc[c] = fmaf(p, fv[c], acc[c]);
            }
        }
    };

    int e0 = start;
    issue(xA, hA, e0);
    for (int it = 0; it < nit; ++it) {
        issue(xB, hB, e0 + 4);       // batch k+1 in flight
        compute(xA, hA, e0, sA);     // consume batch k
        issue(xA, hA, e0 + 8);       // batch k+2 in flight
        compute(xB, hB, e0 + 4, sB); // consume batch k+1
        e0 += 8;
    }

    if (!valid) return;
    float s = sA + sB;
    float inv = 1.0f / s;  // deg >= 1 guaranteed
    float o[CPL];
#pragma unroll
    for (int c = 0; c < CPL; ++c) {
        o[c] = acc[c] * inv + bias[sub * CPL + c];
        if (RELU) o[c] = fmaxf(o[c], 0.f);
    }
    if constexpr (HOUT16) {
        __half* oh = (__half*)outv;
        uint4 u;
        ushort* up = (ushort*)&u;
#pragma unroll
        for (int c = 0; c < CPL; ++c)
            up[c] = __half_as_ushort(__float2half_rn(o[c]));
        if constexpr (CPL == 8) {
            *(uint4*)&oh[(size_t)n * F + sub * 8] = u;
        } else {
            *(uint2*)&oh[(size_t)n * F + sub * 4] = make_uint2(u.x, u.y);
        }
    } else {
        float* of = (float*)outv;
        if constexpr (CPL == 8) {
            *(float4*)&of[(size_t)n * F + sub * 8] =
                make_float4(o[0], o[1], o[2], o[3]);
            *(float4*)&of[(size_t)n * F + sub * 8 + 4] =
                make_float4(o[4], o[5], o[6], o[7]);
        } else {
            *(float4*)&of[(size_t)n * F + sub * 4] =
                make_float4(o[0], o[1], o[2], o[3]);
        }
    }
}

// ---------------- host launch ----------------

static inline size_t alignup(size_t x) { return (x + 255) & ~(size_t)255; }

extern "C" void kernel_launch(void* const* d_in, const int* in_sizes, int n_in,
                              void* d_out, int out_size, void* d_ws, size_t ws_size,
                              hipStream_t stream) {
    const float* features = (const float*)d_in[0];
    const int* src = (const int*)d_in[1];
    const int* dst = (const int*)d_in[2];
    const float* W0 = (const float*)d_in[3];
    const float* al0 = (const float*)d_in[4];
    const float* ar0 = (const float*)d_in[5];
    const float* b0 = (const float*)d_in[6];
    const float* W1 = (const float*)d_in[7];
    const float* al1 = (const float*)d_in[8];
    const float* ar1 = (const float*)d_in[9];
    const float* b1 = (const float*)d_in[10];
    const float* W2 = (const float*)d_in[11];
    const float* al2 = (const float*)d_in[12];
    const float* ar2 = (const float*)d_in[13];
    const float* b2 = (const float*)d_in[14];
    float* out = (float*)d_out;

    const int N = in_sizes[0] / 128;  // 100000
    const int E = in_sizes[1];        // 1600000
    const int nebs = (E + EPB - 1) / EPB;   // sort blocks (391)
    const int nbuck = (N + 511) >> BSH;     // 196 buckets

    char* w = (char*)d_ws;
    int* rowptr = (int*)w;       w += alignup((size_t)(N + 1) * 4);
    int* colx = (int*)w;         w += alignup((size_t)E * 4 + 256);
    float* ft32 = (float*)w;     w += alignup((size_t)N * 64 * 4);
    __half* ft16 = (__half*)w;   w += alignup((size_t)N * 128 * 2);
    __half* hbuf16 = (__half*)w; w += alignup((size_t)N * 128 * 2);
    float* el = (float*)w;       w += alignup((size_t)N * 4 * 4);
    float* er = (float*)w;       w += alignup((size_t)N * 4 * 4);
    unsigned* ebuf = (unsigned*)w; w += alignup((size_t)E * 4);
    int* cmat = (int*)w;         w += alignup((size_t)256 * nebs * 4);
    int* rowtot = (int*)w;       w += alignup(256 * 4);
    int* bbase = (int*)w;        w += alignup(256 * 4);
    ushort* wsw0 = (ushort*)w;   w += alignup(128 * 128 * 2 * 2);
    ushort* wsw1 = (ushort*)w;   w += alignup(128 * 128 * 2 * 2);
    ushort* wsw2 = (ushort*)w;   w += alignup(128 * 64 * 2 * 2);

    // CSR build (atomic-free bucketed counting sort, u32-packed)
    ehist<<<nebs, 256, 0, stream>>>(dst, cmat, E, nebs);
    bscan<<<nbuck, 512, 0, stream>>>(cmat, rowtot, nebs);
    bbase_scan<<<1, 256, 0, stream>>>(rowtot, bbase, nbuck);
    escatter<<<nebs, 256, 0, stream>>>(src, dst, cmat, bbase, ebuf, E, nebs);
    bucket_fill<<<nbuck, 512, 0, stream>>>(ebuf, bbase, rowptr, colx, N, E, nbuck);

    // W pre-swizzle (single launch for all three weights)
    wprep_all<<<40, 256, 0, stream>>>(W0, W1, W2, wsw0, wsw1, wsw2);

    const int gG = (N + 63) / 64;
    const int gAgg = (N + 15) / 16;  // 4 nodes/wave, 4 waves/block

    // Layer 0: features(fp32) -> ft16 -> hbuf16
    gemm_mfma<128, 4, true, false><<<gG, 256, 0, stream>>>(features, wsw0, al0, ar0, ft16, el, er, N);
    gat_aggregate<128, 4, true, true, true><<<gAgg, 256, 0, stream>>>(rowptr, colx, el, er, ft16, b0, hbuf16, N);

    // Layer 1: hbuf16 -> ft16 -> hbuf16
    gemm_mfma<128, 4, true, true><<<gG, 256, 0, stream>>>(hbuf16, wsw1, al1, ar1, ft16, el, er, N);
    gat_aggregate<128, 4, true, true, true><<<gAgg, 256, 0, stream>>>(rowptr, colx, el, er, ft16, b1, hbuf16, N);

    // Layer 2: hbuf16 -> ft32 -> out (fp32)
    gemm_mfma<64, 1, false, true><<<gG, 256, 0, stream>>>(hbuf16, wsw2, al2, ar2, ft32, el, er, N);
    gat_aggregate<64, 1, false, false, false><<<gAgg, 256, 0, stream>>>(rowptr, colx, el, er, ft32, b2, out, N);
}